// Round 1
// baseline (1903.675 us; speedup 1.0000x reference)
//
#include <hip/hip_runtime.h>
#include <math.h>

#define L_SEQ 1600
#define CDIM 256
#define NH 8
#define HD 32
#define GRID_H 40
#define GRID_W 40
#define DFF_ 1024
#define WS_ 15
#define WIN 225
#define MAXD 7
#define SCALE_QK 0.17677669529663687f

__device__ __forceinline__ float waveReduceSum(float v) {
#pragma unroll
    for (int off = 32; off > 0; off >>= 1) v += __shfl_down(v, off, 64);
    return v;
}
__device__ __forceinline__ float waveReduceMax(float v) {
#pragma unroll
    for (int off = 32; off > 0; off >>= 1) v = fmaxf(v, __shfl_down(v, off, 64));
    return v;
}
// block of exactly 256 threads (4 waves)
__device__ __forceinline__ float blockReduceSum(float v, float* sh4) {
    v = waveReduceSum(v);
    int lane = threadIdx.x & 63, wid = threadIdx.x >> 6;
    __syncthreads();
    if (lane == 0) sh4[wid] = v;
    __syncthreads();
    return sh4[0] + sh4[1] + sh4[2] + sh4[3];
}
__device__ __forceinline__ float blockReduceMax(float v, float* sh4) {
    v = waveReduceMax(v);
    int lane = threadIdx.x & 63, wid = threadIdx.x >> 6;
    __syncthreads();
    if (lane == 0) sh4[wid] = v;
    __syncthreads();
    return fmaxf(fmaxf(sh4[0], sh4[1]), fmaxf(sh4[2], sh4[3]));
}

// LayerNorm over C=256; one block (256 thr) per row. out2 = out + addin (optional)
__global__ __launch_bounds__(256) void ln_kernel(const float* __restrict__ x,
                                                 const float* __restrict__ g,
                                                 const float* __restrict__ b,
                                                 const float* __restrict__ addin,
                                                 float* __restrict__ out,
                                                 float* __restrict__ out2) {
    __shared__ float sh4[4];
    int row = blockIdx.x;
    int c = threadIdx.x;
    float v = x[row * CDIM + c];
    float mean = blockReduceSum(v, sh4) * (1.0f / CDIM);
    float d = v - mean;
    float var = blockReduceSum(d * d, sh4) * (1.0f / CDIM);
    float y = d * rsqrtf(var + 1e-5f) * g[c] + b[c];
    out[row * CDIM + c] = y;
    if (out2) out2[row * CDIM + c] = y + addin[row * CDIM + c];
}

// C[M,N] = A[M,K] @ W[N,K]^T + bias + (res?)   all row-major f32
#define BM 64
#define BN 64
#define BK 16
__global__ __launch_bounds__(256) void gemm_bias_res(const float* __restrict__ A,
                                                     const float* __restrict__ W,
                                                     const float* __restrict__ bias,
                                                     const float* __restrict__ res,
                                                     float* __restrict__ C,
                                                     int M, int N, int K) {
    __shared__ float As[BK][BM + 1];
    __shared__ float Bs[BK][BN + 1];
    int bm = blockIdx.y * BM;
    int bn = blockIdx.x * BN;
    int tid = threadIdx.x;
    int tr = tid / 16, tc = tid % 16;
    float acc[4][4] = {};
    for (int k0 = 0; k0 < K; k0 += BK) {
        for (int i = tid; i < BM * BK; i += 256) {
            int m = i / BK, kk = i % BK;
            int gm = bm + m;
            As[kk][m] = (gm < M) ? A[gm * K + k0 + kk] : 0.f;
        }
        for (int i = tid; i < BN * BK; i += 256) {
            int n = i / BK, kk = i % BK;
            int gn = bn + n;
            Bs[kk][n] = (gn < N) ? W[gn * K + k0 + kk] : 0.f;
        }
        __syncthreads();
#pragma unroll
        for (int kk = 0; kk < BK; ++kk) {
            float a[4], bv[4];
#pragma unroll
            for (int i = 0; i < 4; i++) a[i] = As[kk][tr * 4 + i];
#pragma unroll
            for (int j = 0; j < 4; j++) bv[j] = Bs[kk][tc * 4 + j];
#pragma unroll
            for (int i = 0; i < 4; i++)
#pragma unroll
                for (int j = 0; j < 4; j++) acc[i][j] += a[i] * bv[j];
        }
        __syncthreads();
    }
#pragma unroll
    for (int i = 0; i < 4; i++) {
        int gm = bm + tr * 4 + i;
        if (gm >= M) continue;
#pragma unroll
        for (int j = 0; j < 4; j++) {
            int gn = bn + tc * 4 + j;
            if (gn >= N) continue;
            float v = acc[i][j] + (bias ? bias[gn] : 0.f);
            if (res) v += res[gm * N + gn];
            C[gm * N + gn] = v;
        }
    }
}

// MHA core: one block per (query, head). Q,K,V are (L,256), head h cols [h*32,h*32+32)
__global__ __launch_bounds__(256) void mha_kernel(const float* __restrict__ Q,
                                                  const float* __restrict__ K,
                                                  const float* __restrict__ V,
                                                  float* __restrict__ O) {
    __shared__ float sc[L_SEQ];
    __shared__ float qsh[HD];
    __shared__ float sh4[4];
    __shared__ float oacc[8][HD];
    int qi = blockIdx.x, h = blockIdx.y, tid = threadIdx.x;
    if (tid < HD) qsh[tid] = Q[qi * CDIM + h * HD + tid] * SCALE_QK;
    __syncthreads();
    float lmax = -INFINITY;
    for (int j = tid; j < L_SEQ; j += 256) {
        const float* kr = K + j * CDIM + h * HD;
        float s = 0.f;
#pragma unroll
        for (int d2 = 0; d2 < HD; ++d2) s += qsh[d2] * kr[d2];
        sc[j] = s;
        lmax = fmaxf(lmax, s);
    }
    float smax = blockReduceMax(lmax, sh4);
    float lsum = 0.f;
    for (int j = tid; j < L_SEQ; j += 256) {
        float e = expf(sc[j] - smax);
        sc[j] = e;
        lsum += e;
    }
    float inv = 1.0f / blockReduceSum(lsum, sh4);
    int d2 = tid & 31, ch = tid >> 5;
    float acc = 0.f;
    for (int j = ch; j < L_SEQ; j += 8) acc += sc[j] * V[j * CDIM + h * HD + d2];
    oacc[ch][d2] = acc;
    __syncthreads();
    if (tid < HD) {
        float s = 0.f;
#pragma unroll
        for (int i = 0; i < 8; ++i) s += oacc[i][tid];
        O[qi * CDIM + h * HD + tid] = s * inv;
    }
}

// Local windowed attention: one block per (position, head)
__global__ __launch_bounds__(256) void local_attn_kernel(const float* __restrict__ Q,
                                                         const float* __restrict__ K,
                                                         const float* __restrict__ V,
                                                         float* __restrict__ O) {
    __shared__ float qsh[HD];
    __shared__ float p[WIN];
    __shared__ float sh4[4];
    __shared__ float oacc[8][HD];
    int n = blockIdx.x, h = blockIdx.y, tid = threadIdx.x;
    int y = n / GRID_W, x = n % GRID_W;
    if (tid < HD) qsh[tid] = Q[n * CDIM + h * HD + tid] * SCALE_QK;
    __syncthreads();
    float lg = -INFINITY;
    if (tid < WIN) {
        int dy = tid / WS_ - MAXD, dx = tid % WS_ - MAXD;
        int yy = y + dy, xx = x + dx;
        if (yy >= 0 && yy < GRID_H && xx >= 0 && xx < GRID_W) {
            const float* kr = K + (yy * GRID_W + xx) * CDIM + h * HD;
            float s = 0.f;
#pragma unroll
            for (int d2 = 0; d2 < HD; ++d2) s += qsh[d2] * kr[d2];
            lg = s;
        } else {
            lg = -1.0e9f;
        }
    }
    float smax = blockReduceMax(lg, sh4);
    float e = 0.f;
    if (tid < WIN) {
        e = expf(lg - smax);
        p[tid] = e;
    }
    float inv = 1.0f / blockReduceSum(e, sh4);
    int d2 = tid & 31, ch = tid >> 5;
    float acc = 0.f;
    for (int w = ch; w < WIN; w += 8) {
        int dy = w / WS_ - MAXD, dx = w % WS_ - MAXD;
        int yy = y + dy, xx = x + dx;
        if (yy >= 0 && yy < GRID_H && xx >= 0 && xx < GRID_W)
            acc += p[w] * V[(yy * GRID_W + xx) * CDIM + h * HD + d2];
    }
    oacc[ch][d2] = acc;
    __syncthreads();
    if (tid < HD) {
        float s = 0.f;
#pragma unroll
        for (int i = 0; i < 8; ++i) s += oacc[i][tid];
        O[n * CDIM + h * HD + tid] = s * inv;
    }
}

// build curr_Q (contiguous), global_K, global_V from qv (1600x512) and idkv (1600x264)
__global__ __launch_bounds__(256) void make_qkv_kernel(const float* __restrict__ qv,
                                                       const float* __restrict__ idkv,
                                                       float* __restrict__ Qc,
                                                       float* __restrict__ gK,
                                                       float* __restrict__ gV) {
    int idx = blockIdx.x * 256 + threadIdx.x;
    if (idx >= L_SEQ * CDIM) return;
    int l = idx >> 8, c = idx & 255;
    int h = c >> 5;
    float q = qv[l * 512 + c];
    Qc[idx] = q;
    gK[idx] = q * (1.f + tanhf(idkv[l * 264 + h]));
    gV[idx] = qv[l * 512 + 256 + c] + idkv[l * 264 + 8 + c];
}

// GroupNorm (32 groups of 32 ch over 1600 positions) + exact GELU; X,Y are (1600,1024)
__global__ __launch_bounds__(256) void gn_gelu_kernel(const float* __restrict__ X,
                                                      const float* __restrict__ g,
                                                      const float* __restrict__ b,
                                                      float* __restrict__ Y) {
    __shared__ float sh4[4];
    int grp = blockIdx.x, tid = threadIdx.x;
    int base = grp * 32;
    float s = 0.f, s2 = 0.f;
    for (int i = tid; i < L_SEQ * 32; i += 256) {
        int l = i >> 5, c = i & 31;
        float v = X[l * DFF_ + base + c];
        s += v;
        s2 += v * v;
    }
    const float invn = 1.0f / (L_SEQ * 32);
    float mean = blockReduceSum(s, sh4) * invn;
    float ex2 = blockReduceSum(s2, sh4) * invn;
    float rs = rsqrtf(ex2 - mean * mean + 1e-5f);
    for (int i = tid; i < L_SEQ * 32; i += 256) {
        int l = i >> 5, c = i & 31;
        float v = X[l * DFF_ + base + c];
        float yv = (v - mean) * rs * g[base + c] + b[base + c];
        yv = 0.5f * yv * (1.0f + erff(yv * 0.70710678118654752f));
        Y[l * DFF_ + base + c] = yv;
    }
}

// depthwise 5x5 conv, pad 2 (cross-correlation). X,Y (1600,1024) l-major; Kw (1024,25)
__global__ __launch_bounds__(256) void dwconv_kernel(const float* __restrict__ X,
                                                     const float* __restrict__ Kw,
                                                     float* __restrict__ Y) {
    int idx = blockIdx.x * 256 + threadIdx.x;
    if (idx >= L_SEQ * DFF_) return;
    int c = idx & 1023, l = idx >> 10;
    int y = l / GRID_W, x = l % GRID_W;
    float acc = 0.f;
#pragma unroll
    for (int ky = 0; ky < 5; ++ky) {
        int yy = y + ky - 2;
        if (yy < 0 || yy >= GRID_H) continue;
#pragma unroll
        for (int kx = 0; kx < 5; ++kx) {
            int xx = x + kx - 2;
            if (xx < 0 || xx >= GRID_W) continue;
            acc += X[(yy * GRID_W + xx) * DFF_ + c] * Kw[c * 25 + ky * 5 + kx];
        }
    }
    Y[idx] = acc;
}

extern "C" void kernel_launch(void* const* d_in, const int* in_sizes, int n_in,
                              void* d_out, int out_size, void* d_ws, size_t ws_size,
                              hipStream_t stream) {
    (void)in_sizes; (void)n_in; (void)out_size; (void)ws_size;
    const float* tgt = (const float*)d_in[0];
    const float* curr_id_emb = (const float*)d_in[1];
    const float* self_pos = (const float*)d_in[2];
    const float* ln1_g = (const float*)d_in[3];
    const float* ln1_b = (const float*)d_in[4];
    const float* sa_wq = (const float*)d_in[5];
    const float* sa_bq = (const float*)d_in[6];
    const float* sa_wk = (const float*)d_in[7];
    const float* sa_bk = (const float*)d_in[8];
    const float* sa_wv = (const float*)d_in[9];
    const float* sa_bv = (const float*)d_in[10];
    const float* sa_wo = (const float*)d_in[11];
    const float* sa_bo = (const float*)d_in[12];
    const float* ln2_g = (const float*)d_in[13];
    const float* ln2_b = (const float*)d_in[14];
    const float* w_qv = (const float*)d_in[15];
    const float* b_qv = (const float*)d_in[16];
    const float* w_id = (const float*)d_in[17];
    const float* b_id = (const float*)d_in[18];
    const float* lt_wo = (const float*)d_in[19];
    const float* lt_bo = (const float*)d_in[20];
    const float* st_wo = (const float*)d_in[21];
    const float* st_bo = (const float*)d_in[22];
    const float* ln3_g = (const float*)d_in[23];
    const float* ln3_b = (const float*)d_in[24];
    const float* w1 = (const float*)d_in[25];
    const float* b1 = (const float*)d_in[26];
    const float* gn_g = (const float*)d_in[27];
    const float* gn_b = (const float*)d_in[28];
    const float* dw_k = (const float*)d_in[29];
    const float* w2 = (const float*)d_in[30];
    const float* b2 = (const float*)d_in[31];
    float* out = (float*)d_out;

    float* ws = (float*)d_ws;
    const int LC = L_SEQ * CDIM;           // 409600
    float* bufA = ws;                      // _t
    float* bufB = bufA + LC;               // qk_in / tgt1+tgt2
    float* bufC = bufB + LC;               // q_ / curr_Q
    float* bufD = bufC + LC;               // k_ / global_K
    float* bufE = bufD + LC;               // v_ / global_V
    float* bufF = bufE + LC;               // attn outs
    float* bufG = bufF + LC;               // tgt1 / tgt_b
    float* bufH = bufG + LC;               // qv (1600x512)
    float* bufI = bufH + L_SEQ * 512;      // idkv (1600x264)
    float* bufX = bufI + L_SEQ * 264;      // w1 out (1600x1024)
    float* bufY = bufX + L_SEQ * DFF_;     // gn+gelu out
    float* bufZ = bufY + L_SEQ * DFF_;     // conv out

    dim3 blk(256);
    dim3 gemmGrid256(4, 25), gemmGrid512(8, 25), gemmGrid264(5, 25), gemmGrid1024(16, 25);

    // 1. LN1: bufA = ln(tgt), bufB = bufA + self_pos
    ln_kernel<<<L_SEQ, blk, 0, stream>>>(tgt, ln1_g, ln1_b, self_pos, bufA, bufB);
    // 2-4. q,k,v projections
    gemm_bias_res<<<gemmGrid256, blk, 0, stream>>>(bufB, sa_wq, sa_bq, nullptr, bufC, L_SEQ, CDIM, CDIM);
    gemm_bias_res<<<gemmGrid256, blk, 0, stream>>>(bufB, sa_wk, sa_bk, nullptr, bufD, L_SEQ, CDIM, CDIM);
    gemm_bias_res<<<gemmGrid256, blk, 0, stream>>>(bufA, sa_wv, sa_bv, nullptr, bufE, L_SEQ, CDIM, CDIM);
    // 5. self attention
    mha_kernel<<<dim3(L_SEQ, NH), blk, 0, stream>>>(bufC, bufD, bufE, bufF);
    // 6. out proj + residual -> tgt1 (bufG)
    gemm_bias_res<<<gemmGrid256, blk, 0, stream>>>(bufF, sa_wo, sa_bo, tgt, bufG, L_SEQ, CDIM, CDIM);
    // 7. LN2 -> bufA
    ln_kernel<<<L_SEQ, blk, 0, stream>>>(bufG, ln2_g, ln2_b, nullptr, bufA, nullptr);
    // 8. qv = bufA @ w_qv^T -> bufH (1600x512)
    gemm_bias_res<<<gemmGrid512, blk, 0, stream>>>(bufA, w_qv, b_qv, nullptr, bufH, L_SEQ, 512, CDIM);
    // 9. idkv = curr_id_emb @ w_id^T -> bufI (1600x264)
    gemm_bias_res<<<gemmGrid264, blk, 0, stream>>>(curr_id_emb, w_id, b_id, nullptr, bufI, L_SEQ, 264, CDIM);
    // 10. curr_Q (bufC), global_K (bufD), global_V (bufE)
    make_qkv_kernel<<<L_SEQ, blk, 0, stream>>>(bufH, bufI, bufC, bufD, bufE);
    // 11. long-term attention
    mha_kernel<<<dim3(L_SEQ, NH), blk, 0, stream>>>(bufC, bufD, bufE, bufF);
    // 12. lt out proj + residual(tgt1) -> bufB
    gemm_bias_res<<<gemmGrid256, blk, 0, stream>>>(bufF, lt_wo, lt_bo, bufG, bufB, L_SEQ, CDIM, CDIM);
    // 13. local attention -> bufF
    local_attn_kernel<<<dim3(L_SEQ, NH), blk, 0, stream>>>(bufC, bufD, bufE, bufF);
    // 14. st out proj + residual(bufB) -> tgt_b (bufG)
    gemm_bias_res<<<gemmGrid256, blk, 0, stream>>>(bufF, st_wo, st_bo, bufB, bufG, L_SEQ, CDIM, CDIM);
    // 15. LN3 -> bufA
    ln_kernel<<<L_SEQ, blk, 0, stream>>>(bufG, ln3_g, ln3_b, nullptr, bufA, nullptr);
    // 16. x = bufA @ w1^T -> bufX (1600x1024)
    gemm_bias_res<<<gemmGrid1024, blk, 0, stream>>>(bufA, w1, b1, nullptr, bufX, L_SEQ, DFF_, CDIM);
    // 17. GroupNorm + GELU -> bufY
    gn_gelu_kernel<<<32, blk, 0, stream>>>(bufX, gn_g, gn_b, bufY);
    // 18. depthwise conv -> bufZ
    dwconv_kernel<<<(L_SEQ * DFF_ + 255) / 256, blk, 0, stream>>>(bufY, dw_k, bufZ);
    // 19. final proj + residual(tgt_b) -> out
    gemm_bias_res<<<gemmGrid256, blk, 0, stream>>>(bufZ, w2, b2, bufG, out, L_SEQ, CDIM, DFF_);
}

// Round 3
// 1269.721 us; speedup vs baseline: 1.4993x; 1.4993x over previous
//
#include <hip/hip_runtime.h>
#include <math.h>

#define L_SEQ 1600
#define CDIM 256
#define NH 8
#define HD 32
#define GRID_H 40
#define GRID_W 40
#define DFF_ 1024
#define WS_ 15
#define WIN 225
#define MAXD 7
#define SCALE_QK 0.17677669529663687f

__device__ __forceinline__ float waveReduceSum(float v) {
#pragma unroll
    for (int off = 32; off > 0; off >>= 1) v += __shfl_down(v, off, 64);
    return v;
}
__device__ __forceinline__ float waveReduceMax(float v) {
#pragma unroll
    for (int off = 32; off > 0; off >>= 1) v = fmaxf(v, __shfl_down(v, off, 64));
    return v;
}
// block of exactly 256 threads (4 waves)
__device__ __forceinline__ float blockReduceSum(float v, float* sh4) {
    v = waveReduceSum(v);
    int lane = threadIdx.x & 63, wid = threadIdx.x >> 6;
    __syncthreads();
    if (lane == 0) sh4[wid] = v;
    __syncthreads();
    return sh4[0] + sh4[1] + sh4[2] + sh4[3];
}
__device__ __forceinline__ float blockReduceMax(float v, float* sh4) {
    v = waveReduceMax(v);
    int lane = threadIdx.x & 63, wid = threadIdx.x >> 6;
    __syncthreads();
    if (lane == 0) sh4[wid] = v;
    __syncthreads();
    return fmaxf(fmaxf(sh4[0], sh4[1]), fmaxf(sh4[2], sh4[3]));
}

// LayerNorm over C=256; one block (256 thr) per row. out2 = out + addin (optional)
__global__ __launch_bounds__(256) void ln_kernel(const float* __restrict__ x,
                                                 const float* __restrict__ g,
                                                 const float* __restrict__ b,
                                                 const float* __restrict__ addin,
                                                 float* __restrict__ out,
                                                 float* __restrict__ out2) {
    __shared__ float sh4[4];
    int row = blockIdx.x;
    int c = threadIdx.x;
    float v = x[row * CDIM + c];
    float mean = blockReduceSum(v, sh4) * (1.0f / CDIM);
    float d = v - mean;
    float var = blockReduceSum(d * d, sh4) * (1.0f / CDIM);
    float y = d * rsqrtf(var + 1e-5f) * g[c] + b[c];
    out[row * CDIM + c] = y;
    if (out2) out2[row * CDIM + c] = y + addin[row * CDIM + c];
}

// C[M,N] = A[M,K] @ W[N,K]^T + bias + (res?)   all row-major f32
#define BM 64
#define BN 64
#define BK 16
__global__ __launch_bounds__(256) void gemm_bias_res(const float* __restrict__ A,
                                                     const float* __restrict__ W,
                                                     const float* __restrict__ bias,
                                                     const float* __restrict__ res,
                                                     float* __restrict__ C,
                                                     int M, int N, int K) {
    __shared__ float As[BK][BM + 1];
    __shared__ float Bs[BK][BN + 1];
    int bm = blockIdx.y * BM;
    int bn = blockIdx.x * BN;
    int tid = threadIdx.x;
    int tr = tid / 16, tc = tid % 16;
    float acc[4][4] = {};
    for (int k0 = 0; k0 < K; k0 += BK) {
        for (int i = tid; i < BM * BK; i += 256) {
            int m = i / BK, kk = i % BK;
            int gm = bm + m;
            As[kk][m] = (gm < M) ? A[gm * K + k0 + kk] : 0.f;
        }
        for (int i = tid; i < BN * BK; i += 256) {
            int n = i / BK, kk = i % BK;
            int gn = bn + n;
            Bs[kk][n] = (gn < N) ? W[gn * K + k0 + kk] : 0.f;
        }
        __syncthreads();
#pragma unroll
        for (int kk = 0; kk < BK; ++kk) {
            float a[4], bv[4];
#pragma unroll
            for (int i = 0; i < 4; i++) a[i] = As[kk][tr * 4 + i];
#pragma unroll
            for (int j = 0; j < 4; j++) bv[j] = Bs[kk][tc * 4 + j];
#pragma unroll
            for (int i = 0; i < 4; i++)
#pragma unroll
                for (int j = 0; j < 4; j++) acc[i][j] += a[i] * bv[j];
        }
        __syncthreads();
    }
#pragma unroll
    for (int i = 0; i < 4; i++) {
        int gm = bm + tr * 4 + i;
        if (gm >= M) continue;
#pragma unroll
        for (int j = 0; j < 4; j++) {
            int gn = bn + tc * 4 + j;
            if (gn >= N) continue;
            float v = acc[i][j] + (bias ? bias[gn] : 0.f);
            if (res) v += res[gm * N + gn];
            C[gm * N + gn] = v;
        }
    }
}

// ---------------------------------------------------------------------------
// Fused MHA: one block = 8 query rows of one head. 256 threads (4 waves),
// each wave owns 2 query rows held in registers. K/V staged in LDS in 128-row
// tiles with XOR swizzle (col4 ^= row&7) to kill the 32-way bank conflict of
// row-major 128B rows. Scores kept in LDS (8x1600), two-pass softmax.
// ---------------------------------------------------------------------------
#define QB 8
#define TJ 128
__global__ __launch_bounds__(256) void mha_flash(const float* __restrict__ Q,
                                                 const float* __restrict__ K,
                                                 const float* __restrict__ V,
                                                 float* __restrict__ O) {
    __shared__ float sc[QB][L_SEQ];     // 51200 B
    __shared__ float4 kt[TJ][8];        // 16384 B, swizzled
    int h = blockIdx.y;
    int qbase = blockIdx.x * QB;
    int tid = threadIdx.x;
    int wave = tid >> 6, lane = tid & 63;
    int lq0 = 2 * wave, lq1 = lq0 + 1;

    // load + scale this wave's 2 query rows into registers
    const float4* Qr0 = (const float4*)(Q + (qbase + lq0) * CDIM + h * HD);
    const float4* Qr1 = (const float4*)(Q + (qbase + lq1) * CDIM + h * HD);
    float4 qa[8], qb[8];
#pragma unroll
    for (int c = 0; c < 8; ++c) {
        float4 a = Qr0[c], b = Qr1[c];
        a.x *= SCALE_QK; a.y *= SCALE_QK; a.z *= SCALE_QK; a.w *= SCALE_QK;
        b.x *= SCALE_QK; b.y *= SCALE_QK; b.z *= SCALE_QK; b.w *= SCALE_QK;
        qa[c] = a; qb[c] = b;
    }

    // ---- phase 1: scores = q . k ----
    float m0 = -INFINITY, m1 = -INFINITY;
    for (int t = 0; t < L_SEQ; t += TJ) {
        __syncthreads();
#pragma unroll
        for (int r = 0; r < 4; ++r) {
            int idx = tid + 256 * r;          // 0..1023
            int row = idx >> 3, c = idx & 7;
            int j = t + row;
            float4 kv = make_float4(0.f, 0.f, 0.f, 0.f);
            if (j < L_SEQ) kv = ((const float4*)(K + j * CDIM + h * HD))[c];
            kt[row][c ^ (row & 7)] = kv;
        }
        __syncthreads();
#pragma unroll
        for (int m = 0; m < 2; ++m) {
            int row = lane + 64 * m;
            int j = t + row;
            if (j < L_SEQ) {
                float s0 = 0.f, s1 = 0.f;
#pragma unroll
                for (int c = 0; c < 8; ++c) {
                    float4 kv = kt[row][c ^ (row & 7)];
                    s0 += qa[c].x * kv.x + qa[c].y * kv.y + qa[c].z * kv.z + qa[c].w * kv.w;
                    s1 += qb[c].x * kv.x + qb[c].y * kv.y + qb[c].z * kv.z + qb[c].w * kv.w;
                }
                sc[lq0][j] = s0;
                sc[lq1][j] = s1;
                m0 = fmaxf(m0, s0);
                m1 = fmaxf(m1, s1);
            }
        }
    }
#pragma unroll
    for (int off = 32; off > 0; off >>= 1) {
        m0 = fmaxf(m0, __shfl_xor(m0, off, 64));
        m1 = fmaxf(m1, __shfl_xor(m1, off, 64));
    }

    // ---- phase 2: exp + row sums (wave-private rows, no barrier needed) ----
    float l0 = 0.f, l1 = 0.f;
    for (int j = lane; j < L_SEQ; j += 64) {
        float e0 = __expf(sc[lq0][j] - m0);
        float e1 = __expf(sc[lq1][j] - m1);
        sc[lq0][j] = e0;
        sc[lq1][j] = e1;
        l0 += e0;
        l1 += e1;
    }
#pragma unroll
    for (int off = 32; off > 0; off >>= 1) {
        l0 += __shfl_xor(l0, off, 64);
        l1 += __shfl_xor(l1, off, 64);
    }
    float inv0 = 1.f / l0, inv1 = 1.f / l1;

    // ---- phase 3: O = P . V ----
    float4 o0 = make_float4(0.f, 0.f, 0.f, 0.f);
    float4 o1 = make_float4(0.f, 0.f, 0.f, 0.f);
    int d4 = lane & 7, jsl = lane >> 3;
    for (int t = 0; t < L_SEQ; t += TJ) {
        __syncthreads();
#pragma unroll
        for (int r = 0; r < 4; ++r) {
            int idx = tid + 256 * r;
            int row = idx >> 3, c = idx & 7;
            int j = t + row;
            float4 vv = make_float4(0.f, 0.f, 0.f, 0.f);
            if (j < L_SEQ) vv = ((const float4*)(V + j * CDIM + h * HD))[c];
            kt[row][c ^ (row & 7)] = vv;
        }
        __syncthreads();
#pragma unroll
        for (int m = 0; m < 16; ++m) {
            int row = jsl + 8 * m;
            int j = t + row;
            if (j >= L_SEQ) break;
            float4 vv = kt[row][d4 ^ (row & 7)];
            float p0 = sc[lq0][j], p1 = sc[lq1][j];
            o0.x += p0 * vv.x; o0.y += p0 * vv.y; o0.z += p0 * vv.z; o0.w += p0 * vv.w;
            o1.x += p1 * vv.x; o1.y += p1 * vv.y; o1.z += p1 * vv.z; o1.w += p1 * vv.w;
        }
    }
    // reduce partials across jsl (lane bits 3..5)
#pragma unroll
    for (int off = 8; off < 64; off <<= 1) {
        o0.x += __shfl_xor(o0.x, off, 64);
        o0.y += __shfl_xor(o0.y, off, 64);
        o0.z += __shfl_xor(o0.z, off, 64);
        o0.w += __shfl_xor(o0.w, off, 64);
        o1.x += __shfl_xor(o1.x, off, 64);
        o1.y += __shfl_xor(o1.y, off, 64);
        o1.z += __shfl_xor(o1.z, off, 64);
        o1.w += __shfl_xor(o1.w, off, 64);
    }
    if (jsl == 0) {
        float4 r0, r1;
        r0.x = o0.x * inv0; r0.y = o0.y * inv0; r0.z = o0.z * inv0; r0.w = o0.w * inv0;
        r1.x = o1.x * inv1; r1.y = o1.y * inv1; r1.z = o1.z * inv1; r1.w = o1.w * inv1;
        ((float4*)(O + (qbase + lq0) * CDIM + h * HD))[d4] = r0;
        ((float4*)(O + (qbase + lq1) * CDIM + h * HD))[d4] = r1;
    }
}

// Local windowed attention: one block per (position, head)
__global__ __launch_bounds__(256) void local_attn_kernel(const float* __restrict__ Q,
                                                         const float* __restrict__ K,
                                                         const float* __restrict__ V,
                                                         float* __restrict__ O) {
    __shared__ float qsh[HD];
    __shared__ float p[WIN];
    __shared__ float sh4[4];
    __shared__ float oacc[8][HD];
    int n = blockIdx.x, h = blockIdx.y, tid = threadIdx.x;
    int y = n / GRID_W, x = n % GRID_W;
    if (tid < HD) qsh[tid] = Q[n * CDIM + h * HD + tid] * SCALE_QK;
    __syncthreads();
    float lg = -INFINITY;
    if (tid < WIN) {
        int dy = tid / WS_ - MAXD, dx = tid % WS_ - MAXD;
        int yy = y + dy, xx = x + dx;
        if (yy >= 0 && yy < GRID_H && xx >= 0 && xx < GRID_W) {
            const float* kr = K + (yy * GRID_W + xx) * CDIM + h * HD;
            float s = 0.f;
#pragma unroll
            for (int d2 = 0; d2 < HD; ++d2) s += qsh[d2] * kr[d2];
            lg = s;
        } else {
            lg = -1.0e9f;
        }
    }
    float smax = blockReduceMax(lg, sh4);
    float e = 0.f;
    if (tid < WIN) {
        e = expf(lg - smax);
        p[tid] = e;
    }
    float inv = 1.0f / blockReduceSum(e, sh4);
    int d2 = tid & 31, ch = tid >> 5;
    float acc = 0.f;
    for (int w = ch; w < WIN; w += 8) {
        int dy = w / WS_ - MAXD, dx = w % WS_ - MAXD;
        int yy = y + dy, xx = x + dx;
        if (yy >= 0 && yy < GRID_H && xx >= 0 && xx < GRID_W)
            acc += p[w] * V[(yy * GRID_W + xx) * CDIM + h * HD + d2];
    }
    oacc[ch][d2] = acc;
    __syncthreads();
    if (tid < HD) {
        float s = 0.f;
#pragma unroll
        for (int i = 0; i < 8; ++i) s += oacc[i][tid];
        O[n * CDIM + h * HD + tid] = s * inv;
    }
}

// build curr_Q (contiguous), global_K, global_V from qv (1600x512) and idkv (1600x264)
__global__ __launch_bounds__(256) void make_qkv_kernel(const float* __restrict__ qv,
                                                       const float* __restrict__ idkv,
                                                       float* __restrict__ Qc,
                                                       float* __restrict__ gK,
                                                       float* __restrict__ gV) {
    int idx = blockIdx.x * 256 + threadIdx.x;
    if (idx >= L_SEQ * CDIM) return;
    int l = idx >> 8, c = idx & 255;
    int h = c >> 5;
    float q = qv[l * 512 + c];
    Qc[idx] = q;
    gK[idx] = q * (1.f + tanhf(idkv[l * 264 + h]));
    gV[idx] = qv[l * 512 + 256 + c] + idkv[l * 264 + 8 + c];
}

// GroupNorm (32 groups of 32 ch over 1600 positions) + exact GELU; X,Y are (1600,1024)
__global__ __launch_bounds__(256) void gn_gelu_kernel(const float* __restrict__ X,
                                                      const float* __restrict__ g,
                                                      const float* __restrict__ b,
                                                      float* __restrict__ Y) {
    __shared__ float sh4[4];
    int grp = blockIdx.x, tid = threadIdx.x;
    int base = grp * 32;
    float s = 0.f, s2 = 0.f;
    for (int i = tid; i < L_SEQ * 32; i += 256) {
        int l = i >> 5, c = i & 31;
        float v = X[l * DFF_ + base + c];
        s += v;
        s2 += v * v;
    }
    const float invn = 1.0f / (L_SEQ * 32);
    float mean = blockReduceSum(s, sh4) * invn;
    float ex2 = blockReduceSum(s2, sh4) * invn;
    float rs = rsqrtf(ex2 - mean * mean + 1e-5f);
    for (int i = tid; i < L_SEQ * 32; i += 256) {
        int l = i >> 5, c = i & 31;
        float v = X[l * DFF_ + base + c];
        float yv = (v - mean) * rs * g[base + c] + b[base + c];
        yv = 0.5f * yv * (1.0f + erff(yv * 0.70710678118654752f));
        Y[l * DFF_ + base + c] = yv;
    }
}

// depthwise 5x5 conv, pad 2 (cross-correlation). X,Y (1600,1024) l-major; Kw (1024,25)
__global__ __launch_bounds__(256) void dwconv_kernel(const float* __restrict__ X,
                                                     const float* __restrict__ Kw,
                                                     float* __restrict__ Y) {
    int idx = blockIdx.x * 256 + threadIdx.x;
    if (idx >= L_SEQ * DFF_) return;
    int c = idx & 1023, l = idx >> 10;
    int y = l / GRID_W, x = l % GRID_W;
    float acc = 0.f;
#pragma unroll
    for (int ky = 0; ky < 5; ++ky) {
        int yy = y + ky - 2;
        if (yy < 0 || yy >= GRID_H) continue;
#pragma unroll
        for (int kx = 0; kx < 5; ++kx) {
            int xx = x + kx - 2;
            if (xx < 0 || xx >= GRID_W) continue;
            acc += X[(yy * GRID_W + xx) * DFF_ + c] * Kw[c * 25 + ky * 5 + kx];
        }
    }
    Y[idx] = acc;
}

extern "C" void kernel_launch(void* const* d_in, const int* in_sizes, int n_in,
                              void* d_out, int out_size, void* d_ws, size_t ws_size,
                              hipStream_t stream) {
    (void)in_sizes; (void)n_in; (void)out_size; (void)ws_size;
    const float* tgt = (const float*)d_in[0];
    const float* curr_id_emb = (const float*)d_in[1];
    const float* self_pos = (const float*)d_in[2];
    const float* ln1_g = (const float*)d_in[3];
    const float* ln1_b = (const float*)d_in[4];
    const float* sa_wq = (const float*)d_in[5];
    const float* sa_bq = (const float*)d_in[6];
    const float* sa_wk = (const float*)d_in[7];
    const float* sa_bk = (const float*)d_in[8];
    const float* sa_wv = (const float*)d_in[9];
    const float* sa_bv = (const float*)d_in[10];
    const float* sa_wo = (const float*)d_in[11];
    const float* sa_bo = (const float*)d_in[12];
    const float* ln2_g = (const float*)d_in[13];
    const float* ln2_b = (const float*)d_in[14];
    const float* w_qv = (const float*)d_in[15];
    const float* b_qv = (const float*)d_in[16];
    const float* w_id = (const float*)d_in[17];
    const float* b_id = (const float*)d_in[18];
    const float* lt_wo = (const float*)d_in[19];
    const float* lt_bo = (const float*)d_in[20];
    const float* st_wo = (const float*)d_in[21];
    const float* st_bo = (const float*)d_in[22];
    const float* ln3_g = (const float*)d_in[23];
    const float* ln3_b = (const float*)d_in[24];
    const float* w1 = (const float*)d_in[25];
    const float* b1 = (const float*)d_in[26];
    const float* gn_g = (const float*)d_in[27];
    const float* gn_b = (const float*)d_in[28];
    const float* dw_k = (const float*)d_in[29];
    const float* w2 = (const float*)d_in[30];
    const float* b2 = (const float*)d_in[31];
    float* out = (float*)d_out;

    float* ws = (float*)d_ws;
    const int LC = L_SEQ * CDIM;           // 409600
    float* bufA = ws;                      // _t
    float* bufB = bufA + LC;               // qk_in / tgt1+tgt2
    float* bufC = bufB + LC;               // q_ / curr_Q
    float* bufD = bufC + LC;               // k_ / global_K
    float* bufE = bufD + LC;               // v_ / global_V
    float* bufF = bufE + LC;               // attn outs
    float* bufG = bufF + LC;               // tgt1 / tgt_b
    float* bufH = bufG + LC;               // qv (1600x512)
    float* bufI = bufH + L_SEQ * 512;      // idkv (1600x264)
    float* bufX = bufI + L_SEQ * 264;      // w1 out (1600x1024)
    float* bufY = bufX + L_SEQ * DFF_;     // gn+gelu out
    float* bufZ = bufY + L_SEQ * DFF_;     // conv out

    dim3 blk(256);
    dim3 gemmGrid256(4, 25), gemmGrid512(8, 25), gemmGrid264(5, 25), gemmGrid1024(16, 25);
    dim3 mhaGrid(L_SEQ / QB, NH);

    // 1. LN1: bufA = ln(tgt), bufB = bufA + self_pos
    ln_kernel<<<L_SEQ, blk, 0, stream>>>(tgt, ln1_g, ln1_b, self_pos, bufA, bufB);
    // 2-4. q,k,v projections
    gemm_bias_res<<<gemmGrid256, blk, 0, stream>>>(bufB, sa_wq, sa_bq, nullptr, bufC, L_SEQ, CDIM, CDIM);
    gemm_bias_res<<<gemmGrid256, blk, 0, stream>>>(bufB, sa_wk, sa_bk, nullptr, bufD, L_SEQ, CDIM, CDIM);
    gemm_bias_res<<<gemmGrid256, blk, 0, stream>>>(bufA, sa_wv, sa_bv, nullptr, bufE, L_SEQ, CDIM, CDIM);
    // 5. self attention
    mha_flash<<<mhaGrid, blk, 0, stream>>>(bufC, bufD, bufE, bufF);
    // 6. out proj + residual -> tgt1 (bufG)
    gemm_bias_res<<<gemmGrid256, blk, 0, stream>>>(bufF, sa_wo, sa_bo, tgt, bufG, L_SEQ, CDIM, CDIM);
    // 7. LN2 -> bufA
    ln_kernel<<<L_SEQ, blk, 0, stream>>>(bufG, ln2_g, ln2_b, nullptr, bufA, nullptr);
    // 8. qv = bufA @ w_qv^T -> bufH (1600x512)
    gemm_bias_res<<<gemmGrid512, blk, 0, stream>>>(bufA, w_qv, b_qv, nullptr, bufH, L_SEQ, 512, CDIM);
    // 9. idkv = curr_id_emb @ w_id^T -> bufI (1600x264)
    gemm_bias_res<<<gemmGrid264, blk, 0, stream>>>(curr_id_emb, w_id, b_id, nullptr, bufI, L_SEQ, 264, CDIM);
    // 10. curr_Q (bufC), global_K (bufD), global_V (bufE)
    make_qkv_kernel<<<L_SEQ, blk, 0, stream>>>(bufH, bufI, bufC, bufD, bufE);
    // 11. long-term attention
    mha_flash<<<mhaGrid, blk, 0, stream>>>(bufC, bufD, bufE, bufF);
    // 12. lt out proj + residual(tgt1) -> bufB
    gemm_bias_res<<<gemmGrid256, blk, 0, stream>>>(bufF, lt_wo, lt_bo, bufG, bufB, L_SEQ, CDIM, CDIM);
    // 13. local attention -> bufF
    local_attn_kernel<<<dim3(L_SEQ, NH), blk, 0, stream>>>(bufC, bufD, bufE, bufF);
    // 14. st out proj + residual(bufB) -> tgt_b (bufG)
    gemm_bias_res<<<gemmGrid256, blk, 0, stream>>>(bufF, st_wo, st_bo, bufB, bufG, L_SEQ, CDIM, CDIM);
    // 15. LN3 -> bufA
    ln_kernel<<<L_SEQ, blk, 0, stream>>>(bufG, ln3_g, ln3_b, nullptr, bufA, nullptr);
    // 16. x = bufA @ w1^T -> bufX (1600x1024)
    gemm_bias_res<<<gemmGrid1024, blk, 0, stream>>>(bufA, w1, b1, nullptr, bufX, L_SEQ, DFF_, CDIM);
    // 17. GroupNorm + GELU -> bufY
    gn_gelu_kernel<<<32, blk, 0, stream>>>(bufX, gn_g, gn_b, bufY);
    // 18. depthwise conv -> bufZ
    dwconv_kernel<<<(L_SEQ * DFF_ + 255) / 256, blk, 0, stream>>>(bufY, dw_k, bufZ);
    // 19. final proj + residual(tgt_b) -> out
    gemm_bias_res<<<gemmGrid256, blk, 0, stream>>>(bufZ, w2, b2, bufG, out, L_SEQ, CDIM, DFF_);
}

// Round 4
// 1162.711 us; speedup vs baseline: 1.6373x; 1.0920x over previous
//
#include <hip/hip_runtime.h>
#include <math.h>

#define L_SEQ 1600
#define CDIM 256
#define NH 8
#define HD 32
#define GRID_H 40
#define GRID_W 40
#define DFF_ 1024
#define WS_ 15
#define WIN 225
#define MAXD 7
#define SCALE_QK 0.17677669529663687f

__device__ __forceinline__ float waveReduceSum(float v) {
#pragma unroll
    for (int off = 32; off > 0; off >>= 1) v += __shfl_down(v, off, 64);
    return v;
}
__device__ __forceinline__ float waveReduceMax(float v) {
#pragma unroll
    for (int off = 32; off > 0; off >>= 1) v = fmaxf(v, __shfl_down(v, off, 64));
    return v;
}
// block of exactly 256 threads (4 waves)
__device__ __forceinline__ float blockReduceSum(float v, float* sh4) {
    v = waveReduceSum(v);
    int lane = threadIdx.x & 63, wid = threadIdx.x >> 6;
    __syncthreads();
    if (lane == 0) sh4[wid] = v;
    __syncthreads();
    return sh4[0] + sh4[1] + sh4[2] + sh4[3];
}
__device__ __forceinline__ float blockReduceMax(float v, float* sh4) {
    v = waveReduceMax(v);
    int lane = threadIdx.x & 63, wid = threadIdx.x >> 6;
    __syncthreads();
    if (lane == 0) sh4[wid] = v;
    __syncthreads();
    return fmaxf(fmaxf(sh4[0], sh4[1]), fmaxf(sh4[2], sh4[3]));
}

// LayerNorm over C=256; one block (256 thr) per row. out2 = out + addin (optional)
__global__ __launch_bounds__(256) void ln_kernel(const float* __restrict__ x,
                                                 const float* __restrict__ g,
                                                 const float* __restrict__ b,
                                                 const float* __restrict__ addin,
                                                 float* __restrict__ out,
                                                 float* __restrict__ out2) {
    __shared__ float sh4[4];
    int row = blockIdx.x;
    int c = threadIdx.x;
    float v = x[row * CDIM + c];
    float mean = blockReduceSum(v, sh4) * (1.0f / CDIM);
    float d = v - mean;
    float var = blockReduceSum(d * d, sh4) * (1.0f / CDIM);
    float y = d * rsqrtf(var + 1e-5f) * g[c] + b[c];
    out[row * CDIM + c] = y;
    if (out2) out2[row * CDIM + c] = y + addin[row * CDIM + c];
}

// C[M,N] = A[M,K] @ W[N,K]^T + bias + (res?)   all row-major f32
#define BM 64
#define BN 64
#define BK 16
__global__ __launch_bounds__(256) void gemm_bias_res(const float* __restrict__ A,
                                                     const float* __restrict__ W,
                                                     const float* __restrict__ bias,
                                                     const float* __restrict__ res,
                                                     float* __restrict__ C,
                                                     int M, int N, int K) {
    __shared__ float As[BK][BM + 1];
    __shared__ float Bs[BK][BN + 1];
    int bm = blockIdx.y * BM;
    int bn = blockIdx.x * BN;
    int tid = threadIdx.x;
    int tr = tid / 16, tc = tid % 16;
    float acc[4][4] = {};
    for (int k0 = 0; k0 < K; k0 += BK) {
        for (int i = tid; i < BM * BK; i += 256) {
            int m = i / BK, kk = i % BK;
            int gm = bm + m;
            As[kk][m] = (gm < M) ? A[gm * K + k0 + kk] : 0.f;
        }
        for (int i = tid; i < BN * BK; i += 256) {
            int n = i / BK, kk = i % BK;
            int gn = bn + n;
            Bs[kk][n] = (gn < N) ? W[gn * K + k0 + kk] : 0.f;
        }
        __syncthreads();
#pragma unroll
        for (int kk = 0; kk < BK; ++kk) {
            float a[4], bv[4];
#pragma unroll
            for (int i = 0; i < 4; i++) a[i] = As[kk][tr * 4 + i];
#pragma unroll
            for (int j = 0; j < 4; j++) bv[j] = Bs[kk][tc * 4 + j];
#pragma unroll
            for (int i = 0; i < 4; i++)
#pragma unroll
                for (int j = 0; j < 4; j++) acc[i][j] += a[i] * bv[j];
        }
        __syncthreads();
    }
#pragma unroll
    for (int i = 0; i < 4; i++) {
        int gm = bm + tr * 4 + i;
        if (gm >= M) continue;
#pragma unroll
        for (int j = 0; j < 4; j++) {
            int gn = bn + tc * 4 + j;
            if (gn >= N) continue;
            float v = acc[i][j] + (bias ? bias[gn] : 0.f);
            if (res) v += res[gm * N + gn];
            C[gm * N + gn] = v;
        }
    }
}

// ---------------------------------------------------------------------------
// Flash MHA with online softmax: one block = 8 query rows of one head.
// 256 threads (4 waves), each wave owns 2 query rows (q in registers).
// Per 128-key tile: stage K+V in LDS (swizzled), QK^T, online (m,l) update
// via wave shuffles, P-slice to 4KB wave-private LDS strip, PV accumulate in
// registers with rescale. LDS 36.9KB -> 4 blocks/CU (vs 2 before).
// ---------------------------------------------------------------------------
#define QB 8
#define TJ 128
__global__ __launch_bounds__(256) void mha_flash(const float* __restrict__ Q,
                                                 const float* __restrict__ K,
                                                 const float* __restrict__ V,
                                                 float* __restrict__ O) {
    __shared__ float4 kt[TJ][8];        // 16384 B, swizzled
    __shared__ float4 vt[TJ][8];        // 16384 B, swizzled
    __shared__ float p_lds[QB][TJ];     // 4096 B
    int h = blockIdx.y;
    int qbase = blockIdx.x * QB;
    int tid = threadIdx.x;
    int wave = tid >> 6, lane = tid & 63;
    int lq0 = 2 * wave, lq1 = lq0 + 1;
    int d4 = lane & 7, jsl = lane >> 3;

    // load + scale this wave's 2 query rows into registers
    const float4* Qr0 = (const float4*)(Q + (qbase + lq0) * CDIM + h * HD);
    const float4* Qr1 = (const float4*)(Q + (qbase + lq1) * CDIM + h * HD);
    float4 qa[8], qb[8];
#pragma unroll
    for (int c = 0; c < 8; ++c) {
        float4 a = Qr0[c], b = Qr1[c];
        a.x *= SCALE_QK; a.y *= SCALE_QK; a.z *= SCALE_QK; a.w *= SCALE_QK;
        b.x *= SCALE_QK; b.y *= SCALE_QK; b.z *= SCALE_QK; b.w *= SCALE_QK;
        qa[c] = a; qb[c] = b;
    }

    float m0 = -INFINITY, m1 = -INFINITY;
    float l0 = 0.f, l1 = 0.f;
    float4 o0 = make_float4(0.f, 0.f, 0.f, 0.f);
    float4 o1 = make_float4(0.f, 0.f, 0.f, 0.f);

    for (int t = 0; t < L_SEQ; t += TJ) {
        // ---- stage K and V tiles ----
#pragma unroll
        for (int r = 0; r < 4; ++r) {
            int idx = tid + 256 * r;          // 0..1023
            int row = idx >> 3, c = idx & 7;
            int j = t + row;
            float4 kv = make_float4(0.f, 0.f, 0.f, 0.f);
            float4 vv = make_float4(0.f, 0.f, 0.f, 0.f);
            if (j < L_SEQ) {
                kv = ((const float4*)(K + j * CDIM + h * HD))[c];
                vv = ((const float4*)(V + j * CDIM + h * HD))[c];
            }
            kt[row][c ^ (row & 7)] = kv;
            vt[row][c ^ (row & 7)] = vv;
        }
        __syncthreads();

        // ---- QK^T for this wave's 2 rows; j = t + lane + 64m ----
        float s00, s01, s10, s11;
        {
            int row = lane;
            float a0 = 0.f, a1 = 0.f;
#pragma unroll
            for (int c = 0; c < 8; ++c) {
                float4 kv = kt[row][c ^ (row & 7)];
                a0 += qa[c].x * kv.x + qa[c].y * kv.y + qa[c].z * kv.z + qa[c].w * kv.w;
                a1 += qb[c].x * kv.x + qb[c].y * kv.y + qb[c].z * kv.z + qb[c].w * kv.w;
            }
            s00 = a0; s01 = a1;
        }
        {
            int row = lane + 64;
            float a0 = 0.f, a1 = 0.f;
#pragma unroll
            for (int c = 0; c < 8; ++c) {
                float4 kv = kt[row][c ^ (row & 7)];
                a0 += qa[c].x * kv.x + qa[c].y * kv.y + qa[c].z * kv.z + qa[c].w * kv.w;
                a1 += qb[c].x * kv.x + qb[c].y * kv.y + qb[c].z * kv.z + qb[c].w * kv.w;
            }
            s10 = a0; s11 = a1;
        }
        if (t + lane >= L_SEQ)      { s00 = -1e30f; s01 = -1e30f; }
        if (t + lane + 64 >= L_SEQ) { s10 = -1e30f; s11 = -1e30f; }

        // ---- online softmax update ----
        float tm0 = fmaxf(s00, s10), tm1 = fmaxf(s01, s11);
#pragma unroll
        for (int off = 32; off > 0; off >>= 1) {
            tm0 = fmaxf(tm0, __shfl_xor(tm0, off, 64));
            tm1 = fmaxf(tm1, __shfl_xor(tm1, off, 64));
        }
        float nm0 = fmaxf(m0, tm0), nm1 = fmaxf(m1, tm1);
        float sc0 = __expf(m0 - nm0), sc1 = __expf(m1 - nm1);
        float e00 = __expf(s00 - nm0), e10 = __expf(s10 - nm0);
        float e01 = __expf(s01 - nm1), e11 = __expf(s11 - nm1);
        float ts0 = e00 + e10, ts1 = e01 + e11;
#pragma unroll
        for (int off = 32; off > 0; off >>= 1) {
            ts0 += __shfl_xor(ts0, off, 64);
            ts1 += __shfl_xor(ts1, off, 64);
        }
        l0 = l0 * sc0 + ts0;
        l1 = l1 * sc1 + ts1;
        m0 = nm0; m1 = nm1;
        o0.x *= sc0; o0.y *= sc0; o0.z *= sc0; o0.w *= sc0;
        o1.x *= sc1; o1.y *= sc1; o1.z *= sc1; o1.w *= sc1;

        // ---- write P slice (wave-private rows; no block barrier needed) ----
        p_lds[lq0][lane] = e00;
        p_lds[lq1][lane] = e01;
        p_lds[lq0][lane + 64] = e10;
        p_lds[lq1][lane + 64] = e11;

        // ---- PV accumulate ----
#pragma unroll
        for (int mm = 0; mm < 16; ++mm) {
            int row = jsl + 8 * mm;
            float4 vv = vt[row][d4 ^ (row & 7)];
            float pp0 = p_lds[lq0][row], pp1 = p_lds[lq1][row];
            o0.x += pp0 * vv.x; o0.y += pp0 * vv.y; o0.z += pp0 * vv.z; o0.w += pp0 * vv.w;
            o1.x += pp1 * vv.x; o1.y += pp1 * vv.y; o1.z += pp1 * vv.z; o1.w += pp1 * vv.w;
        }
        __syncthreads();   // before next tile's staging overwrites kt/vt
    }

    // reduce partials across jsl (lane bits 3..5)
#pragma unroll
    for (int off = 8; off < 64; off <<= 1) {
        o0.x += __shfl_xor(o0.x, off, 64);
        o0.y += __shfl_xor(o0.y, off, 64);
        o0.z += __shfl_xor(o0.z, off, 64);
        o0.w += __shfl_xor(o0.w, off, 64);
        o1.x += __shfl_xor(o1.x, off, 64);
        o1.y += __shfl_xor(o1.y, off, 64);
        o1.z += __shfl_xor(o1.z, off, 64);
        o1.w += __shfl_xor(o1.w, off, 64);
    }
    if (jsl == 0) {
        float inv0 = 1.f / l0, inv1 = 1.f / l1;
        float4 r0, r1;
        r0.x = o0.x * inv0; r0.y = o0.y * inv0; r0.z = o0.z * inv0; r0.w = o0.w * inv0;
        r1.x = o1.x * inv1; r1.y = o1.y * inv1; r1.z = o1.z * inv1; r1.w = o1.w * inv1;
        ((float4*)(O + (qbase + lq0) * CDIM + h * HD))[d4] = r0;
        ((float4*)(O + (qbase + lq1) * CDIM + h * HD))[d4] = r1;
    }
}

// Local windowed attention: one block per (position, head)
__global__ __launch_bounds__(256) void local_attn_kernel(const float* __restrict__ Q,
                                                         const float* __restrict__ K,
                                                         const float* __restrict__ V,
                                                         float* __restrict__ O) {
    __shared__ float qsh[HD];
    __shared__ float p[WIN];
    __shared__ float sh4[4];
    __shared__ float oacc[8][HD];
    int n = blockIdx.x, h = blockIdx.y, tid = threadIdx.x;
    int y = n / GRID_W, x = n % GRID_W;
    if (tid < HD) qsh[tid] = Q[n * CDIM + h * HD + tid] * SCALE_QK;
    __syncthreads();
    float lg = -INFINITY;
    if (tid < WIN) {
        int dy = tid / WS_ - MAXD, dx = tid % WS_ - MAXD;
        int yy = y + dy, xx = x + dx;
        if (yy >= 0 && yy < GRID_H && xx >= 0 && xx < GRID_W) {
            const float* kr = K + (yy * GRID_W + xx) * CDIM + h * HD;
            float s = 0.f;
#pragma unroll
            for (int d2 = 0; d2 < HD; ++d2) s += qsh[d2] * kr[d2];
            lg = s;
        } else {
            lg = -1.0e9f;
        }
    }
    float smax = blockReduceMax(lg, sh4);
    float e = 0.f;
    if (tid < WIN) {
        e = expf(lg - smax);
        p[tid] = e;
    }
    float inv = 1.0f / blockReduceSum(e, sh4);
    int d2 = tid & 31, ch = tid >> 5;
    float acc = 0.f;
    for (int w = ch; w < WIN; w += 8) {
        int dy = w / WS_ - MAXD, dx = w % WS_ - MAXD;
        int yy = y + dy, xx = x + dx;
        if (yy >= 0 && yy < GRID_H && xx >= 0 && xx < GRID_W)
            acc += p[w] * V[(yy * GRID_W + xx) * CDIM + h * HD + d2];
    }
    oacc[ch][d2] = acc;
    __syncthreads();
    if (tid < HD) {
        float s = 0.f;
#pragma unroll
        for (int i = 0; i < 8; ++i) s += oacc[i][tid];
        O[n * CDIM + h * HD + tid] = s * inv;
    }
}

// build curr_Q (contiguous), global_K, global_V from qv (1600x512) and idkv (1600x264)
__global__ __launch_bounds__(256) void make_qkv_kernel(const float* __restrict__ qv,
                                                       const float* __restrict__ idkv,
                                                       float* __restrict__ Qc,
                                                       float* __restrict__ gK,
                                                       float* __restrict__ gV) {
    int idx = blockIdx.x * 256 + threadIdx.x;
    if (idx >= L_SEQ * CDIM) return;
    int l = idx >> 8, c = idx & 255;
    int h = c >> 5;
    float q = qv[l * 512 + c];
    Qc[idx] = q;
    gK[idx] = q * (1.f + tanhf(idkv[l * 264 + h]));
    gV[idx] = qv[l * 512 + 256 + c] + idkv[l * 264 + 8 + c];
}

// GroupNorm (32 groups of 32 ch over 1600 positions) + exact GELU; X,Y are (1600,1024)
__global__ __launch_bounds__(256) void gn_gelu_kernel(const float* __restrict__ X,
                                                      const float* __restrict__ g,
                                                      const float* __restrict__ b,
                                                      float* __restrict__ Y) {
    __shared__ float sh4[4];
    int grp = blockIdx.x, tid = threadIdx.x;
    int base = grp * 32;
    float s = 0.f, s2 = 0.f;
    for (int i = tid; i < L_SEQ * 32; i += 256) {
        int l = i >> 5, c = i & 31;
        float v = X[l * DFF_ + base + c];
        s += v;
        s2 += v * v;
    }
    const float invn = 1.0f / (L_SEQ * 32);
    float mean = blockReduceSum(s, sh4) * invn;
    float ex2 = blockReduceSum(s2, sh4) * invn;
    float rs = rsqrtf(ex2 - mean * mean + 1e-5f);
    for (int i = tid; i < L_SEQ * 32; i += 256) {
        int l = i >> 5, c = i & 31;
        float v = X[l * DFF_ + base + c];
        float yv = (v - mean) * rs * g[base + c] + b[base + c];
        yv = 0.5f * yv * (1.0f + erff(yv * 0.70710678118654752f));
        Y[l * DFF_ + base + c] = yv;
    }
}

// depthwise 5x5 conv, pad 2 (cross-correlation). X,Y (1600,1024) l-major; Kw (1024,25)
__global__ __launch_bounds__(256) void dwconv_kernel(const float* __restrict__ X,
                                                     const float* __restrict__ Kw,
                                                     float* __restrict__ Y) {
    int idx = blockIdx.x * 256 + threadIdx.x;
    if (idx >= L_SEQ * DFF_) return;
    int c = idx & 1023, l = idx >> 10;
    int y = l / GRID_W, x = l % GRID_W;
    float acc = 0.f;
#pragma unroll
    for (int ky = 0; ky < 5; ++ky) {
        int yy = y + ky - 2;
        if (yy < 0 || yy >= GRID_H) continue;
#pragma unroll
        for (int kx = 0; kx < 5; ++kx) {
            int xx = x + kx - 2;
            if (xx < 0 || xx >= GRID_W) continue;
            acc += X[(yy * GRID_W + xx) * DFF_ + c] * Kw[c * 25 + ky * 5 + kx];
        }
    }
    Y[idx] = acc;
}

extern "C" void kernel_launch(void* const* d_in, const int* in_sizes, int n_in,
                              void* d_out, int out_size, void* d_ws, size_t ws_size,
                              hipStream_t stream) {
    (void)in_sizes; (void)n_in; (void)out_size; (void)ws_size;
    const float* tgt = (const float*)d_in[0];
    const float* curr_id_emb = (const float*)d_in[1];
    const float* self_pos = (const float*)d_in[2];
    const float* ln1_g = (const float*)d_in[3];
    const float* ln1_b = (const float*)d_in[4];
    const float* sa_wq = (const float*)d_in[5];
    const float* sa_bq = (const float*)d_in[6];
    const float* sa_wk = (const float*)d_in[7];
    const float* sa_bk = (const float*)d_in[8];
    const float* sa_wv = (const float*)d_in[9];
    const float* sa_bv = (const float*)d_in[10];
    const float* sa_wo = (const float*)d_in[11];
    const float* sa_bo = (const float*)d_in[12];
    const float* ln2_g = (const float*)d_in[13];
    const float* ln2_b = (const float*)d_in[14];
    const float* w_qv = (const float*)d_in[15];
    const float* b_qv = (const float*)d_in[16];
    const float* w_id = (const float*)d_in[17];
    const float* b_id = (const float*)d_in[18];
    const float* lt_wo = (const float*)d_in[19];
    const float* lt_bo = (const float*)d_in[20];
    const float* st_wo = (const float*)d_in[21];
    const float* st_bo = (const float*)d_in[22];
    const float* ln3_g = (const float*)d_in[23];
    const float* ln3_b = (const float*)d_in[24];
    const float* w1 = (const float*)d_in[25];
    const float* b1 = (const float*)d_in[26];
    const float* gn_g = (const float*)d_in[27];
    const float* gn_b = (const float*)d_in[28];
    const float* dw_k = (const float*)d_in[29];
    const float* w2 = (const float*)d_in[30];
    const float* b2 = (const float*)d_in[31];
    float* out = (float*)d_out;

    float* ws = (float*)d_ws;
    const int LC = L_SEQ * CDIM;           // 409600
    float* bufA = ws;                      // _t
    float* bufB = bufA + LC;               // qk_in / tgt1+tgt2
    float* bufC = bufB + LC;               // q_ / curr_Q
    float* bufD = bufC + LC;               // k_ / global_K
    float* bufE = bufD + LC;               // v_ / global_V
    float* bufF = bufE + LC;               // attn outs
    float* bufG = bufF + LC;               // tgt1 / tgt_b
    float* bufH = bufG + LC;               // qv (1600x512)
    float* bufI = bufH + L_SEQ * 512;      // idkv (1600x264)
    float* bufX = bufI + L_SEQ * 264;      // w1 out (1600x1024)
    float* bufY = bufX + L_SEQ * DFF_;     // gn+gelu out
    float* bufZ = bufY + L_SEQ * DFF_;     // conv out

    dim3 blk(256);
    dim3 gemmGrid256(4, 25), gemmGrid512(8, 25), gemmGrid264(5, 25), gemmGrid1024(16, 25);
    dim3 mhaGrid(L_SEQ / QB, NH);

    // 1. LN1: bufA = ln(tgt), bufB = bufA + self_pos
    ln_kernel<<<L_SEQ, blk, 0, stream>>>(tgt, ln1_g, ln1_b, self_pos, bufA, bufB);
    // 2-4. q,k,v projections
    gemm_bias_res<<<gemmGrid256, blk, 0, stream>>>(bufB, sa_wq, sa_bq, nullptr, bufC, L_SEQ, CDIM, CDIM);
    gemm_bias_res<<<gemmGrid256, blk, 0, stream>>>(bufB, sa_wk, sa_bk, nullptr, bufD, L_SEQ, CDIM, CDIM);
    gemm_bias_res<<<gemmGrid256, blk, 0, stream>>>(bufA, sa_wv, sa_bv, nullptr, bufE, L_SEQ, CDIM, CDIM);
    // 5. self attention
    mha_flash<<<mhaGrid, blk, 0, stream>>>(bufC, bufD, bufE, bufF);
    // 6. out proj + residual -> tgt1 (bufG)
    gemm_bias_res<<<gemmGrid256, blk, 0, stream>>>(bufF, sa_wo, sa_bo, tgt, bufG, L_SEQ, CDIM, CDIM);
    // 7. LN2 -> bufA
    ln_kernel<<<L_SEQ, blk, 0, stream>>>(bufG, ln2_g, ln2_b, nullptr, bufA, nullptr);
    // 8. qv = bufA @ w_qv^T -> bufH (1600x512)
    gemm_bias_res<<<gemmGrid512, blk, 0, stream>>>(bufA, w_qv, b_qv, nullptr, bufH, L_SEQ, 512, CDIM);
    // 9. idkv = curr_id_emb @ w_id^T -> bufI (1600x264)
    gemm_bias_res<<<gemmGrid264, blk, 0, stream>>>(curr_id_emb, w_id, b_id, nullptr, bufI, L_SEQ, 264, CDIM);
    // 10. curr_Q (bufC), global_K (bufD), global_V (bufE)
    make_qkv_kernel<<<L_SEQ, blk, 0, stream>>>(bufH, bufI, bufC, bufD, bufE);
    // 11. long-term attention
    mha_flash<<<mhaGrid, blk, 0, stream>>>(bufC, bufD, bufE, bufF);
    // 12. lt out proj + residual(tgt1) -> bufB
    gemm_bias_res<<<gemmGrid256, blk, 0, stream>>>(bufF, lt_wo, lt_bo, bufG, bufB, L_SEQ, CDIM, CDIM);
    // 13. local attention -> bufF
    local_attn_kernel<<<dim3(L_SEQ, NH), blk, 0, stream>>>(bufC, bufD, bufE, bufF);
    // 14. st out proj + residual(bufB) -> tgt_b (bufG)
    gemm_bias_res<<<gemmGrid256, blk, 0, stream>>>(bufF, st_wo, st_bo, bufB, bufG, L_SEQ, CDIM, CDIM);
    // 15. LN3 -> bufA
    ln_kernel<<<L_SEQ, blk, 0, stream>>>(bufG, ln3_g, ln3_b, nullptr, bufA, nullptr);
    // 16. x = bufA @ w1^T -> bufX (1600x1024)
    gemm_bias_res<<<gemmGrid1024, blk, 0, stream>>>(bufA, w1, b1, nullptr, bufX, L_SEQ, DFF_, CDIM);
    // 17. GroupNorm + GELU -> bufY
    gn_gelu_kernel<<<32, blk, 0, stream>>>(bufX, gn_g, gn_b, bufY);
    // 18. depthwise conv -> bufZ
    dwconv_kernel<<<(L_SEQ * DFF_ + 255) / 256, blk, 0, stream>>>(bufY, dw_k, bufZ);
    // 19. final proj + residual(tgt_b) -> out
    gemm_bias_res<<<gemmGrid256, blk, 0, stream>>>(bufZ, w2, b2, bufG, out, L_SEQ, CDIM, DFF_);
}

// Round 5
// 662.813 us; speedup vs baseline: 2.8721x; 1.7542x over previous
//
#include <hip/hip_runtime.h>
#include <math.h>

#define L_SEQ 1600
#define CDIM 256
#define NH 8
#define HD 32
#define GRID_H 40
#define GRID_W 40
#define DFF_ 1024
#define WS_ 15
#define WIN 225
#define MAXD 7
#define SCALE_QK 0.17677669529663687f

typedef __attribute__((ext_vector_type(8))) short short8;
typedef __attribute__((ext_vector_type(4))) float f32x4;

__device__ __forceinline__ float waveReduceSum(float v) {
#pragma unroll
    for (int off = 32; off > 0; off >>= 1) v += __shfl_down(v, off, 64);
    return v;
}
__device__ __forceinline__ float waveReduceMax(float v) {
#pragma unroll
    for (int off = 32; off > 0; off >>= 1) v = fmaxf(v, __shfl_down(v, off, 64));
    return v;
}
// block of exactly 256 threads (4 waves)
__device__ __forceinline__ float blockReduceSum(float v, float* sh4) {
    v = waveReduceSum(v);
    int lane = threadIdx.x & 63, wid = threadIdx.x >> 6;
    __syncthreads();
    if (lane == 0) sh4[wid] = v;
    __syncthreads();
    return sh4[0] + sh4[1] + sh4[2] + sh4[3];
}
__device__ __forceinline__ float blockReduceMax(float v, float* sh4) {
    v = waveReduceMax(v);
    int lane = threadIdx.x & 63, wid = threadIdx.x >> 6;
    __syncthreads();
    if (lane == 0) sh4[wid] = v;
    __syncthreads();
    return fmaxf(fmaxf(sh4[0], sh4[1]), fmaxf(sh4[2], sh4[3]));
}

__device__ __forceinline__ unsigned short f2bf(float x) {
    union { float f; unsigned u; } v; v.f = x;
    unsigned r = (v.u + 0x7FFFu + ((v.u >> 16) & 1u)) >> 16;
    return (unsigned short)r;
}

// LayerNorm over C=256; one block (256 thr) per row. out2 = out + addin (optional)
__global__ __launch_bounds__(256) void ln_kernel(const float* __restrict__ x,
                                                 const float* __restrict__ g,
                                                 const float* __restrict__ b,
                                                 const float* __restrict__ addin,
                                                 float* __restrict__ out,
                                                 float* __restrict__ out2) {
    __shared__ float sh4[4];
    int row = blockIdx.x;
    int c = threadIdx.x;
    float v = x[row * CDIM + c];
    float mean = blockReduceSum(v, sh4) * (1.0f / CDIM);
    float d = v - mean;
    float var = blockReduceSum(d * d, sh4) * (1.0f / CDIM);
    float y = d * rsqrtf(var + 1e-5f) * g[c] + b[c];
    out[row * CDIM + c] = y;
    if (out2) out2[row * CDIM + c] = y + addin[row * CDIM + c];
}

// ---------------------------------------------------------------------------
// bf16 MFMA GEMM: C[M,N] = A[M,K] @ W[N,K]^T + bias + (res?)
// 64x64 block tile, 4 waves (2x2), each wave 32x32 via 2x2 mfma_16x16x32_bf16.
// LDS in fragment order [frag][lane][8] -> ds_read_b128 conflict-free.
// Double-buffered, reg-staged f32->bf16 (RNE). Requires M%64==0, K%32==0;
// N guarded (handles N=264).
// ---------------------------------------------------------------------------
__global__ __launch_bounds__(256) void gemm_mfma(const float* __restrict__ A,
                                                 const float* __restrict__ W,
                                                 const float* __restrict__ bias,
                                                 const float* __restrict__ res,
                                                 float* __restrict__ C,
                                                 int M, int N, int K) {
    __shared__ unsigned short Al[2][4][64][8];   // 8KB
    __shared__ unsigned short Bl[2][4][64][8];   // 8KB
    int tid = threadIdx.x;
    int bm = blockIdx.y * 64, bn = blockIdx.x * 64;
    int lane = tid & 63, wave = tid >> 6;
    int wr = wave >> 1, wc = wave & 1;

    int srow = tid >> 3;        // 0..31 (pass adds +32)
    int q = tid & 7;            // which float4 along the 32-k tile
    int sfrag0 = srow >> 4, sl0 = (srow & 15) + 16 * (q >> 1);
    int e0 = (q & 1) * 4;

    f32x4 acc[2][2] = {};
    int nsteps = K >> 5;

    float4 ra[2], rb[2];
    // ---- prologue: load + write step 0 ----
    {
        int k0 = 0;
#pragma unroll
        for (int r = 0; r < 2; ++r) {
            int row = srow + 32 * r;
            ra[r] = *(const float4*)(A + (bm + row) * K + k0 + 4 * q);
            int n = bn + row;
            rb[r] = (n < N) ? *(const float4*)(W + n * K + k0 + 4 * q)
                            : make_float4(0.f, 0.f, 0.f, 0.f);
        }
#pragma unroll
        for (int r = 0; r < 2; ++r) {
            int row = srow + 32 * r;
            int frag = (row >> 4), l = (row & 15) + 16 * (q >> 1);
            unsigned pa0 = ((unsigned)f2bf(ra[r].x)) | (((unsigned)f2bf(ra[r].y)) << 16);
            unsigned pa1 = ((unsigned)f2bf(ra[r].z)) | (((unsigned)f2bf(ra[r].w)) << 16);
            unsigned pb0 = ((unsigned)f2bf(rb[r].x)) | (((unsigned)f2bf(rb[r].y)) << 16);
            unsigned pb1 = ((unsigned)f2bf(rb[r].z)) | (((unsigned)f2bf(rb[r].w)) << 16);
            *(uint2*)&Al[0][frag][l][e0] = make_uint2(pa0, pa1);
            *(uint2*)&Bl[0][frag][l][e0] = make_uint2(pb0, pb1);
        }
    }
    __syncthreads();

    for (int s = 0; s < nsteps; ++s) {
        bool more = (s + 1) < nsteps;
        if (more) {
            int k0 = (s + 1) << 5;
#pragma unroll
            for (int r = 0; r < 2; ++r) {
                int row = srow + 32 * r;
                ra[r] = *(const float4*)(A + (bm + row) * K + k0 + 4 * q);
                int n = bn + row;
                rb[r] = (n < N) ? *(const float4*)(W + n * K + k0 + 4 * q)
                                : make_float4(0.f, 0.f, 0.f, 0.f);
            }
        }
        // ---- compute on buffer s&1 ----
        {
            int buf = s & 1;
            short8 af[2], bfr[2];
#pragma unroll
            for (int i = 0; i < 2; ++i) {
                af[i] = *(const short8*)&Al[buf][2 * wr + i][lane][0];
                bfr[i] = *(const short8*)&Bl[buf][2 * wc + i][lane][0];
            }
#pragma unroll
            for (int i = 0; i < 2; ++i)
#pragma unroll
                for (int j = 0; j < 2; ++j)
                    acc[i][j] = __builtin_amdgcn_mfma_f32_16x16x32_bf16(af[i], bfr[j], acc[i][j], 0, 0, 0);
        }
        if (more) {
            int buf = (s + 1) & 1;
#pragma unroll
            for (int r = 0; r < 2; ++r) {
                int row = srow + 32 * r;
                int frag = (row >> 4), l = (row & 15) + 16 * (q >> 1);
                unsigned pa0 = ((unsigned)f2bf(ra[r].x)) | (((unsigned)f2bf(ra[r].y)) << 16);
                unsigned pa1 = ((unsigned)f2bf(ra[r].z)) | (((unsigned)f2bf(ra[r].w)) << 16);
                unsigned pb0 = ((unsigned)f2bf(rb[r].x)) | (((unsigned)f2bf(rb[r].y)) << 16);
                unsigned pb1 = ((unsigned)f2bf(rb[r].z)) | (((unsigned)f2bf(rb[r].w)) << 16);
                *(uint2*)&Al[buf][frag][l][e0] = make_uint2(pa0, pa1);
                *(uint2*)&Bl[buf][frag][l][e0] = make_uint2(pb0, pb1);
            }
        }
        __syncthreads();
    }

    // ---- epilogue: C/D layout col=lane&15, row=(lane>>4)*4+reg ----
#pragma unroll
    for (int j = 0; j < 2; ++j) {
        int col = bn + wc * 32 + j * 16 + (lane & 15);
        if (col >= N) continue;
        float bv = bias ? bias[col] : 0.f;
#pragma unroll
        for (int i = 0; i < 2; ++i) {
            int rbase = bm + wr * 32 + i * 16 + ((lane >> 4) << 2);
#pragma unroll
            for (int r = 0; r < 4; ++r) {
                int row = rbase + r;
                float v = acc[i][j][r] + bv;
                if (res) v += res[row * N + col];
                C[row * N + col] = v;
            }
        }
    }
    (void)M;
}

// ---------------------------------------------------------------------------
// Flash MHA with online softmax (unchanged from round 4)
// ---------------------------------------------------------------------------
#define QB 8
#define TJ 128
__global__ __launch_bounds__(256) void mha_flash(const float* __restrict__ Q,
                                                 const float* __restrict__ K,
                                                 const float* __restrict__ V,
                                                 float* __restrict__ O) {
    __shared__ float4 kt[TJ][8];        // 16384 B, swizzled
    __shared__ float4 vt[TJ][8];        // 16384 B, swizzled
    __shared__ float p_lds[QB][TJ];     // 4096 B
    int h = blockIdx.y;
    int qbase = blockIdx.x * QB;
    int tid = threadIdx.x;
    int wave = tid >> 6, lane = tid & 63;
    int lq0 = 2 * wave, lq1 = lq0 + 1;
    int d4 = lane & 7, jsl = lane >> 3;

    const float4* Qr0 = (const float4*)(Q + (qbase + lq0) * CDIM + h * HD);
    const float4* Qr1 = (const float4*)(Q + (qbase + lq1) * CDIM + h * HD);
    float4 qa[8], qb[8];
#pragma unroll
    for (int c = 0; c < 8; ++c) {
        float4 a = Qr0[c], b = Qr1[c];
        a.x *= SCALE_QK; a.y *= SCALE_QK; a.z *= SCALE_QK; a.w *= SCALE_QK;
        b.x *= SCALE_QK; b.y *= SCALE_QK; b.z *= SCALE_QK; b.w *= SCALE_QK;
        qa[c] = a; qb[c] = b;
    }

    float m0 = -INFINITY, m1 = -INFINITY;
    float l0 = 0.f, l1 = 0.f;
    float4 o0 = make_float4(0.f, 0.f, 0.f, 0.f);
    float4 o1 = make_float4(0.f, 0.f, 0.f, 0.f);

    for (int t = 0; t < L_SEQ; t += TJ) {
#pragma unroll
        for (int r = 0; r < 4; ++r) {
            int idx = tid + 256 * r;
            int row = idx >> 3, c = idx & 7;
            int j = t + row;
            float4 kv = make_float4(0.f, 0.f, 0.f, 0.f);
            float4 vv = make_float4(0.f, 0.f, 0.f, 0.f);
            if (j < L_SEQ) {
                kv = ((const float4*)(K + j * CDIM + h * HD))[c];
                vv = ((const float4*)(V + j * CDIM + h * HD))[c];
            }
            kt[row][c ^ (row & 7)] = kv;
            vt[row][c ^ (row & 7)] = vv;
        }
        __syncthreads();

        float s00, s01, s10, s11;
        {
            int row = lane;
            float a0 = 0.f, a1 = 0.f;
#pragma unroll
            for (int c = 0; c < 8; ++c) {
                float4 kv = kt[row][c ^ (row & 7)];
                a0 += qa[c].x * kv.x + qa[c].y * kv.y + qa[c].z * kv.z + qa[c].w * kv.w;
                a1 += qb[c].x * kv.x + qb[c].y * kv.y + qb[c].z * kv.z + qb[c].w * kv.w;
            }
            s00 = a0; s01 = a1;
        }
        {
            int row = lane + 64;
            float a0 = 0.f, a1 = 0.f;
#pragma unroll
            for (int c = 0; c < 8; ++c) {
                float4 kv = kt[row][c ^ (row & 7)];
                a0 += qa[c].x * kv.x + qa[c].y * kv.y + qa[c].z * kv.z + qa[c].w * kv.w;
                a1 += qb[c].x * kv.x + qb[c].y * kv.y + qb[c].z * kv.z + qb[c].w * kv.w;
            }
            s10 = a0; s11 = a1;
        }
        if (t + lane >= L_SEQ)      { s00 = -1e30f; s01 = -1e30f; }
        if (t + lane + 64 >= L_SEQ) { s10 = -1e30f; s11 = -1e30f; }

        float tm0 = fmaxf(s00, s10), tm1 = fmaxf(s01, s11);
#pragma unroll
        for (int off = 32; off > 0; off >>= 1) {
            tm0 = fmaxf(tm0, __shfl_xor(tm0, off, 64));
            tm1 = fmaxf(tm1, __shfl_xor(tm1, off, 64));
        }
        float nm0 = fmaxf(m0, tm0), nm1 = fmaxf(m1, tm1);
        float sc0 = __expf(m0 - nm0), sc1 = __expf(m1 - nm1);
        float e00 = __expf(s00 - nm0), e10 = __expf(s10 - nm0);
        float e01 = __expf(s01 - nm1), e11 = __expf(s11 - nm1);
        float ts0 = e00 + e10, ts1 = e01 + e11;
#pragma unroll
        for (int off = 32; off > 0; off >>= 1) {
            ts0 += __shfl_xor(ts0, off, 64);
            ts1 += __shfl_xor(ts1, off, 64);
        }
        l0 = l0 * sc0 + ts0;
        l1 = l1 * sc1 + ts1;
        m0 = nm0; m1 = nm1;
        o0.x *= sc0; o0.y *= sc0; o0.z *= sc0; o0.w *= sc0;
        o1.x *= sc1; o1.y *= sc1; o1.z *= sc1; o1.w *= sc1;

        p_lds[lq0][lane] = e00;
        p_lds[lq1][lane] = e01;
        p_lds[lq0][lane + 64] = e10;
        p_lds[lq1][lane + 64] = e11;

#pragma unroll
        for (int mm = 0; mm < 16; ++mm) {
            int row = jsl + 8 * mm;
            float4 vv = vt[row][d4 ^ (row & 7)];
            float pp0 = p_lds[lq0][row], pp1 = p_lds[lq1][row];
            o0.x += pp0 * vv.x; o0.y += pp0 * vv.y; o0.z += pp0 * vv.z; o0.w += pp0 * vv.w;
            o1.x += pp1 * vv.x; o1.y += pp1 * vv.y; o1.z += pp1 * vv.z; o1.w += pp1 * vv.w;
        }
        __syncthreads();
    }

#pragma unroll
    for (int off = 8; off < 64; off <<= 1) {
        o0.x += __shfl_xor(o0.x, off, 64);
        o0.y += __shfl_xor(o0.y, off, 64);
        o0.z += __shfl_xor(o0.z, off, 64);
        o0.w += __shfl_xor(o0.w, off, 64);
        o1.x += __shfl_xor(o1.x, off, 64);
        o1.y += __shfl_xor(o1.y, off, 64);
        o1.z += __shfl_xor(o1.z, off, 64);
        o1.w += __shfl_xor(o1.w, off, 64);
    }
    if (jsl == 0) {
        float inv0 = 1.f / l0, inv1 = 1.f / l1;
        float4 r0, r1;
        r0.x = o0.x * inv0; r0.y = o0.y * inv0; r0.z = o0.z * inv0; r0.w = o0.w * inv0;
        r1.x = o1.x * inv1; r1.y = o1.y * inv1; r1.z = o1.z * inv1; r1.w = o1.w * inv1;
        ((float4*)(O + (qbase + lq0) * CDIM + h * HD))[d4] = r0;
        ((float4*)(O + (qbase + lq1) * CDIM + h * HD))[d4] = r1;
    }
}

// Local windowed attention: one block per (position, head)
__global__ __launch_bounds__(256) void local_attn_kernel(const float* __restrict__ Q,
                                                         const float* __restrict__ K,
                                                         const float* __restrict__ V,
                                                         float* __restrict__ O) {
    __shared__ float qsh[HD];
    __shared__ float p[WIN];
    __shared__ float sh4[4];
    __shared__ float oacc[8][HD];
    int n = blockIdx.x, h = blockIdx.y, tid = threadIdx.x;
    int y = n / GRID_W, x = n % GRID_W;
    if (tid < HD) qsh[tid] = Q[n * CDIM + h * HD + tid] * SCALE_QK;
    __syncthreads();
    float lg = -INFINITY;
    if (tid < WIN) {
        int dy = tid / WS_ - MAXD, dx = tid % WS_ - MAXD;
        int yy = y + dy, xx = x + dx;
        if (yy >= 0 && yy < GRID_H && xx >= 0 && xx < GRID_W) {
            const float* kr = K + (yy * GRID_W + xx) * CDIM + h * HD;
            float s = 0.f;
#pragma unroll
            for (int d2 = 0; d2 < HD; ++d2) s += qsh[d2] * kr[d2];
            lg = s;
        } else {
            lg = -1.0e9f;
        }
    }
    float smax = blockReduceMax(lg, sh4);
    float e = 0.f;
    if (tid < WIN) {
        e = expf(lg - smax);
        p[tid] = e;
    }
    float inv = 1.0f / blockReduceSum(e, sh4);
    int d2 = tid & 31, ch = tid >> 5;
    float acc = 0.f;
    for (int w = ch; w < WIN; w += 8) {
        int dy = w / WS_ - MAXD, dx = w % WS_ - MAXD;
        int yy = y + dy, xx = x + dx;
        if (yy >= 0 && yy < GRID_H && xx >= 0 && xx < GRID_W)
            acc += p[w] * V[(yy * GRID_W + xx) * CDIM + h * HD + d2];
    }
    oacc[ch][d2] = acc;
    __syncthreads();
    if (tid < HD) {
        float s = 0.f;
#pragma unroll
        for (int i = 0; i < 8; ++i) s += oacc[i][tid];
        O[n * CDIM + h * HD + tid] = s * inv;
    }
}

// build curr_Q (contiguous), global_K, global_V from qv (1600x512) and idkv (1600x264)
__global__ __launch_bounds__(256) void make_qkv_kernel(const float* __restrict__ qv,
                                                       const float* __restrict__ idkv,
                                                       float* __restrict__ Qc,
                                                       float* __restrict__ gK,
                                                       float* __restrict__ gV) {
    int idx = blockIdx.x * 256 + threadIdx.x;
    if (idx >= L_SEQ * CDIM) return;
    int l = idx >> 8, c = idx & 255;
    int h = c >> 5;
    float q = qv[l * 512 + c];
    Qc[idx] = q;
    gK[idx] = q * (1.f + tanhf(idkv[l * 264 + h]));
    gV[idx] = qv[l * 512 + 256 + c] + idkv[l * 264 + 8 + c];
}

// GroupNorm partials: grid (32 groups, 8 chunks); deterministic partial sums.
__global__ __launch_bounds__(256) void gn_partial(const float* __restrict__ X,
                                                  float* __restrict__ gstat) {
    __shared__ float sh4[4];
    int g = blockIdx.x, chunk = blockIdx.y;
    int base = g * 32;
    float s = 0.f, s2 = 0.f;
    for (int i = threadIdx.x; i < 200 * 32; i += 256) {
        int l = chunk * 200 + (i >> 5), c = i & 31;
        float v = X[l * DFF_ + base + c];
        s += v;
        s2 += v * v;
    }
    s = blockReduceSum(s, sh4);
    s2 = blockReduceSum(s2, sh4);
    if (threadIdx.x == 0) {
        gstat[g * 8 + chunk] = s;
        gstat[256 + g * 8 + chunk] = s2;
    }
}

// GroupNorm apply + exact GELU, float4-vectorized. 1600 blocks x 256 thr.
__global__ __launch_bounds__(256) void gn_apply(const float* __restrict__ X,
                                                const float* __restrict__ gstat,
                                                const float* __restrict__ g,
                                                const float* __restrict__ b,
                                                float* __restrict__ Y) {
    int idx = blockIdx.x * 256 + threadIdx.x;
    int e4 = idx * 4;
    int c = e4 & 1023;
    int grp = c >> 5;
    float s = 0.f, s2 = 0.f;
#pragma unroll
    for (int i = 0; i < 8; ++i) {
        s += gstat[grp * 8 + i];
        s2 += gstat[256 + grp * 8 + i];
    }
    const float invn = 1.0f / 51200.f;
    float mean = s * invn;
    float rs = rsqrtf(s2 * invn - mean * mean + 1e-5f);
    float4 v = *(const float4*)(X + e4);
    float4 gg = *(const float4*)(g + c);
    float4 bb = *(const float4*)(b + c);
    float4 r;
    float y0 = (v.x - mean) * rs * gg.x + bb.x;
    float y1 = (v.y - mean) * rs * gg.y + bb.y;
    float y2 = (v.z - mean) * rs * gg.z + bb.z;
    float y3 = (v.w - mean) * rs * gg.w + bb.w;
    r.x = 0.5f * y0 * (1.0f + erff(y0 * 0.70710678118654752f));
    r.y = 0.5f * y1 * (1.0f + erff(y1 * 0.70710678118654752f));
    r.z = 0.5f * y2 * (1.0f + erff(y2 * 0.70710678118654752f));
    r.w = 0.5f * y3 * (1.0f + erff(y3 * 0.70710678118654752f));
    *(float4*)(Y + e4) = r;
}

// depthwise 5x5 conv, pad 2 (cross-correlation). X,Y (1600,1024) l-major; Kw (1024,25)
__global__ __launch_bounds__(256) void dwconv_kernel(const float* __restrict__ X,
                                                     const float* __restrict__ Kw,
                                                     float* __restrict__ Y) {
    int idx = blockIdx.x * 256 + threadIdx.x;
    if (idx >= L_SEQ * DFF_) return;
    int c = idx & 1023, l = idx >> 10;
    int y = l / GRID_W, x = l % GRID_W;
    float acc = 0.f;
#pragma unroll
    for (int ky = 0; ky < 5; ++ky) {
        int yy = y + ky - 2;
        if (yy < 0 || yy >= GRID_H) continue;
#pragma unroll
        for (int kx = 0; kx < 5; ++kx) {
            int xx = x + kx - 2;
            if (xx < 0 || xx >= GRID_W) continue;
            acc += X[(yy * GRID_W + xx) * DFF_ + c] * Kw[c * 25 + ky * 5 + kx];
        }
    }
    Y[idx] = acc;
}

extern "C" void kernel_launch(void* const* d_in, const int* in_sizes, int n_in,
                              void* d_out, int out_size, void* d_ws, size_t ws_size,
                              hipStream_t stream) {
    (void)in_sizes; (void)n_in; (void)out_size; (void)ws_size;
    const float* tgt = (const float*)d_in[0];
    const float* curr_id_emb = (const float*)d_in[1];
    const float* self_pos = (const float*)d_in[2];
    const float* ln1_g = (const float*)d_in[3];
    const float* ln1_b = (const float*)d_in[4];
    const float* sa_wq = (const float*)d_in[5];
    const float* sa_bq = (const float*)d_in[6];
    const float* sa_wk = (const float*)d_in[7];
    const float* sa_bk = (const float*)d_in[8];
    const float* sa_wv = (const float*)d_in[9];
    const float* sa_bv = (const float*)d_in[10];
    const float* sa_wo = (const float*)d_in[11];
    const float* sa_bo = (const float*)d_in[12];
    const float* ln2_g = (const float*)d_in[13];
    const float* ln2_b = (const float*)d_in[14];
    const float* w_qv = (const float*)d_in[15];
    const float* b_qv = (const float*)d_in[16];
    const float* w_id = (const float*)d_in[17];
    const float* b_id = (const float*)d_in[18];
    const float* lt_wo = (const float*)d_in[19];
    const float* lt_bo = (const float*)d_in[20];
    const float* st_wo = (const float*)d_in[21];
    const float* st_bo = (const float*)d_in[22];
    const float* ln3_g = (const float*)d_in[23];
    const float* ln3_b = (const float*)d_in[24];
    const float* w1 = (const float*)d_in[25];
    const float* b1 = (const float*)d_in[26];
    const float* gn_g = (const float*)d_in[27];
    const float* gn_b = (const float*)d_in[28];
    const float* dw_k = (const float*)d_in[29];
    const float* w2 = (const float*)d_in[30];
    const float* b2 = (const float*)d_in[31];
    float* out = (float*)d_out;

    float* ws = (float*)d_ws;
    const int LC = L_SEQ * CDIM;           // 409600
    float* bufA = ws;                      // _t
    float* bufB = bufA + LC;               // qk_in / tgt1+tgt2
    float* bufC = bufB + LC;               // q_ / curr_Q
    float* bufD = bufC + LC;               // k_ / global_K
    float* bufE = bufD + LC;               // v_ / global_V
    float* bufF = bufE + LC;               // attn outs
    float* bufG = bufF + LC;               // tgt1 / tgt_b
    float* bufH = bufG + LC;               // qv (1600x512); later: gstat (512 floats)
    float* bufI = bufH + L_SEQ * 512;      // idkv (1600x264)
    float* bufX = bufI + L_SEQ * 264;      // w1 out (1600x1024)
    float* bufY = bufX + L_SEQ * DFF_;     // gn+gelu out
    float* bufZ = bufY + L_SEQ * DFF_;     // conv out

    dim3 blk(256);
    dim3 g256(4, 25), g264(5, 25), g512(8, 25), g1024(16, 25);
    dim3 mhaGrid(L_SEQ / QB, NH);

    // 1. LN1: bufA = ln(tgt), bufB = bufA + self_pos
    ln_kernel<<<L_SEQ, blk, 0, stream>>>(tgt, ln1_g, ln1_b, self_pos, bufA, bufB);
    // 2-4. q,k,v projections
    gemm_mfma<<<g256, blk, 0, stream>>>(bufB, sa_wq, sa_bq, nullptr, bufC, L_SEQ, CDIM, CDIM);
    gemm_mfma<<<g256, blk, 0, stream>>>(bufB, sa_wk, sa_bk, nullptr, bufD, L_SEQ, CDIM, CDIM);
    gemm_mfma<<<g256, blk, 0, stream>>>(bufA, sa_wv, sa_bv, nullptr, bufE, L_SEQ, CDIM, CDIM);
    // 5. self attention
    mha_flash<<<mhaGrid, blk, 0, stream>>>(bufC, bufD, bufE, bufF);
    // 6. out proj + residual -> tgt1 (bufG)
    gemm_mfma<<<g256, blk, 0, stream>>>(bufF, sa_wo, sa_bo, tgt, bufG, L_SEQ, CDIM, CDIM);
    // 7. LN2 -> bufA
    ln_kernel<<<L_SEQ, blk, 0, stream>>>(bufG, ln2_g, ln2_b, nullptr, bufA, nullptr);
    // 8. qv = bufA @ w_qv^T -> bufH (1600x512)
    gemm_mfma<<<g512, blk, 0, stream>>>(bufA, w_qv, b_qv, nullptr, bufH, L_SEQ, 512, CDIM);
    // 9. idkv = curr_id_emb @ w_id^T -> bufI (1600x264)
    gemm_mfma<<<g264, blk, 0, stream>>>(curr_id_emb, w_id, b_id, nullptr, bufI, L_SEQ, 264, CDIM);
    // 10. curr_Q (bufC), global_K (bufD), global_V (bufE)
    make_qkv_kernel<<<L_SEQ, blk, 0, stream>>>(bufH, bufI, bufC, bufD, bufE);
    // 11. long-term attention
    mha_flash<<<mhaGrid, blk, 0, stream>>>(bufC, bufD, bufE, bufF);
    // 12. lt out proj + residual(tgt1) -> bufB
    gemm_mfma<<<g256, blk, 0, stream>>>(bufF, lt_wo, lt_bo, bufG, bufB, L_SEQ, CDIM, CDIM);
    // 13. local attention -> bufF
    local_attn_kernel<<<dim3(L_SEQ, NH), blk, 0, stream>>>(bufC, bufD, bufE, bufF);
    // 14. st out proj + residual(bufB) -> tgt_b (bufG)
    gemm_mfma<<<g256, blk, 0, stream>>>(bufF, st_wo, st_bo, bufB, bufG, L_SEQ, CDIM, CDIM);
    // 15. LN3 -> bufA
    ln_kernel<<<L_SEQ, blk, 0, stream>>>(bufG, ln3_g, ln3_b, nullptr, bufA, nullptr);
    // 16. x = bufA @ w1^T -> bufX (1600x1024)
    gemm_mfma<<<g1024, blk, 0, stream>>>(bufA, w1, b1, nullptr, bufX, L_SEQ, DFF_, CDIM);
    // 17. GroupNorm + GELU -> bufY  (bufH is dead; reuse as gstat)
    gn_partial<<<dim3(32, 8), blk, 0, stream>>>(bufX, bufH);
    gn_apply<<<L_SEQ, blk, 0, stream>>>(bufX, bufH, gn_g, gn_b, bufY);
    // 18. depthwise conv -> bufZ
    dwconv_kernel<<<(L_SEQ * DFF_ + 255) / 256, blk, 0, stream>>>(bufY, dw_k, bufZ);
    // 19. final proj + residual(tgt_b) -> out
    gemm_mfma<<<g256, blk, 0, stream>>>(bufZ, w2, b2, bufG, out, L_SEQ, CDIM, DFF_);
}

// Round 6
// 464.713 us; speedup vs baseline: 4.0965x; 1.4263x over previous
//
#include <hip/hip_runtime.h>
#include <math.h>

#define L_SEQ 1600
#define CDIM 256
#define NH 8
#define HD 32
#define GRID_H 40
#define GRID_W 40
#define DFF_ 1024
#define WS_ 15
#define WIN 225
#define MAXD 7
#define SCALE_QK 0.17677669529663687f

typedef __attribute__((ext_vector_type(8))) short short8;
typedef __attribute__((ext_vector_type(4))) float f32x4;

__device__ __forceinline__ float waveReduceSum(float v) {
#pragma unroll
    for (int off = 32; off > 0; off >>= 1) v += __shfl_down(v, off, 64);
    return v;
}
__device__ __forceinline__ float waveReduceMax(float v) {
#pragma unroll
    for (int off = 32; off > 0; off >>= 1) v = fmaxf(v, __shfl_down(v, off, 64));
    return v;
}
// block of exactly 256 threads (4 waves)
__device__ __forceinline__ float blockReduceSum(float v, float* sh4) {
    v = waveReduceSum(v);
    int lane = threadIdx.x & 63, wid = threadIdx.x >> 6;
    __syncthreads();
    if (lane == 0) sh4[wid] = v;
    __syncthreads();
    return sh4[0] + sh4[1] + sh4[2] + sh4[3];
}
__device__ __forceinline__ float blockReduceMax(float v, float* sh4) {
    v = waveReduceMax(v);
    int lane = threadIdx.x & 63, wid = threadIdx.x >> 6;
    __syncthreads();
    if (lane == 0) sh4[wid] = v;
    __syncthreads();
    return fmaxf(fmaxf(sh4[0], sh4[1]), fmaxf(sh4[2], sh4[3]));
}

__device__ __forceinline__ unsigned short f2bf(float x) {
    union { float f; unsigned u; } v; v.f = x;
    unsigned r = (v.u + 0x7FFFu + ((v.u >> 16) & 1u)) >> 16;
    return (unsigned short)r;
}
__device__ __forceinline__ unsigned pkbf(float lo, float hi) {
    return (unsigned)f2bf(lo) | ((unsigned)f2bf(hi) << 16);
}

// LayerNorm over C=256; one block (256 thr) per row. out2 = out + addin (optional)
__global__ __launch_bounds__(256) void ln_kernel(const float* __restrict__ x,
                                                 const float* __restrict__ g,
                                                 const float* __restrict__ b,
                                                 const float* __restrict__ addin,
                                                 float* __restrict__ out,
                                                 float* __restrict__ out2) {
    __shared__ float sh4[4];
    int row = blockIdx.x;
    int c = threadIdx.x;
    float v = x[row * CDIM + c];
    float mean = blockReduceSum(v, sh4) * (1.0f / CDIM);
    float d = v - mean;
    float var = blockReduceSum(d * d, sh4) * (1.0f / CDIM);
    float y = d * rsqrtf(var + 1e-5f) * g[c] + b[c];
    out[row * CDIM + c] = y;
    if (out2) out2[row * CDIM + c] = y + addin[row * CDIM + c];
}

// ---------------------------------------------------------------------------
// bf16 MFMA GEMM (unchanged from round 5, verified working)
// ---------------------------------------------------------------------------
__global__ __launch_bounds__(256) void gemm_mfma(const float* __restrict__ A,
                                                 const float* __restrict__ W,
                                                 const float* __restrict__ bias,
                                                 const float* __restrict__ res,
                                                 float* __restrict__ C,
                                                 int M, int N, int K) {
    __shared__ unsigned short Al[2][4][64][8];   // 8KB
    __shared__ unsigned short Bl[2][4][64][8];   // 8KB
    int tid = threadIdx.x;
    int bm = blockIdx.y * 64, bn = blockIdx.x * 64;
    int lane = tid & 63, wave = tid >> 6;
    int wr = wave >> 1, wc = wave & 1;

    int srow = tid >> 3;
    int q = tid & 7;
    int e0 = (q & 1) * 4;

    f32x4 acc[2][2] = {};
    int nsteps = K >> 5;

    float4 ra[2], rb[2];
    {
        int k0 = 0;
#pragma unroll
        for (int r = 0; r < 2; ++r) {
            int row = srow + 32 * r;
            ra[r] = *(const float4*)(A + (bm + row) * K + k0 + 4 * q);
            int n = bn + row;
            rb[r] = (n < N) ? *(const float4*)(W + n * K + k0 + 4 * q)
                            : make_float4(0.f, 0.f, 0.f, 0.f);
        }
#pragma unroll
        for (int r = 0; r < 2; ++r) {
            int row = srow + 32 * r;
            int frag = (row >> 4), l = (row & 15) + 16 * (q >> 1);
            unsigned pa0 = ((unsigned)f2bf(ra[r].x)) | (((unsigned)f2bf(ra[r].y)) << 16);
            unsigned pa1 = ((unsigned)f2bf(ra[r].z)) | (((unsigned)f2bf(ra[r].w)) << 16);
            unsigned pb0 = ((unsigned)f2bf(rb[r].x)) | (((unsigned)f2bf(rb[r].y)) << 16);
            unsigned pb1 = ((unsigned)f2bf(rb[r].z)) | (((unsigned)f2bf(rb[r].w)) << 16);
            *(uint2*)&Al[0][frag][l][e0] = make_uint2(pa0, pa1);
            *(uint2*)&Bl[0][frag][l][e0] = make_uint2(pb0, pb1);
        }
    }
    __syncthreads();

    for (int s = 0; s < nsteps; ++s) {
        bool more = (s + 1) < nsteps;
        if (more) {
            int k0 = (s + 1) << 5;
#pragma unroll
            for (int r = 0; r < 2; ++r) {
                int row = srow + 32 * r;
                ra[r] = *(const float4*)(A + (bm + row) * K + k0 + 4 * q);
                int n = bn + row;
                rb[r] = (n < N) ? *(const float4*)(W + n * K + k0 + 4 * q)
                                : make_float4(0.f, 0.f, 0.f, 0.f);
            }
        }
        {
            int buf = s & 1;
            short8 af[2], bfr[2];
#pragma unroll
            for (int i = 0; i < 2; ++i) {
                af[i] = *(const short8*)&Al[buf][2 * wr + i][lane][0];
                bfr[i] = *(const short8*)&Bl[buf][2 * wc + i][lane][0];
            }
#pragma unroll
            for (int i = 0; i < 2; ++i)
#pragma unroll
                for (int j = 0; j < 2; ++j)
                    acc[i][j] = __builtin_amdgcn_mfma_f32_16x16x32_bf16(af[i], bfr[j], acc[i][j], 0, 0, 0);
        }
        if (more) {
            int buf = (s + 1) & 1;
#pragma unroll
            for (int r = 0; r < 2; ++r) {
                int row = srow + 32 * r;
                int frag = (row >> 4), l = (row & 15) + 16 * (q >> 1);
                unsigned pa0 = ((unsigned)f2bf(ra[r].x)) | (((unsigned)f2bf(ra[r].y)) << 16);
                unsigned pa1 = ((unsigned)f2bf(ra[r].z)) | (((unsigned)f2bf(ra[r].w)) << 16);
                unsigned pb0 = ((unsigned)f2bf(rb[r].x)) | (((unsigned)f2bf(rb[r].y)) << 16);
                unsigned pb1 = ((unsigned)f2bf(rb[r].z)) | (((unsigned)f2bf(rb[r].w)) << 16);
                *(uint2*)&Al[buf][frag][l][e0] = make_uint2(pa0, pa1);
                *(uint2*)&Bl[buf][frag][l][e0] = make_uint2(pb0, pb1);
            }
        }
        __syncthreads();
    }

#pragma unroll
    for (int j = 0; j < 2; ++j) {
        int col = bn + wc * 32 + j * 16 + (lane & 15);
        if (col >= N) continue;
        float bv = bias ? bias[col] : 0.f;
#pragma unroll
        for (int i = 0; i < 2; ++i) {
            int rbase = bm + wr * 32 + i * 16 + ((lane >> 4) << 2);
#pragma unroll
            for (int r = 0; r < 4; ++r) {
                int row = rbase + r;
                float v = acc[i][j][r] + bv;
                if (res) v += res[row * N + col];
                C[row * N + col] = v;
            }
        }
    }
    (void)M;
}

// ---------------------------------------------------------------------------
// MFMA flash attention: block = 32 queries x 1 head, 4 waves.
// Per 128-key tile each wave owns a 32-key chunk with its own online softmax
// (m,l,O^T partial); flash-combine merge across waves at the end.
// QK^T: S[j][q] = mfma(Kfrag, Qfrag);  C/D: col=lane&15 (=q), row=4g+r (=j).
// P redistributed to B-frag layout in-register (16 shfl + 8 sel per tile).
// PV: O^T[d][q] = mfma(V^Tfrag, Pfrag).
// ---------------------------------------------------------------------------
#define QBLK 32
#define KTJ 128
__global__ __launch_bounds__(256) void mha_mfma(const float* __restrict__ Q,
                                                const float* __restrict__ K,
                                                const float* __restrict__ V,
                                                float* __restrict__ O) {
    __shared__ unsigned short Kl[8][64][8];       // 8 KB: Kl[jt][lane][e] = K[t+jt*16+(lane&15)][8*(lane>>4)+e]
    __shared__ unsigned short Vl[4][2][64][12];   // 12 KB (pad 8->12): Vl[jc][dt][lane][e] = V[t+32jc+8*(lane>>4)+e][dt*16+(lane&15)]
    __shared__ float mred[4][2][16];
    __shared__ float lred[4][2][16];
    __shared__ float Osh[3][2][2][64][4];         // 12 KB
    int h = blockIdx.y;
    int qbase = blockIdx.x * QBLK;
    int tid = threadIdx.x;
    int w = tid >> 6, lane = tid & 63;
    int g = lane >> 4, c = lane & 15;

    // ---- Q fragments (bf16, pre-scaled) ----
    short8 qfrag[2];
#pragma unroll
    for (int qt = 0; qt < 2; ++qt) {
        const float* qp = Q + (qbase + qt * 16 + c) * CDIM + h * HD + g * 8;
        float4 f0 = *(const float4*)qp;
        float4 f1 = *(const float4*)(qp + 4);
        short8 s;
        s[0] = (short)f2bf(f0.x * SCALE_QK); s[1] = (short)f2bf(f0.y * SCALE_QK);
        s[2] = (short)f2bf(f0.z * SCALE_QK); s[3] = (short)f2bf(f0.w * SCALE_QK);
        s[4] = (short)f2bf(f1.x * SCALE_QK); s[5] = (short)f2bf(f1.y * SCALE_QK);
        s[6] = (short)f2bf(f1.z * SCALE_QK); s[7] = (short)f2bf(f1.w * SCALE_QK);
        qfrag[qt] = s;
    }

    float m[2] = { -INFINITY, -INFINITY };
    float l[2] = { 0.f, 0.f };
    f32x4 acc_o[2][2] = {};   // [dt][qt], O^T partial

    // staging index precompute
    int jrow = tid >> 1;              // 0..127 (K staging row)
    int dhalf = (tid & 1) * 16;       // K staging d-half
    int vjq = tid >> 3;               // V staging: j block = 4*vjq
    int vdq = tid & 7;                // V staging: d0 = 4*vdq
    int vjr = 4 * vjq;
    int vd0 = 4 * vdq;
    int vjc = vjr >> 5, vdt = vd0 >> 4, vjg = (vjr & 31) >> 3, ve0 = vjr & 7;

    int src_lo = 16 * ((2 * g) & 3) + c;
    int src_hi = 16 * ((2 * g + 1) & 3) + c;
    bool hisel = (g >= 2);

    for (int t = 0; t < L_SEQ; t += KTJ) {
        // ---- stage K (fragment-order) ----
        {
            int j = t + jrow;
            float4 f0, f1, f2, f3;
            if (j < L_SEQ) {
                const float4* kp = (const float4*)(K + j * CDIM + h * HD + dhalf);
                f0 = kp[0]; f1 = kp[1]; f2 = kp[2]; f3 = kp[3];
            } else {
                f0 = f1 = f2 = f3 = make_float4(0.f, 0.f, 0.f, 0.f);
            }
            int jt = jrow >> 4;
            int laneA = (jrow & 15) + dhalf * 2;   // 16*(dhalf>>3)
            short8 s0, s1;
            s0[0]=f2bf(f0.x); s0[1]=f2bf(f0.y); s0[2]=f2bf(f0.z); s0[3]=f2bf(f0.w);
            s0[4]=f2bf(f1.x); s0[5]=f2bf(f1.y); s0[6]=f2bf(f1.z); s0[7]=f2bf(f1.w);
            s1[0]=f2bf(f2.x); s1[1]=f2bf(f2.y); s1[2]=f2bf(f2.z); s1[3]=f2bf(f2.w);
            s1[4]=f2bf(f3.x); s1[5]=f2bf(f3.y); s1[6]=f2bf(f3.z); s1[7]=f2bf(f3.w);
            *(short8*)&Kl[jt][laneA][0] = s0;
            *(short8*)&Kl[jt][laneA + 16][0] = s1;
        }
        // ---- stage V (transposed fragment-order), 4x4 block per thread ----
        {
            float4 r0, r1, r2, r3;
            int j0 = t + vjr;
            const float* vb = V + h * HD + vd0;
            r0 = (j0 + 0 < L_SEQ) ? *(const float4*)(vb + (j0 + 0) * CDIM) : make_float4(0,0,0,0);
            r1 = (j0 + 1 < L_SEQ) ? *(const float4*)(vb + (j0 + 1) * CDIM) : make_float4(0,0,0,0);
            r2 = (j0 + 2 < L_SEQ) ? *(const float4*)(vb + (j0 + 2) * CDIM) : make_float4(0,0,0,0);
            r3 = (j0 + 3 < L_SEQ) ? *(const float4*)(vb + (j0 + 3) * CDIM) : make_float4(0,0,0,0);
            float col[4][4] = {
                { r0.x, r1.x, r2.x, r3.x },
                { r0.y, r1.y, r2.y, r3.y },
                { r0.z, r1.z, r2.z, r3.z },
                { r0.w, r1.w, r2.w, r3.w } };
#pragma unroll
            for (int dd = 0; dd < 4; ++dd) {
                int laneV = ((vd0 + dd) & 15) + 16 * vjg;
                uint2 pk;
                pk.x = pkbf(col[dd][0], col[dd][1]);
                pk.y = pkbf(col[dd][2], col[dd][3]);
                *(uint2*)&Vl[vjc][vdt][laneV][ve0] = pk;
            }
        }
        __syncthreads();

        bool alive = (t + 32 * w) < L_SEQ;   // chunks are all-or-nothing (1600 % 32 == 0)
        if (alive) {
            // ---- QK^T ----
            short8 kf0 = *(const short8*)&Kl[2 * w][lane][0];
            short8 kf1 = *(const short8*)&Kl[2 * w + 1][lane][0];
            f32x4 zero = { 0.f, 0.f, 0.f, 0.f };
            f32x4 s[2][2];
            s[0][0] = __builtin_amdgcn_mfma_f32_16x16x32_bf16(kf0, qfrag[0], zero, 0, 0, 0);
            s[0][1] = __builtin_amdgcn_mfma_f32_16x16x32_bf16(kf0, qfrag[1], zero, 0, 0, 0);
            s[1][0] = __builtin_amdgcn_mfma_f32_16x16x32_bf16(kf1, qfrag[0], zero, 0, 0, 0);
            s[1][1] = __builtin_amdgcn_mfma_f32_16x16x32_bf16(kf1, qfrag[1], zero, 0, 0, 0);

            // ---- per-qt online softmax + P frag build ----
            short8 pfrag[2];
#pragma unroll
            for (int qt = 0; qt < 2; ++qt) {
                float mx = s[0][qt][0];
                mx = fmaxf(mx, s[0][qt][1]); mx = fmaxf(mx, s[0][qt][2]); mx = fmaxf(mx, s[0][qt][3]);
                mx = fmaxf(mx, s[1][qt][0]); mx = fmaxf(mx, s[1][qt][1]);
                mx = fmaxf(mx, s[1][qt][2]); mx = fmaxf(mx, s[1][qt][3]);
                mx = fmaxf(mx, __shfl_xor(mx, 16, 64));
                mx = fmaxf(mx, __shfl_xor(mx, 32, 64));
                float nm = fmaxf(m[qt], mx);
                float alpha = __expf(m[qt] - nm);
                m[qt] = nm;
                float p00 = __expf(s[0][qt][0] - nm), p01 = __expf(s[0][qt][1] - nm);
                float p02 = __expf(s[0][qt][2] - nm), p03 = __expf(s[0][qt][3] - nm);
                float p10 = __expf(s[1][qt][0] - nm), p11 = __expf(s[1][qt][1] - nm);
                float p12 = __expf(s[1][qt][2] - nm), p13 = __expf(s[1][qt][3] - nm);
                float ts = ((p00 + p01) + (p02 + p03)) + ((p10 + p11) + (p12 + p13));
                ts += __shfl_xor(ts, 16, 64);
                ts += __shfl_xor(ts, 32, 64);
                l[qt] = l[qt] * alpha + ts;
#pragma unroll
                for (int dt = 0; dt < 2; ++dt) {
                    acc_o[dt][qt][0] *= alpha; acc_o[dt][qt][1] *= alpha;
                    acc_o[dt][qt][2] *= alpha; acc_o[dt][qt][3] *= alpha;
                }
                // pack: W[jt][word]  word0=(r0,r1) word1=(r2,r3)
                unsigned w00 = pkbf(p00, p01), w01 = pkbf(p02, p03);
                unsigned w10 = pkbf(p10, p11), w11 = pkbf(p12, p13);
                // redistribute to B-frag: lane needs P[j=8g+e][q], e=0..7
                unsigned a0 = __shfl(w00, src_lo, 64);
                unsigned a1 = __shfl(w10, src_lo, 64);
                unsigned b0 = __shfl(w01, src_lo, 64);
                unsigned b1 = __shfl(w11, src_lo, 64);
                unsigned c0 = __shfl(w00, src_hi, 64);
                unsigned c1 = __shfl(w10, src_hi, 64);
                unsigned d0 = __shfl(w01, src_hi, 64);
                unsigned d1 = __shfl(w11, src_hi, 64);
                union { short8 s8; unsigned u[4]; } P;
                P.u[0] = hisel ? a1 : a0;
                P.u[1] = hisel ? b1 : b0;
                P.u[2] = hisel ? c1 : c0;
                P.u[3] = hisel ? d1 : d0;
                pfrag[qt] = P.s8;
            }

            // ---- PV ----
            union { short8 s8; uint2 v[2]; } vf0u, vf1u;
            vf0u.v[0] = *(const uint2*)&Vl[w][0][lane][0];
            vf0u.v[1] = *(const uint2*)&Vl[w][0][lane][4];
            vf1u.v[0] = *(const uint2*)&Vl[w][1][lane][0];
            vf1u.v[1] = *(const uint2*)&Vl[w][1][lane][4];
            acc_o[0][0] = __builtin_amdgcn_mfma_f32_16x16x32_bf16(vf0u.s8, pfrag[0], acc_o[0][0], 0, 0, 0);
            acc_o[0][1] = __builtin_amdgcn_mfma_f32_16x16x32_bf16(vf0u.s8, pfrag[1], acc_o[0][1], 0, 0, 0);
            acc_o[1][0] = __builtin_amdgcn_mfma_f32_16x16x32_bf16(vf1u.s8, pfrag[0], acc_o[1][0], 0, 0, 0);
            acc_o[1][1] = __builtin_amdgcn_mfma_f32_16x16x32_bf16(vf1u.s8, pfrag[1], acc_o[1][1], 0, 0, 0);
        }
        __syncthreads();
    }

    // ---- merge across waves (flash combine) ----
    if (g == 0) {
#pragma unroll
        for (int qt = 0; qt < 2; ++qt) { mred[w][qt][c] = m[qt]; lred[w][qt][c] = l[qt]; }
    }
    if (w > 0) {
#pragma unroll
        for (int dt = 0; dt < 2; ++dt)
#pragma unroll
            for (int qt = 0; qt < 2; ++qt)
                *(f32x4*)&Osh[w - 1][dt][qt][lane][0] = acc_o[dt][qt];
    }
    __syncthreads();
    if (w == 0) {
#pragma unroll
        for (int qt = 0; qt < 2; ++qt) {
            float m0_ = mred[0][qt][c], m1_ = mred[1][qt][c];
            float m2_ = mred[2][qt][c], m3_ = mred[3][qt][c];
            float M = fmaxf(fmaxf(m0_, m1_), fmaxf(m2_, m3_));
            float a0 = __expf(m0_ - M), a1 = __expf(m1_ - M);
            float a2 = __expf(m2_ - M), a3 = __expf(m3_ - M);
            float L = a0 * lred[0][qt][c] + a1 * lred[1][qt][c]
                    + a2 * lred[2][qt][c] + a3 * lred[3][qt][c];
            float inv = 1.f / L;
#pragma unroll
            for (int dt = 0; dt < 2; ++dt) {
                f32x4 o1 = *(const f32x4*)&Osh[0][dt][qt][lane][0];
                f32x4 o2 = *(const f32x4*)&Osh[1][dt][qt][lane][0];
                f32x4 o3 = *(const f32x4*)&Osh[2][dt][qt][lane][0];
                float4 r;
                r.x = (acc_o[dt][qt][0] * a0 + o1[0] * a1 + o2[0] * a2 + o3[0] * a3) * inv;
                r.y = (acc_o[dt][qt][1] * a0 + o1[1] * a1 + o2[1] * a2 + o3[1] * a3) * inv;
                r.z = (acc_o[dt][qt][2] * a0 + o1[2] * a1 + o2[2] * a2 + o3[2] * a3) * inv;
                r.w = (acc_o[dt][qt][3] * a0 + o1[3] * a1 + o2[3] * a2 + o3[3] * a3) * inv;
                *(float4*)(O + (qbase + qt * 16 + c) * CDIM + h * HD + dt * 16 + 4 * g) = r;
            }
        }
    }
}

// Local windowed attention: one block per (position, head)
__global__ __launch_bounds__(256) void local_attn_kernel(const float* __restrict__ Q,
                                                         const float* __restrict__ K,
                                                         const float* __restrict__ V,
                                                         float* __restrict__ O) {
    __shared__ float qsh[HD];
    __shared__ float p[WIN];
    __shared__ float sh4[4];
    __shared__ float oacc[8][HD];
    int n = blockIdx.x, h = blockIdx.y, tid = threadIdx.x;
    int y = n / GRID_W, x = n % GRID_W;
    if (tid < HD) qsh[tid] = Q[n * CDIM + h * HD + tid] * SCALE_QK;
    __syncthreads();
    float lg = -INFINITY;
    if (tid < WIN) {
        int dy = tid / WS_ - MAXD, dx = tid % WS_ - MAXD;
        int yy = y + dy, xx = x + dx;
        if (yy >= 0 && yy < GRID_H && xx >= 0 && xx < GRID_W) {
            const float* kr = K + (yy * GRID_W + xx) * CDIM + h * HD;
            float s = 0.f;
#pragma unroll
            for (int d2 = 0; d2 < HD; ++d2) s += qsh[d2] * kr[d2];
            lg = s;
        } else {
            lg = -1.0e9f;
        }
    }
    float smax = blockReduceMax(lg, sh4);
    float e = 0.f;
    if (tid < WIN) {
        e = expf(lg - smax);
        p[tid] = e;
    }
    float inv = 1.0f / blockReduceSum(e, sh4);
    int d2 = tid & 31, ch = tid >> 5;
    float acc = 0.f;
    for (int w = ch; w < WIN; w += 8) {
        int dy = w / WS_ - MAXD, dx = w % WS_ - MAXD;
        int yy = y + dy, xx = x + dx;
        if (yy >= 0 && yy < GRID_H && xx >= 0 && xx < GRID_W)
            acc += p[w] * V[(yy * GRID_W + xx) * CDIM + h * HD + d2];
    }
    oacc[ch][d2] = acc;
    __syncthreads();
    if (tid < HD) {
        float s = 0.f;
#pragma unroll
        for (int i = 0; i < 8; ++i) s += oacc[i][tid];
        O[n * CDIM + h * HD + tid] = s * inv;
    }
}

// build curr_Q (contiguous), global_K, global_V from qv (1600x512) and idkv (1600x264)
__global__ __launch_bounds__(256) void make_qkv_kernel(const float* __restrict__ qv,
                                                       const float* __restrict__ idkv,
                                                       float* __restrict__ Qc,
                                                       float* __restrict__ gK,
                                                       float* __restrict__ gV) {
    int idx = blockIdx.x * 256 + threadIdx.x;
    if (idx >= L_SEQ * CDIM) return;
    int l = idx >> 8, c = idx & 255;
    int h = c >> 5;
    float q = qv[l * 512 + c];
    Qc[idx] = q;
    gK[idx] = q * (1.f + tanhf(idkv[l * 264 + h]));
    gV[idx] = qv[l * 512 + 256 + c] + idkv[l * 264 + 8 + c];
}

// GroupNorm partials: grid (32 groups, 8 chunks); deterministic partial sums.
__global__ __launch_bounds__(256) void gn_partial(const float* __restrict__ X,
                                                  float* __restrict__ gstat) {
    __shared__ float sh4[4];
    int g = blockIdx.x, chunk = blockIdx.y;
    int base = g * 32;
    float s = 0.f, s2 = 0.f;
    for (int i = threadIdx.x; i < 200 * 32; i += 256) {
        int l = chunk * 200 + (i >> 5), c = i & 31;
        float v = X[l * DFF_ + base + c];
        s += v;
        s2 += v * v;
    }
    s = blockReduceSum(s, sh4);
    s2 = blockReduceSum(s2, sh4);
    if (threadIdx.x == 0) {
        gstat[g * 8 + chunk] = s;
        gstat[256 + g * 8 + chunk] = s2;
    }
}

// GroupNorm apply + exact GELU, float4-vectorized. 1600 blocks x 256 thr.
__global__ __launch_bounds__(256) void gn_apply(const float* __restrict__ X,
                                                const float* __restrict__ gstat,
                                                const float* __restrict__ g,
                                                const float* __restrict__ b,
                                                float* __restrict__ Y) {
    int idx = blockIdx.x * 256 + threadIdx.x;
    int e4 = idx * 4;
    int c = e4 & 1023;
    int grp = c >> 5;
    float s = 0.f, s2 = 0.f;
#pragma unroll
    for (int i = 0; i < 8; ++i) {
        s += gstat[grp * 8 + i];
        s2 += gstat[256 + grp * 8 + i];
    }
    const float invn = 1.0f / 51200.f;
    float mean = s * invn;
    float rs = rsqrtf(s2 * invn - mean * mean + 1e-5f);
    float4 v = *(const float4*)(X + e4);
    float4 gg = *(const float4*)(g + c);
    float4 bb = *(const float4*)(b + c);
    float4 r;
    float y0 = (v.x - mean) * rs * gg.x + bb.x;
    float y1 = (v.y - mean) * rs * gg.y + bb.y;
    float y2 = (v.z - mean) * rs * gg.z + bb.z;
    float y3 = (v.w - mean) * rs * gg.w + bb.w;
    r.x = 0.5f * y0 * (1.0f + erff(y0 * 0.70710678118654752f));
    r.y = 0.5f * y1 * (1.0f + erff(y1 * 0.70710678118654752f));
    r.z = 0.5f * y2 * (1.0f + erff(y2 * 0.70710678118654752f));
    r.w = 0.5f * y3 * (1.0f + erff(y3 * 0.70710678118654752f));
    *(float4*)(Y + e4) = r;
}

// depthwise 5x5 conv, pad 2 (cross-correlation). X,Y (1600,1024) l-major; Kw (1024,25)
__global__ __launch_bounds__(256) void dwconv_kernel(const float* __restrict__ X,
                                                     const float* __restrict__ Kw,
                                                     float* __restrict__ Y) {
    int idx = blockIdx.x * 256 + threadIdx.x;
    if (idx >= L_SEQ * DFF_) return;
    int c = idx & 1023, l = idx >> 10;
    int y = l / GRID_W, x = l % GRID_W;
    float acc = 0.f;
#pragma unroll
    for (int ky = 0; ky < 5; ++ky) {
        int yy = y + ky - 2;
        if (yy < 0 || yy >= GRID_H) continue;
#pragma unroll
        for (int kx = 0; kx < 5; ++kx) {
            int xx = x + kx - 2;
            if (xx < 0 || xx >= GRID_W) continue;
            acc += X[(yy * GRID_W + xx) * DFF_ + c] * Kw[c * 25 + ky * 5 + kx];
        }
    }
    Y[idx] = acc;
}

extern "C" void kernel_launch(void* const* d_in, const int* in_sizes, int n_in,
                              void* d_out, int out_size, void* d_ws, size_t ws_size,
                              hipStream_t stream) {
    (void)in_sizes; (void)n_in; (void)out_size; (void)ws_size;
    const float* tgt = (const float*)d_in[0];
    const float* curr_id_emb = (const float*)d_in[1];
    const float* self_pos = (const float*)d_in[2];
    const float* ln1_g = (const float*)d_in[3];
    const float* ln1_b = (const float*)d_in[4];
    const float* sa_wq = (const float*)d_in[5];
    const float* sa_bq = (const float*)d_in[6];
    const float* sa_wk = (const float*)d_in[7];
    const float* sa_bk = (const float*)d_in[8];
    const float* sa_wv = (const float*)d_in[9];
    const float* sa_bv = (const float*)d_in[10];
    const float* sa_wo = (const float*)d_in[11];
    const float* sa_bo = (const float*)d_in[12];
    const float* ln2_g = (const float*)d_in[13];
    const float* ln2_b = (const float*)d_in[14];
    const float* w_qv = (const float*)d_in[15];
    const float* b_qv = (const float*)d_in[16];
    const float* w_id = (const float*)d_in[17];
    const float* b_id = (const float*)d_in[18];
    const float* lt_wo = (const float*)d_in[19];
    const float* lt_bo = (const float*)d_in[20];
    const float* st_wo = (const float*)d_in[21];
    const float* st_bo = (const float*)d_in[22];
    const float* ln3_g = (const float*)d_in[23];
    const float* ln3_b = (const float*)d_in[24];
    const float* w1 = (const float*)d_in[25];
    const float* b1 = (const float*)d_in[26];
    const float* gn_g = (const float*)d_in[27];
    const float* gn_b = (const float*)d_in[28];
    const float* dw_k = (const float*)d_in[29];
    const float* w2 = (const float*)d_in[30];
    const float* b2 = (const float*)d_in[31];
    float* out = (float*)d_out;

    float* ws = (float*)d_ws;
    const int LC = L_SEQ * CDIM;           // 409600
    float* bufA = ws;                      // _t
    float* bufB = bufA + LC;               // qk_in / tgt1+tgt2
    float* bufC = bufB + LC;               // q_ / curr_Q
    float* bufD = bufC + LC;               // k_ / global_K
    float* bufE = bufD + LC;               // v_ / global_V
    float* bufF = bufE + LC;               // attn outs
    float* bufG = bufF + LC;               // tgt1 / tgt_b
    float* bufH = bufG + LC;               // qv (1600x512); later: gstat
    float* bufI = bufH + L_SEQ * 512;      // idkv (1600x264)
    float* bufX = bufI + L_SEQ * 264;      // w1 out (1600x1024)
    float* bufY = bufX + L_SEQ * DFF_;     // gn+gelu out
    float* bufZ = bufY + L_SEQ * DFF_;     // conv out

    dim3 blk(256);
    dim3 g256(4, 25), g264(5, 25), g512(8, 25), g1024(16, 25);
    dim3 mhaGrid(L_SEQ / QBLK, NH);

    // 1. LN1: bufA = ln(tgt), bufB = bufA + self_pos
    ln_kernel<<<L_SEQ, blk, 0, stream>>>(tgt, ln1_g, ln1_b, self_pos, bufA, bufB);
    // 2-4. q,k,v projections
    gemm_mfma<<<g256, blk, 0, stream>>>(bufB, sa_wq, sa_bq, nullptr, bufC, L_SEQ, CDIM, CDIM);
    gemm_mfma<<<g256, blk, 0, stream>>>(bufB, sa_wk, sa_bk, nullptr, bufD, L_SEQ, CDIM, CDIM);
    gemm_mfma<<<g256, blk, 0, stream>>>(bufA, sa_wv, sa_bv, nullptr, bufE, L_SEQ, CDIM, CDIM);
    // 5. self attention
    mha_mfma<<<mhaGrid, blk, 0, stream>>>(bufC, bufD, bufE, bufF);
    // 6. out proj + residual -> tgt1 (bufG)
    gemm_mfma<<<g256, blk, 0, stream>>>(bufF, sa_wo, sa_bo, tgt, bufG, L_SEQ, CDIM, CDIM);
    // 7. LN2 -> bufA
    ln_kernel<<<L_SEQ, blk, 0, stream>>>(bufG, ln2_g, ln2_b, nullptr, bufA, nullptr);
    // 8. qv = bufA @ w_qv^T -> bufH (1600x512)
    gemm_mfma<<<g512, blk, 0, stream>>>(bufA, w_qv, b_qv, nullptr, bufH, L_SEQ, 512, CDIM);
    // 9. idkv = curr_id_emb @ w_id^T -> bufI (1600x264)
    gemm_mfma<<<g264, blk, 0, stream>>>(curr_id_emb, w_id, b_id, nullptr, bufI, L_SEQ, 264, CDIM);
    // 10. curr_Q (bufC), global_K (bufD), global_V (bufE)
    make_qkv_kernel<<<L_SEQ, blk, 0, stream>>>(bufH, bufI, bufC, bufD, bufE);
    // 11. long-term attention
    mha_mfma<<<mhaGrid, blk, 0, stream>>>(bufC, bufD, bufE, bufF);
    // 12. lt out proj + residual(tgt1) -> bufB
    gemm_mfma<<<g256, blk, 0, stream>>>(bufF, lt_wo, lt_bo, bufG, bufB, L_SEQ, CDIM, CDIM);
    // 13. local attention -> bufF
    local_attn_kernel<<<dim3(L_SEQ, NH), blk, 0, stream>>>(bufC, bufD, bufE, bufF);
    // 14. st out proj + residual(bufB) -> tgt_b (bufG)
    gemm_mfma<<<g256, blk, 0, stream>>>(bufF, st_wo, st_bo, bufB, bufG, L_SEQ, CDIM, CDIM);
    // 15. LN3 -> bufA
    ln_kernel<<<L_SEQ, blk, 0, stream>>>(bufG, ln3_g, ln3_b, nullptr, bufA, nullptr);
    // 16. x = bufA @ w1^T -> bufX (1600x1024)
    gemm_mfma<<<g1024, blk, 0, stream>>>(bufA, w1, b1, nullptr, bufX, L_SEQ, DFF_, CDIM);
    // 17. GroupNorm + GELU -> bufY  (bufH is dead; reuse as gstat)
    gn_partial<<<dim3(32, 8), blk, 0, stream>>>(bufX, bufH);
    gn_apply<<<L_SEQ, blk, 0, stream>>>(bufX, bufH, gn_g, gn_b, bufY);
    // 18. depthwise conv -> bufZ
    dwconv_kernel<<<(L_SEQ * DFF_ + 255) / 256, blk, 0, stream>>>(bufY, dw_k, bufZ);
    // 19. final proj + residual(tgt_b) -> out
    gemm_mfma<<<g256, blk, 0, stream>>>(bufZ, w2, b2, bufG, out, L_SEQ, CDIM, DFF_);
}

// Round 7
// 417.432 us; speedup vs baseline: 4.5604x; 1.1133x over previous
//
#include <hip/hip_runtime.h>
#include <math.h>

#define L_SEQ 1600
#define CDIM 256
#define NH 8
#define HD 32
#define GRID_H 40
#define GRID_W 40
#define DFF_ 1024
#define WS_ 15
#define WIN 225
#define MAXD 7
#define SCALE_QK 0.17677669529663687f

typedef __attribute__((ext_vector_type(8))) short short8;
typedef __attribute__((ext_vector_type(4))) float f32x4;

__device__ __forceinline__ float waveReduceSum(float v) {
#pragma unroll
    for (int off = 32; off > 0; off >>= 1) v += __shfl_down(v, off, 64);
    return v;
}
__device__ __forceinline__ float waveReduceMax(float v) {
#pragma unroll
    for (int off = 32; off > 0; off >>= 1) v = fmaxf(v, __shfl_down(v, off, 64));
    return v;
}
// block of exactly 256 threads (4 waves)
__device__ __forceinline__ float blockReduceSum(float v, float* sh4) {
    v = waveReduceSum(v);
    int lane = threadIdx.x & 63, wid = threadIdx.x >> 6;
    __syncthreads();
    if (lane == 0) sh4[wid] = v;
    __syncthreads();
    return sh4[0] + sh4[1] + sh4[2] + sh4[3];
}

__device__ __forceinline__ unsigned short f2bf(float x) {
    union { float f; unsigned u; } v; v.f = x;
    unsigned r = (v.u + 0x7FFFu + ((v.u >> 16) & 1u)) >> 16;
    return (unsigned short)r;
}
__device__ __forceinline__ unsigned pkbf(float lo, float hi) {
    return (unsigned)f2bf(lo) | ((unsigned)f2bf(hi) << 16);
}

// LayerNorm over C=256; one block (256 thr) per row. out2 = out + addin (optional)
__global__ __launch_bounds__(256) void ln_kernel(const float* __restrict__ x,
                                                 const float* __restrict__ g,
                                                 const float* __restrict__ b,
                                                 const float* __restrict__ addin,
                                                 float* __restrict__ out,
                                                 float* __restrict__ out2) {
    __shared__ float sh4[4];
    int row = blockIdx.x;
    int c = threadIdx.x;
    float v = x[row * CDIM + c];
    float mean = blockReduceSum(v, sh4) * (1.0f / CDIM);
    float d = v - mean;
    float var = blockReduceSum(d * d, sh4) * (1.0f / CDIM);
    float y = d * rsqrtf(var + 1e-5f) * g[c] + b[c];
    out[row * CDIM + c] = y;
    if (out2) out2[row * CDIM + c] = y + addin[row * CDIM + c];
}

// ---------------------------------------------------------------------------
// bf16 MFMA GEMM (unchanged, verified)
// ---------------------------------------------------------------------------
__global__ __launch_bounds__(256) void gemm_mfma(const float* __restrict__ A,
                                                 const float* __restrict__ W,
                                                 const float* __restrict__ bias,
                                                 const float* __restrict__ res,
                                                 float* __restrict__ C,
                                                 int M, int N, int K) {
    __shared__ unsigned short Al[2][4][64][8];   // 8KB
    __shared__ unsigned short Bl[2][4][64][8];   // 8KB
    int tid = threadIdx.x;
    int bm = blockIdx.y * 64, bn = blockIdx.x * 64;
    int lane = tid & 63, wave = tid >> 6;
    int wr = wave >> 1, wc = wave & 1;

    int srow = tid >> 3;
    int q = tid & 7;
    int e0 = (q & 1) * 4;

    f32x4 acc[2][2] = {};
    int nsteps = K >> 5;

    float4 ra[2], rb[2];
    {
        int k0 = 0;
#pragma unroll
        for (int r = 0; r < 2; ++r) {
            int row = srow + 32 * r;
            ra[r] = *(const float4*)(A + (bm + row) * K + k0 + 4 * q);
            int n = bn + row;
            rb[r] = (n < N) ? *(const float4*)(W + n * K + k0 + 4 * q)
                            : make_float4(0.f, 0.f, 0.f, 0.f);
        }
#pragma unroll
        for (int r = 0; r < 2; ++r) {
            int row = srow + 32 * r;
            int frag = (row >> 4), l = (row & 15) + 16 * (q >> 1);
            unsigned pa0 = ((unsigned)f2bf(ra[r].x)) | (((unsigned)f2bf(ra[r].y)) << 16);
            unsigned pa1 = ((unsigned)f2bf(ra[r].z)) | (((unsigned)f2bf(ra[r].w)) << 16);
            unsigned pb0 = ((unsigned)f2bf(rb[r].x)) | (((unsigned)f2bf(rb[r].y)) << 16);
            unsigned pb1 = ((unsigned)f2bf(rb[r].z)) | (((unsigned)f2bf(rb[r].w)) << 16);
            *(uint2*)&Al[0][frag][l][e0] = make_uint2(pa0, pa1);
            *(uint2*)&Bl[0][frag][l][e0] = make_uint2(pb0, pb1);
        }
    }
    __syncthreads();

    for (int s = 0; s < nsteps; ++s) {
        bool more = (s + 1) < nsteps;
        if (more) {
            int k0 = (s + 1) << 5;
#pragma unroll
            for (int r = 0; r < 2; ++r) {
                int row = srow + 32 * r;
                ra[r] = *(const float4*)(A + (bm + row) * K + k0 + 4 * q);
                int n = bn + row;
                rb[r] = (n < N) ? *(const float4*)(W + n * K + k0 + 4 * q)
                                : make_float4(0.f, 0.f, 0.f, 0.f);
            }
        }
        {
            int buf = s & 1;
            short8 af[2], bfr[2];
#pragma unroll
            for (int i = 0; i < 2; ++i) {
                af[i] = *(const short8*)&Al[buf][2 * wr + i][lane][0];
                bfr[i] = *(const short8*)&Bl[buf][2 * wc + i][lane][0];
            }
#pragma unroll
            for (int i = 0; i < 2; ++i)
#pragma unroll
                for (int j = 0; j < 2; ++j)
                    acc[i][j] = __builtin_amdgcn_mfma_f32_16x16x32_bf16(af[i], bfr[j], acc[i][j], 0, 0, 0);
        }
        if (more) {
            int buf = (s + 1) & 1;
#pragma unroll
            for (int r = 0; r < 2; ++r) {
                int row = srow + 32 * r;
                int frag = (row >> 4), l = (row & 15) + 16 * (q >> 1);
                unsigned pa0 = ((unsigned)f2bf(ra[r].x)) | (((unsigned)f2bf(ra[r].y)) << 16);
                unsigned pa1 = ((unsigned)f2bf(ra[r].z)) | (((unsigned)f2bf(ra[r].w)) << 16);
                unsigned pb0 = ((unsigned)f2bf(rb[r].x)) | (((unsigned)f2bf(rb[r].y)) << 16);
                unsigned pb1 = ((unsigned)f2bf(rb[r].z)) | (((unsigned)f2bf(rb[r].w)) << 16);
                *(uint2*)&Al[buf][frag][l][e0] = make_uint2(pa0, pa1);
                *(uint2*)&Bl[buf][frag][l][e0] = make_uint2(pb0, pb1);
            }
        }
        __syncthreads();
    }

#pragma unroll
    for (int j = 0; j < 2; ++j) {
        int col = bn + wc * 32 + j * 16 + (lane & 15);
        if (col >= N) continue;
        float bv = bias ? bias[col] : 0.f;
#pragma unroll
        for (int i = 0; i < 2; ++i) {
            int rbase = bm + wr * 32 + i * 16 + ((lane >> 4) << 2);
#pragma unroll
            for (int r = 0; r < 4; ++r) {
                int row = rbase + r;
                float v = acc[i][j][r] + bv;
                if (res) v += res[row * N + col];
                C[row * N + col] = v;
            }
        }
    }
    (void)M;
}

// ---------------------------------------------------------------------------
// MFMA flash attention (unchanged, verified)
// ---------------------------------------------------------------------------
#define QBLK 32
#define KTJ 128
__global__ __launch_bounds__(256) void mha_mfma(const float* __restrict__ Q,
                                                const float* __restrict__ K,
                                                const float* __restrict__ V,
                                                float* __restrict__ O) {
    __shared__ unsigned short Kl[8][64][8];
    __shared__ unsigned short Vl[4][2][64][12];
    __shared__ float mred[4][2][16];
    __shared__ float lred[4][2][16];
    __shared__ float Osh[3][2][2][64][4];
    int h = blockIdx.y;
    int qbase = blockIdx.x * QBLK;
    int tid = threadIdx.x;
    int w = tid >> 6, lane = tid & 63;
    int g = lane >> 4, c = lane & 15;

    short8 qfrag[2];
#pragma unroll
    for (int qt = 0; qt < 2; ++qt) {
        const float* qp = Q + (qbase + qt * 16 + c) * CDIM + h * HD + g * 8;
        float4 f0 = *(const float4*)qp;
        float4 f1 = *(const float4*)(qp + 4);
        short8 s;
        s[0] = (short)f2bf(f0.x * SCALE_QK); s[1] = (short)f2bf(f0.y * SCALE_QK);
        s[2] = (short)f2bf(f0.z * SCALE_QK); s[3] = (short)f2bf(f0.w * SCALE_QK);
        s[4] = (short)f2bf(f1.x * SCALE_QK); s[5] = (short)f2bf(f1.y * SCALE_QK);
        s[6] = (short)f2bf(f1.z * SCALE_QK); s[7] = (short)f2bf(f1.w * SCALE_QK);
        qfrag[qt] = s;
    }

    float m[2] = { -INFINITY, -INFINITY };
    float l[2] = { 0.f, 0.f };
    f32x4 acc_o[2][2] = {};

    int jrow = tid >> 1;
    int dhalf = (tid & 1) * 16;
    int vjq = tid >> 3;
    int vdq = tid & 7;
    int vjr = 4 * vjq;
    int vd0 = 4 * vdq;
    int vjc = vjr >> 5, vdt = vd0 >> 4, vjg = (vjr & 31) >> 3, ve0 = vjr & 7;

    int src_lo = 16 * ((2 * g) & 3) + c;
    int src_hi = 16 * ((2 * g + 1) & 3) + c;
    bool hisel = (g >= 2);

    for (int t = 0; t < L_SEQ; t += KTJ) {
        {
            int j = t + jrow;
            float4 f0, f1, f2, f3;
            if (j < L_SEQ) {
                const float4* kp = (const float4*)(K + j * CDIM + h * HD + dhalf);
                f0 = kp[0]; f1 = kp[1]; f2 = kp[2]; f3 = kp[3];
            } else {
                f0 = f1 = f2 = f3 = make_float4(0.f, 0.f, 0.f, 0.f);
            }
            int jt = jrow >> 4;
            int laneA = (jrow & 15) + dhalf * 2;
            short8 s0, s1;
            s0[0]=f2bf(f0.x); s0[1]=f2bf(f0.y); s0[2]=f2bf(f0.z); s0[3]=f2bf(f0.w);
            s0[4]=f2bf(f1.x); s0[5]=f2bf(f1.y); s0[6]=f2bf(f1.z); s0[7]=f2bf(f1.w);
            s1[0]=f2bf(f2.x); s1[1]=f2bf(f2.y); s1[2]=f2bf(f2.z); s1[3]=f2bf(f2.w);
            s1[4]=f2bf(f3.x); s1[5]=f2bf(f3.y); s1[6]=f2bf(f3.z); s1[7]=f2bf(f3.w);
            *(short8*)&Kl[jt][laneA][0] = s0;
            *(short8*)&Kl[jt][laneA + 16][0] = s1;
        }
        {
            float4 r0, r1, r2, r3;
            int j0 = t + vjr;
            const float* vb = V + h * HD + vd0;
            r0 = (j0 + 0 < L_SEQ) ? *(const float4*)(vb + (j0 + 0) * CDIM) : make_float4(0,0,0,0);
            r1 = (j0 + 1 < L_SEQ) ? *(const float4*)(vb + (j0 + 1) * CDIM) : make_float4(0,0,0,0);
            r2 = (j0 + 2 < L_SEQ) ? *(const float4*)(vb + (j0 + 2) * CDIM) : make_float4(0,0,0,0);
            r3 = (j0 + 3 < L_SEQ) ? *(const float4*)(vb + (j0 + 3) * CDIM) : make_float4(0,0,0,0);
            float col[4][4] = {
                { r0.x, r1.x, r2.x, r3.x },
                { r0.y, r1.y, r2.y, r3.y },
                { r0.z, r1.z, r2.z, r3.z },
                { r0.w, r1.w, r2.w, r3.w } };
#pragma unroll
            for (int dd = 0; dd < 4; ++dd) {
                int laneV = ((vd0 + dd) & 15) + 16 * vjg;
                uint2 pk;
                pk.x = pkbf(col[dd][0], col[dd][1]);
                pk.y = pkbf(col[dd][2], col[dd][3]);
                *(uint2*)&Vl[vjc][vdt][laneV][ve0] = pk;
            }
        }
        __syncthreads();

        bool alive = (t + 32 * w) < L_SEQ;
        if (alive) {
            short8 kf0 = *(const short8*)&Kl[2 * w][lane][0];
            short8 kf1 = *(const short8*)&Kl[2 * w + 1][lane][0];
            f32x4 zero = { 0.f, 0.f, 0.f, 0.f };
            f32x4 s[2][2];
            s[0][0] = __builtin_amdgcn_mfma_f32_16x16x32_bf16(kf0, qfrag[0], zero, 0, 0, 0);
            s[0][1] = __builtin_amdgcn_mfma_f32_16x16x32_bf16(kf0, qfrag[1], zero, 0, 0, 0);
            s[1][0] = __builtin_amdgcn_mfma_f32_16x16x32_bf16(kf1, qfrag[0], zero, 0, 0, 0);
            s[1][1] = __builtin_amdgcn_mfma_f32_16x16x32_bf16(kf1, qfrag[1], zero, 0, 0, 0);

            short8 pfrag[2];
#pragma unroll
            for (int qt = 0; qt < 2; ++qt) {
                float mx = s[0][qt][0];
                mx = fmaxf(mx, s[0][qt][1]); mx = fmaxf(mx, s[0][qt][2]); mx = fmaxf(mx, s[0][qt][3]);
                mx = fmaxf(mx, s[1][qt][0]); mx = fmaxf(mx, s[1][qt][1]);
                mx = fmaxf(mx, s[1][qt][2]); mx = fmaxf(mx, s[1][qt][3]);
                mx = fmaxf(mx, __shfl_xor(mx, 16, 64));
                mx = fmaxf(mx, __shfl_xor(mx, 32, 64));
                float nm = fmaxf(m[qt], mx);
                float alpha = __expf(m[qt] - nm);
                m[qt] = nm;
                float p00 = __expf(s[0][qt][0] - nm), p01 = __expf(s[0][qt][1] - nm);
                float p02 = __expf(s[0][qt][2] - nm), p03 = __expf(s[0][qt][3] - nm);
                float p10 = __expf(s[1][qt][0] - nm), p11 = __expf(s[1][qt][1] - nm);
                float p12 = __expf(s[1][qt][2] - nm), p13 = __expf(s[1][qt][3] - nm);
                float ts = ((p00 + p01) + (p02 + p03)) + ((p10 + p11) + (p12 + p13));
                ts += __shfl_xor(ts, 16, 64);
                ts += __shfl_xor(ts, 32, 64);
                l[qt] = l[qt] * alpha + ts;
#pragma unroll
                for (int dt = 0; dt < 2; ++dt) {
                    acc_o[dt][qt][0] *= alpha; acc_o[dt][qt][1] *= alpha;
                    acc_o[dt][qt][2] *= alpha; acc_o[dt][qt][3] *= alpha;
                }
                unsigned w00 = pkbf(p00, p01), w01 = pkbf(p02, p03);
                unsigned w10 = pkbf(p10, p11), w11 = pkbf(p12, p13);
                unsigned a0 = __shfl(w00, src_lo, 64);
                unsigned a1 = __shfl(w10, src_lo, 64);
                unsigned b0 = __shfl(w01, src_lo, 64);
                unsigned b1 = __shfl(w11, src_lo, 64);
                unsigned c0 = __shfl(w00, src_hi, 64);
                unsigned c1 = __shfl(w10, src_hi, 64);
                unsigned d0 = __shfl(w01, src_hi, 64);
                unsigned d1 = __shfl(w11, src_hi, 64);
                union { short8 s8; unsigned u[4]; } P;
                P.u[0] = hisel ? a1 : a0;
                P.u[1] = hisel ? b1 : b0;
                P.u[2] = hisel ? c1 : c0;
                P.u[3] = hisel ? d1 : d0;
                pfrag[qt] = P.s8;
            }

            union { short8 s8; uint2 v[2]; } vf0u, vf1u;
            vf0u.v[0] = *(const uint2*)&Vl[w][0][lane][0];
            vf0u.v[1] = *(const uint2*)&Vl[w][0][lane][4];
            vf1u.v[0] = *(const uint2*)&Vl[w][1][lane][0];
            vf1u.v[1] = *(const uint2*)&Vl[w][1][lane][4];
            acc_o[0][0] = __builtin_amdgcn_mfma_f32_16x16x32_bf16(vf0u.s8, pfrag[0], acc_o[0][0], 0, 0, 0);
            acc_o[0][1] = __builtin_amdgcn_mfma_f32_16x16x32_bf16(vf0u.s8, pfrag[1], acc_o[0][1], 0, 0, 0);
            acc_o[1][0] = __builtin_amdgcn_mfma_f32_16x16x32_bf16(vf1u.s8, pfrag[0], acc_o[1][0], 0, 0, 0);
            acc_o[1][1] = __builtin_amdgcn_mfma_f32_16x16x32_bf16(vf1u.s8, pfrag[1], acc_o[1][1], 0, 0, 0);
        }
        __syncthreads();
    }

    if (g == 0) {
#pragma unroll
        for (int qt = 0; qt < 2; ++qt) { mred[w][qt][c] = m[qt]; lred[w][qt][c] = l[qt]; }
    }
    if (w > 0) {
#pragma unroll
        for (int dt = 0; dt < 2; ++dt)
#pragma unroll
            for (int qt = 0; qt < 2; ++qt)
                *(f32x4*)&Osh[w - 1][dt][qt][lane][0] = acc_o[dt][qt];
    }
    __syncthreads();
    if (w == 0) {
#pragma unroll
        for (int qt = 0; qt < 2; ++qt) {
            float m0_ = mred[0][qt][c], m1_ = mred[1][qt][c];
            float m2_ = mred[2][qt][c], m3_ = mred[3][qt][c];
            float M = fmaxf(fmaxf(m0_, m1_), fmaxf(m2_, m3_));
            float a0 = __expf(m0_ - M), a1 = __expf(m1_ - M);
            float a2 = __expf(m2_ - M), a3 = __expf(m3_ - M);
            float L = a0 * lred[0][qt][c] + a1 * lred[1][qt][c]
                    + a2 * lred[2][qt][c] + a3 * lred[3][qt][c];
            float inv = 1.f / L;
#pragma unroll
            for (int dt = 0; dt < 2; ++dt) {
                f32x4 o1 = *(const f32x4*)&Osh[0][dt][qt][lane][0];
                f32x4 o2 = *(const f32x4*)&Osh[1][dt][qt][lane][0];
                f32x4 o3 = *(const f32x4*)&Osh[2][dt][qt][lane][0];
                float4 r;
                r.x = (acc_o[dt][qt][0] * a0 + o1[0] * a1 + o2[0] * a2 + o3[0] * a3) * inv;
                r.y = (acc_o[dt][qt][1] * a0 + o1[1] * a1 + o2[1] * a2 + o3[1] * a3) * inv;
                r.z = (acc_o[dt][qt][2] * a0 + o1[2] * a1 + o2[2] * a2 + o3[2] * a3) * inv;
                r.w = (acc_o[dt][qt][3] * a0 + o1[3] * a1 + o2[3] * a2 + o3[3] * a3) * inv;
                *(float4*)(O + (qbase + qt * 16 + c) * CDIM + h * HD + dt * 16 + 4 * g) = r;
            }
        }
    }
}

// ---------------------------------------------------------------------------
// MFMA local windowed attention. Block = (row y, head h), grid (40, 8).
// 40 queries (pad->48 = 3 q-frags). Keys: 16 rows (y-7..y+8, row 15 pad)
// x 48 cols (40 + pad) = 768 keys = 48 frags; wave w owns frags 12w..12w+11
// (ky = 4w + i/3, fx = i%3). Single-pass softmax with global max (no online
// rescale). K in LDS Kp[key][40-pad] (frag rows = b128). V planar-transposed
// Vt[d][776-pad] -> PV A-operand is b128. P->B-frag via validated shuffle.
// Cross-wave O is a pure sum. LDS = 128 KB exactly -> 1 block/CU.
// ---------------------------------------------------------------------------
__global__ __launch_bounds__(256, 1) void local_mfma(const float* __restrict__ Q,
                                                     const float* __restrict__ K,
                                                     const float* __restrict__ V,
                                                     float* __restrict__ O) {
    __shared__ unsigned short Kp[768 * 40];     // 61440 B
    __shared__ unsigned short Vt[32 * 776];     // 49664 B
    __shared__ float mred[4][3][16];            // 768 B
    __shared__ float lred[4][3][16];            // 768 B
    __shared__ float Osh[3][2][3][64][4];       // 18432 B   (total 131072 B)
    int y = blockIdx.x, h = blockIdx.y;
    int tid = threadIdx.x;
    int w = tid >> 6, lane = tid & 63;
    int g = lane >> 4, c = lane & 15;

    // ---- stage K (frag-row layout) and V (planar transposed) ----
#pragma unroll 4
    for (int rep = 0; rep < 24; ++rep) {
        int idx = rep * 256 + tid;              // 0..6143
        int key = idx >> 3, dq = idx & 7;       // key 0..767, d0 = 4*dq
        int ky = key / 48;
        int xx = key - 48 * ky;
        int yy = y + ky - 7;
        bool ok = (xx < 40) && (yy >= 0) && (yy < 40);
        float4 fk = make_float4(0.f, 0.f, 0.f, 0.f);
        float4 fv = make_float4(0.f, 0.f, 0.f, 0.f);
        if (ok) {
            int pos = (yy * 40 + xx) * CDIM + h * HD + 4 * dq;
            fk = *(const float4*)(K + pos);
            fv = *(const float4*)(V + pos);
        }
        *(uint2*)&Kp[key * 40 + 4 * dq] = make_uint2(pkbf(fk.x, fk.y), pkbf(fk.z, fk.w));
        int vb = (4 * dq) * 776 + key;
        Vt[vb] = f2bf(fv.x);
        Vt[vb + 776] = f2bf(fv.y);
        Vt[vb + 1552] = f2bf(fv.z);
        Vt[vb + 2328] = f2bf(fv.w);
    }

    // ---- Q fragments (bf16, pre-scaled); q >= 40 -> zeros ----
    short8 qfrag[3];
#pragma unroll
    for (int qt = 0; qt < 3; ++qt) {
        short8 s = { 0, 0, 0, 0, 0, 0, 0, 0 };
        int qx = qt * 16 + c;
        if (qx < 40) {
            const float* qp = Q + (y * 40 + qx) * CDIM + h * HD + g * 8;
            float4 f0 = *(const float4*)qp;
            float4 f1 = *(const float4*)(qp + 4);
            s[0] = (short)f2bf(f0.x * SCALE_QK); s[1] = (short)f2bf(f0.y * SCALE_QK);
            s[2] = (short)f2bf(f0.z * SCALE_QK); s[3] = (short)f2bf(f0.w * SCALE_QK);
            s[4] = (short)f2bf(f1.x * SCALE_QK); s[5] = (short)f2bf(f1.y * SCALE_QK);
            s[6] = (short)f2bf(f1.z * SCALE_QK); s[7] = (short)f2bf(f1.w * SCALE_QK);
        }
        qfrag[qt] = s;
    }
    __syncthreads();

    // ---- QK^T: 12 key-frags x 3 q-frags per wave ----
    f32x4 sfr[12][3];
    const f32x4 zf = { 0.f, 0.f, 0.f, 0.f };
#pragma unroll
    for (int i = 0; i < 12; ++i) {
        int ky = 4 * w + i / 3;
        int fx = i % 3;
        short8 kf = *(const short8*)&Kp[(ky * 48 + fx * 16 + c) * 40 + 8 * g];
#pragma unroll
        for (int qt = 0; qt < 3; ++qt)
            sfr[i][qt] = __builtin_amdgcn_mfma_f32_16x16x32_bf16(kf, qfrag[qt], zf, 0, 0, 0);
    }

    // ---- mask + wave max ----
    float mw[3] = { -1e30f, -1e30f, -1e30f };
#pragma unroll
    for (int i = 0; i < 12; ++i) {
        int ky = 4 * w + i / 3, fx = i % 3;
        int yy = y + ky - 7;
        bool rowok = (yy >= 0) && (yy < 40);
        int xxb = fx * 16 + 4 * g;
#pragma unroll
        for (int qt = 0; qt < 3; ++qt) {
            int qx = qt * 16 + c;
#pragma unroll
            for (int r = 0; r < 4; ++r) {
                int xx = xxb + r;
                int dd = xx - qx;
                bool ok = rowok && (xx < 40) && (dd <= 7) && (dd >= -7);
                float v = ok ? sfr[i][qt][r] : -1e9f;
                sfr[i][qt][r] = v;
                mw[qt] = fmaxf(mw[qt], v);
            }
        }
    }
#pragma unroll
    for (int qt = 0; qt < 3; ++qt) {
        mw[qt] = fmaxf(mw[qt], __shfl_xor(mw[qt], 16, 64));
        mw[qt] = fmaxf(mw[qt], __shfl_xor(mw[qt], 32, 64));
    }
    if (lane < 16) {
#pragma unroll
        for (int qt = 0; qt < 3; ++qt) mred[w][qt][lane] = mw[qt];
    }
    __syncthreads();
    float M[3];
#pragma unroll
    for (int qt = 0; qt < 3; ++qt)
        M[qt] = fmaxf(fmaxf(mred[0][qt][c], mred[1][qt][c]),
                      fmaxf(mred[2][qt][c], mred[3][qt][c]));

    // ---- exp + P-frag build + PV (6 chunks of 32 keys per wave) ----
    float lsum[3] = { 0.f, 0.f, 0.f };
    f32x4 acc_o[2][3] = {};
    int src_lo = 16 * ((2 * g) & 3) + c;
    int src_hi = 16 * ((2 * g + 1) & 3) + c;
    bool hisel = (g >= 2);
#pragma unroll
    for (int chk = 0; chk < 6; ++chk) {
        short8 pfrag[3];
#pragma unroll
        for (int qt = 0; qt < 3; ++qt) {
            float p00 = __expf(sfr[2 * chk][qt][0] - M[qt]);
            float p01 = __expf(sfr[2 * chk][qt][1] - M[qt]);
            float p02 = __expf(sfr[2 * chk][qt][2] - M[qt]);
            float p03 = __expf(sfr[2 * chk][qt][3] - M[qt]);
            float p10 = __expf(sfr[2 * chk + 1][qt][0] - M[qt]);
            float p11 = __expf(sfr[2 * chk + 1][qt][1] - M[qt]);
            float p12 = __expf(sfr[2 * chk + 1][qt][2] - M[qt]);
            float p13 = __expf(sfr[2 * chk + 1][qt][3] - M[qt]);
            lsum[qt] += ((p00 + p01) + (p02 + p03)) + ((p10 + p11) + (p12 + p13));
            unsigned w00 = pkbf(p00, p01), w01 = pkbf(p02, p03);
            unsigned w10 = pkbf(p10, p11), w11 = pkbf(p12, p13);
            unsigned a0 = __shfl(w00, src_lo, 64);
            unsigned a1 = __shfl(w10, src_lo, 64);
            unsigned b0 = __shfl(w01, src_lo, 64);
            unsigned b1 = __shfl(w11, src_lo, 64);
            unsigned c0 = __shfl(w00, src_hi, 64);
            unsigned c1 = __shfl(w10, src_hi, 64);
            unsigned d0 = __shfl(w01, src_hi, 64);
            unsigned d1 = __shfl(w11, src_hi, 64);
            union { short8 s8; unsigned u[4]; } P;
            P.u[0] = hisel ? a1 : a0;
            P.u[1] = hisel ? b1 : b0;
            P.u[2] = hisel ? c1 : c0;
            P.u[3] = hisel ? d1 : d0;
            pfrag[qt] = P.s8;
        }
        int jb = 32 * (6 * w + chk);
        short8 vf0 = *(const short8*)&Vt[c * 776 + jb + 8 * g];
        short8 vf1 = *(const short8*)&Vt[(16 + c) * 776 + jb + 8 * g];
#pragma unroll
        for (int qt = 0; qt < 3; ++qt) {
            acc_o[0][qt] = __builtin_amdgcn_mfma_f32_16x16x32_bf16(vf0, pfrag[qt], acc_o[0][qt], 0, 0, 0);
            acc_o[1][qt] = __builtin_amdgcn_mfma_f32_16x16x32_bf16(vf1, pfrag[qt], acc_o[1][qt], 0, 0, 0);
        }
    }

    // ---- cross-wave reduce (pure sum: shared global max) + output ----
#pragma unroll
    for (int qt = 0; qt < 3; ++qt) {
        lsum[qt] += __shfl_xor(lsum[qt], 16, 64);
        lsum[qt] += __shfl_xor(lsum[qt], 32, 64);
    }
    if (lane < 16) {
#pragma unroll
        for (int qt = 0; qt < 3; ++qt) lred[w][qt][lane] = lsum[qt];
    }
    if (w > 0) {
#pragma unroll
        for (int dt = 0; dt < 2; ++dt)
#pragma unroll
            for (int qt = 0; qt < 3; ++qt)
                *(f32x4*)&Osh[w - 1][dt][qt][lane][0] = acc_o[dt][qt];
    }
    __syncthreads();
    if (w == 0) {
#pragma unroll
        for (int qt = 0; qt < 3; ++qt) {
            int qx = qt * 16 + c;
            if (qx >= 40) continue;
            float L = (lred[0][qt][c] + lred[1][qt][c]) + (lred[2][qt][c] + lred[3][qt][c]);
            float inv = 1.f / L;
#pragma unroll
            for (int dt = 0; dt < 2; ++dt) {
                f32x4 o1 = *(const f32x4*)&Osh[0][dt][qt][lane][0];
                f32x4 o2 = *(const f32x4*)&Osh[1][dt][qt][lane][0];
                f32x4 o3 = *(const f32x4*)&Osh[2][dt][qt][lane][0];
                float4 r;
                r.x = (acc_o[dt][qt][0] + o1[0] + o2[0] + o3[0]) * inv;
                r.y = (acc_o[dt][qt][1] + o1[1] + o2[1] + o3[1]) * inv;
                r.z = (acc_o[dt][qt][2] + o1[2] + o2[2] + o3[2]) * inv;
                r.w = (acc_o[dt][qt][3] + o1[3] + o2[3] + o3[3]) * inv;
                *(float4*)(O + (y * 40 + qx) * CDIM + h * HD + dt * 16 + 4 * g) = r;
            }
        }
    }
}

// build curr_Q (contiguous), global_K, global_V from qv (1600x512) and idkv (1600x264)
__global__ __launch_bounds__(256) void make_qkv_kernel(const float* __restrict__ qv,
                                                       const float* __restrict__ idkv,
                                                       float* __restrict__ Qc,
                                                       float* __restrict__ gK,
                                                       float* __restrict__ gV) {
    int idx = blockIdx.x * 256 + threadIdx.x;
    if (idx >= L_SEQ * CDIM) return;
    int l = idx >> 8, c = idx & 255;
    int h = c >> 5;
    float q = qv[l * 512 + c];
    Qc[idx] = q;
    gK[idx] = q * (1.f + tanhf(idkv[l * 264 + h]));
    gV[idx] = qv[l * 512 + 256 + c] + idkv[l * 264 + 8 + c];
}

// GroupNorm partials: grid (32 groups, 8 chunks); deterministic partial sums.
__global__ __launch_bounds__(256) void gn_partial(const float* __restrict__ X,
                                                  float* __restrict__ gstat) {
    __shared__ float sh4[4];
    int g = blockIdx.x, chunk = blockIdx.y;
    int base = g * 32;
    float s = 0.f, s2 = 0.f;
    for (int i = threadIdx.x; i < 200 * 32; i += 256) {
        int l = chunk * 200 + (i >> 5), c = i & 31;
        float v = X[l * DFF_ + base + c];
        s += v;
        s2 += v * v;
    }
    s = blockReduceSum(s, sh4);
    s2 = blockReduceSum(s2, sh4);
    if (threadIdx.x == 0) {
        gstat[g * 8 + chunk] = s;
        gstat[256 + g * 8 + chunk] = s2;
    }
}

// GroupNorm apply + exact GELU, float4-vectorized. 1600 blocks x 256 thr.
__global__ __launch_bounds__(256) void gn_apply(const float* __restrict__ X,
                                                const float* __restrict__ gstat,
                                                const float* __restrict__ g,
                                                const float* __restrict__ b,
                                                float* __restrict__ Y) {
    int idx = blockIdx.x * 256 + threadIdx.x;
    int e4 = idx * 4;
    int c = e4 & 1023;
    int grp = c >> 5;
    float s = 0.f, s2 = 0.f;
#pragma unroll
    for (int i = 0; i < 8; ++i) {
        s += gstat[grp * 8 + i];
        s2 += gstat[256 + grp * 8 + i];
    }
    const float invn = 1.0f / 51200.f;
    float mean = s * invn;
    float rs = rsqrtf(s2 * invn - mean * mean + 1e-5f);
    float4 v = *(const float4*)(X + e4);
    float4 gg = *(const float4*)(g + c);
    float4 bb = *(const float4*)(b + c);
    float4 r;
    float y0 = (v.x - mean) * rs * gg.x + bb.x;
    float y1 = (v.y - mean) * rs * gg.y + bb.y;
    float y2 = (v.z - mean) * rs * gg.z + bb.z;
    float y3 = (v.w - mean) * rs * gg.w + bb.w;
    r.x = 0.5f * y0 * (1.0f + erff(y0 * 0.70710678118654752f));
    r.y = 0.5f * y1 * (1.0f + erff(y1 * 0.70710678118654752f));
    r.z = 0.5f * y2 * (1.0f + erff(y2 * 0.70710678118654752f));
    r.w = 0.5f * y3 * (1.0f + erff(y3 * 0.70710678118654752f));
    *(float4*)(Y + e4) = r;
}

// depthwise 5x5 conv, pad 2 (cross-correlation). X,Y (1600,1024) l-major; Kw (1024,25)
__global__ __launch_bounds__(256) void dwconv_kernel(const float* __restrict__ X,
                                                     const float* __restrict__ Kw,
                                                     float* __restrict__ Y) {
    int idx = blockIdx.x * 256 + threadIdx.x;
    if (idx >= L_SEQ * DFF_) return;
    int c = idx & 1023, l = idx >> 10;
    int y = l / GRID_W, x = l % GRID_W;
    float acc = 0.f;
#pragma unroll
    for (int ky = 0; ky < 5; ++ky) {
        int yy = y + ky - 2;
        if (yy < 0 || yy >= GRID_H) continue;
#pragma unroll
        for (int kx = 0; kx < 5; ++kx) {
            int xx = x + kx - 2;
            if (xx < 0 || xx >= GRID_W) continue;
            acc += X[(yy * GRID_W + xx) * DFF_ + c] * Kw[c * 25 + ky * 5 + kx];
        }
    }
    Y[idx] = acc;
}

extern "C" void kernel_launch(void* const* d_in, const int* in_sizes, int n_in,
                              void* d_out, int out_size, void* d_ws, size_t ws_size,
                              hipStream_t stream) {
    (void)in_sizes; (void)n_in; (void)out_size; (void)ws_size;
    const float* tgt = (const float*)d_in[0];
    const float* curr_id_emb = (const float*)d_in[1];
    const float* self_pos = (const float*)d_in[2];
    const float* ln1_g = (const float*)d_in[3];
    const float* ln1_b = (const float*)d_in[4];
    const float* sa_wq = (const float*)d_in[5];
    const float* sa_bq = (const float*)d_in[6];
    const float* sa_wk = (const float*)d_in[7];
    const float* sa_bk = (const float*)d_in[8];
    const float* sa_wv = (const float*)d_in[9];
    const float* sa_bv = (const float*)d_in[10];
    const float* sa_wo = (const float*)d_in[11];
    const float* sa_bo = (const float*)d_in[12];
    const float* ln2_g = (const float*)d_in[13];
    const float* ln2_b = (const float*)d_in[14];
    const float* w_qv = (const float*)d_in[15];
    const float* b_qv = (const float*)d_in[16];
    const float* w_id = (const float*)d_in[17];
    const float* b_id = (const float*)d_in[18];
    const float* lt_wo = (const float*)d_in[19];
    const float* lt_bo = (const float*)d_in[20];
    const float* st_wo = (const float*)d_in[21];
    const float* st_bo = (const float*)d_in[22];
    const float* ln3_g = (const float*)d_in[23];
    const float* ln3_b = (const float*)d_in[24];
    const float* w1 = (const float*)d_in[25];
    const float* b1 = (const float*)d_in[26];
    const float* gn_g = (const float*)d_in[27];
    const float* gn_b = (const float*)d_in[28];
    const float* dw_k = (const float*)d_in[29];
    const float* w2 = (const float*)d_in[30];
    const float* b2 = (const float*)d_in[31];
    float* out = (float*)d_out;

    float* ws = (float*)d_ws;
    const int LC = L_SEQ * CDIM;           // 409600
    float* bufA = ws;                      // _t
    float* bufB = bufA + LC;               // qk_in / tgt1+tgt2
    float* bufC = bufB + LC;               // q_ / curr_Q
    float* bufD = bufC + LC;               // k_ / global_K
    float* bufE = bufD + LC;               // v_ / global_V
    float* bufF = bufE + LC;               // attn outs
    float* bufG = bufF + LC;               // tgt1 / tgt_b
    float* bufH = bufG + LC;               // qv (1600x512); later: gstat
    float* bufI = bufH + L_SEQ * 512;      // idkv (1600x264)
    float* bufX = bufI + L_SEQ * 264;      // w1 out (1600x1024)
    float* bufY = bufX + L_SEQ * DFF_;     // gn+gelu out
    float* bufZ = bufY + L_SEQ * DFF_;     // conv out

    dim3 blk(256);
    dim3 g256(4, 25), g264(5, 25), g512(8, 25), g1024(16, 25);
    dim3 mhaGrid(L_SEQ / QBLK, NH);

    // 1. LN1: bufA = ln(tgt), bufB = bufA + self_pos
    ln_kernel<<<L_SEQ, blk, 0, stream>>>(tgt, ln1_g, ln1_b, self_pos, bufA, bufB);
    // 2-4. q,k,v projections
    gemm_mfma<<<g256, blk, 0, stream>>>(bufB, sa_wq, sa_bq, nullptr, bufC, L_SEQ, CDIM, CDIM);
    gemm_mfma<<<g256, blk, 0, stream>>>(bufB, sa_wk, sa_bk, nullptr, bufD, L_SEQ, CDIM, CDIM);
    gemm_mfma<<<g256, blk, 0, stream>>>(bufA, sa_wv, sa_bv, nullptr, bufE, L_SEQ, CDIM, CDIM);
    // 5. self attention
    mha_mfma<<<mhaGrid, blk, 0, stream>>>(bufC, bufD, bufE, bufF);
    // 6. out proj + residual -> tgt1 (bufG)
    gemm_mfma<<<g256, blk, 0, stream>>>(bufF, sa_wo, sa_bo, tgt, bufG, L_SEQ, CDIM, CDIM);
    // 7. LN2 -> bufA
    ln_kernel<<<L_SEQ, blk, 0, stream>>>(bufG, ln2_g, ln2_b, nullptr, bufA, nullptr);
    // 8. qv = bufA @ w_qv^T -> bufH (1600x512)
    gemm_mfma<<<g512, blk, 0, stream>>>(bufA, w_qv, b_qv, nullptr, bufH, L_SEQ, 512, CDIM);
    // 9. idkv = curr_id_emb @ w_id^T -> bufI (1600x264)
    gemm_mfma<<<g264, blk, 0, stream>>>(curr_id_emb, w_id, b_id, nullptr, bufI, L_SEQ, 264, CDIM);
    // 10. curr_Q (bufC), global_K (bufD), global_V (bufE)
    make_qkv_kernel<<<L_SEQ, blk, 0, stream>>>(bufH, bufI, bufC, bufD, bufE);
    // 11. long-term attention
    mha_mfma<<<mhaGrid, blk, 0, stream>>>(bufC, bufD, bufE, bufF);
    // 12. lt out proj + residual(tgt1) -> bufB
    gemm_mfma<<<g256, blk, 0, stream>>>(bufF, lt_wo, lt_bo, bufG, bufB, L_SEQ, CDIM, CDIM);
    // 13. local attention (MFMA) -> bufF
    local_mfma<<<dim3(GRID_H, NH), blk, 0, stream>>>(bufC, bufD, bufE, bufF);
    // 14. st out proj + residual(bufB) -> tgt_b (bufG)
    gemm_mfma<<<g256, blk, 0, stream>>>(bufF, st_wo, st_bo, bufB, bufG, L_SEQ, CDIM, CDIM);
    // 15. LN3 -> bufA
    ln_kernel<<<L_SEQ, blk, 0, stream>>>(bufG, ln3_g, ln3_b, nullptr, bufA, nullptr);
    // 16. x = bufA @ w1^T -> bufX (1600x1024)
    gemm_mfma<<<g1024, blk, 0, stream>>>(bufA, w1, b1, nullptr, bufX, L_SEQ, DFF_, CDIM);
    // 17. GroupNorm + GELU -> bufY  (bufH is dead; reuse as gstat)
    gn_partial<<<dim3(32, 8), blk, 0, stream>>>(bufX, bufH);
    gn_apply<<<L_SEQ, blk, 0, stream>>>(bufX, bufH, gn_g, gn_b, bufY);
    // 18. depthwise conv -> bufZ
    dwconv_kernel<<<(L_SEQ * DFF_ + 255) / 256, blk, 0, stream>>>(bufY, dw_k, bufZ);
    // 19. final proj + residual(tgt_b) -> out
    gemm_mfma<<<g256, blk, 0, stream>>>(bufZ, w2, b2, bufG, out, L_SEQ, CDIM, DFF_);
}

// Round 8
// 383.542 us; speedup vs baseline: 4.9634x; 1.0884x over previous
//
#include <hip/hip_runtime.h>
#include <math.h>

#define L_SEQ 1600
#define CDIM 256
#define NH 8
#define HD 32
#define GRID_H 40
#define GRID_W 40
#define DFF_ 1024
#define WS_ 15
#define WIN 225
#define MAXD 7
#define SCALE_QK 0.17677669529663687f

typedef __attribute__((ext_vector_type(8))) short short8;
typedef __attribute__((ext_vector_type(4))) float f32x4;

__device__ __forceinline__ float waveReduceSum(float v) {
#pragma unroll
    for (int off = 32; off > 0; off >>= 1) v += __shfl_down(v, off, 64);
    return v;
}
// block of exactly 256 threads (4 waves)
__device__ __forceinline__ float blockReduceSum(float v, float* sh4) {
    v = waveReduceSum(v);
    int lane = threadIdx.x & 63, wid = threadIdx.x >> 6;
    __syncthreads();
    if (lane == 0) sh4[wid] = v;
    __syncthreads();
    return sh4[0] + sh4[1] + sh4[2] + sh4[3];
}

__device__ __forceinline__ unsigned short f2bf(float x) {
    union { float f; unsigned u; } v; v.f = x;
    unsigned r = (v.u + 0x7FFFu + ((v.u >> 16) & 1u)) >> 16;
    return (unsigned short)r;
}
__device__ __forceinline__ unsigned pkbf(float lo, float hi) {
    return (unsigned)f2bf(lo) | ((unsigned)f2bf(hi) << 16);
}

// LayerNorm over C=256; one block (256 thr) per row. out2 = out + addin (optional)
__global__ __launch_bounds__(256) void ln_kernel(const float* __restrict__ x,
                                                 const float* __restrict__ g,
                                                 const float* __restrict__ b,
                                                 const float* __restrict__ addin,
                                                 float* __restrict__ out,
                                                 float* __restrict__ out2) {
    __shared__ float sh4[4];
    int row = blockIdx.x;
    int c = threadIdx.x;
    float v = x[row * CDIM + c];
    float mean = blockReduceSum(v, sh4) * (1.0f / CDIM);
    float d = v - mean;
    float var = blockReduceSum(d * d, sh4) * (1.0f / CDIM);
    float y = d * rsqrtf(var + 1e-5f) * g[c] + b[c];
    out[row * CDIM + c] = y;
    if (out2) out2[row * CDIM + c] = y + addin[row * CDIM + c];
}

// ---------------------------------------------------------------------------
// bf16 MFMA GEMM (unchanged, verified)
// ---------------------------------------------------------------------------
__global__ __launch_bounds__(256) void gemm_mfma(const float* __restrict__ A,
                                                 const float* __restrict__ W,
                                                 const float* __restrict__ bias,
                                                 const float* __restrict__ res,
                                                 float* __restrict__ C,
                                                 int M, int N, int K) {
    __shared__ unsigned short Al[2][4][64][8];   // 8KB
    __shared__ unsigned short Bl[2][4][64][8];   // 8KB
    int tid = threadIdx.x;
    int bm = blockIdx.y * 64, bn = blockIdx.x * 64;
    int lane = tid & 63, wave = tid >> 6;
    int wr = wave >> 1, wc = wave & 1;

    int srow = tid >> 3;
    int q = tid & 7;
    int e0 = (q & 1) * 4;

    f32x4 acc[2][2] = {};
    int nsteps = K >> 5;

    float4 ra[2], rb[2];
    {
        int k0 = 0;
#pragma unroll
        for (int r = 0; r < 2; ++r) {
            int row = srow + 32 * r;
            ra[r] = *(const float4*)(A + (bm + row) * K + k0 + 4 * q);
            int n = bn + row;
            rb[r] = (n < N) ? *(const float4*)(W + n * K + k0 + 4 * q)
                            : make_float4(0.f, 0.f, 0.f, 0.f);
        }
#pragma unroll
        for (int r = 0; r < 2; ++r) {
            int row = srow + 32 * r;
            int frag = (row >> 4), l = (row & 15) + 16 * (q >> 1);
            unsigned pa0 = ((unsigned)f2bf(ra[r].x)) | (((unsigned)f2bf(ra[r].y)) << 16);
            unsigned pa1 = ((unsigned)f2bf(ra[r].z)) | (((unsigned)f2bf(ra[r].w)) << 16);
            unsigned pb0 = ((unsigned)f2bf(rb[r].x)) | (((unsigned)f2bf(rb[r].y)) << 16);
            unsigned pb1 = ((unsigned)f2bf(rb[r].z)) | (((unsigned)f2bf(rb[r].w)) << 16);
            *(uint2*)&Al[0][frag][l][e0] = make_uint2(pa0, pa1);
            *(uint2*)&Bl[0][frag][l][e0] = make_uint2(pb0, pb1);
        }
    }
    __syncthreads();

    for (int s = 0; s < nsteps; ++s) {
        bool more = (s + 1) < nsteps;
        if (more) {
            int k0 = (s + 1) << 5;
#pragma unroll
            for (int r = 0; r < 2; ++r) {
                int row = srow + 32 * r;
                ra[r] = *(const float4*)(A + (bm + row) * K + k0 + 4 * q);
                int n = bn + row;
                rb[r] = (n < N) ? *(const float4*)(W + n * K + k0 + 4 * q)
                                : make_float4(0.f, 0.f, 0.f, 0.f);
            }
        }
        {
            int buf = s & 1;
            short8 af[2], bfr[2];
#pragma unroll
            for (int i = 0; i < 2; ++i) {
                af[i] = *(const short8*)&Al[buf][2 * wr + i][lane][0];
                bfr[i] = *(const short8*)&Bl[buf][2 * wc + i][lane][0];
            }
#pragma unroll
            for (int i = 0; i < 2; ++i)
#pragma unroll
                for (int j = 0; j < 2; ++j)
                    acc[i][j] = __builtin_amdgcn_mfma_f32_16x16x32_bf16(af[i], bfr[j], acc[i][j], 0, 0, 0);
        }
        if (more) {
            int buf = (s + 1) & 1;
#pragma unroll
            for (int r = 0; r < 2; ++r) {
                int row = srow + 32 * r;
                int frag = (row >> 4), l = (row & 15) + 16 * (q >> 1);
                unsigned pa0 = ((unsigned)f2bf(ra[r].x)) | (((unsigned)f2bf(ra[r].y)) << 16);
                unsigned pa1 = ((unsigned)f2bf(ra[r].z)) | (((unsigned)f2bf(ra[r].w)) << 16);
                unsigned pb0 = ((unsigned)f2bf(rb[r].x)) | (((unsigned)f2bf(rb[r].y)) << 16);
                unsigned pb1 = ((unsigned)f2bf(rb[r].z)) | (((unsigned)f2bf(rb[r].w)) << 16);
                *(uint2*)&Al[buf][frag][l][e0] = make_uint2(pa0, pa1);
                *(uint2*)&Bl[buf][frag][l][e0] = make_uint2(pb0, pb1);
            }
        }
        __syncthreads();
    }

#pragma unroll
    for (int j = 0; j < 2; ++j) {
        int col = bn + wc * 32 + j * 16 + (lane & 15);
        if (col >= N) continue;
        float bv = bias ? bias[col] : 0.f;
#pragma unroll
        for (int i = 0; i < 2; ++i) {
            int rbase = bm + wr * 32 + i * 16 + ((lane >> 4) << 2);
#pragma unroll
            for (int r = 0; r < 4; ++r) {
                int row = rbase + r;
                float v = acc[i][j][r] + bv;
                if (res) v += res[row * N + col];
                C[row * N + col] = v;
            }
        }
    }
    (void)M;
}

// ---------------------------------------------------------------------------
// MFMA flash attention (unchanged, verified)
// ---------------------------------------------------------------------------
#define QBLK 32
#define KTJ 128
__global__ __launch_bounds__(256) void mha_mfma(const float* __restrict__ Q,
                                                const float* __restrict__ K,
                                                const float* __restrict__ V,
                                                float* __restrict__ O) {
    __shared__ unsigned short Kl[8][64][8];
    __shared__ unsigned short Vl[4][2][64][12];
    __shared__ float mred[4][2][16];
    __shared__ float lred[4][2][16];
    __shared__ float Osh[3][2][2][64][4];
    int h = blockIdx.y;
    int qbase = blockIdx.x * QBLK;
    int tid = threadIdx.x;
    int w = tid >> 6, lane = tid & 63;
    int g = lane >> 4, c = lane & 15;

    short8 qfrag[2];
#pragma unroll
    for (int qt = 0; qt < 2; ++qt) {
        const float* qp = Q + (qbase + qt * 16 + c) * CDIM + h * HD + g * 8;
        float4 f0 = *(const float4*)qp;
        float4 f1 = *(const float4*)(qp + 4);
        short8 s;
        s[0] = (short)f2bf(f0.x * SCALE_QK); s[1] = (short)f2bf(f0.y * SCALE_QK);
        s[2] = (short)f2bf(f0.z * SCALE_QK); s[3] = (short)f2bf(f0.w * SCALE_QK);
        s[4] = (short)f2bf(f1.x * SCALE_QK); s[5] = (short)f2bf(f1.y * SCALE_QK);
        s[6] = (short)f2bf(f1.z * SCALE_QK); s[7] = (short)f2bf(f1.w * SCALE_QK);
        qfrag[qt] = s;
    }

    float m[2] = { -INFINITY, -INFINITY };
    float l[2] = { 0.f, 0.f };
    f32x4 acc_o[2][2] = {};

    int jrow = tid >> 1;
    int dhalf = (tid & 1) * 16;
    int vjq = tid >> 3;
    int vdq = tid & 7;
    int vjr = 4 * vjq;
    int vd0 = 4 * vdq;
    int vjc = vjr >> 5, vdt = vd0 >> 4, vjg = (vjr & 31) >> 3, ve0 = vjr & 7;

    int src_lo = 16 * ((2 * g) & 3) + c;
    int src_hi = 16 * ((2 * g + 1) & 3) + c;
    bool hisel = (g >= 2);

    for (int t = 0; t < L_SEQ; t += KTJ) {
        {
            int j = t + jrow;
            float4 f0, f1, f2, f3;
            if (j < L_SEQ) {
                const float4* kp = (const float4*)(K + j * CDIM + h * HD + dhalf);
                f0 = kp[0]; f1 = kp[1]; f2 = kp[2]; f3 = kp[3];
            } else {
                f0 = f1 = f2 = f3 = make_float4(0.f, 0.f, 0.f, 0.f);
            }
            int jt = jrow >> 4;
            int laneA = (jrow & 15) + dhalf * 2;
            short8 s0, s1;
            s0[0]=f2bf(f0.x); s0[1]=f2bf(f0.y); s0[2]=f2bf(f0.z); s0[3]=f2bf(f0.w);
            s0[4]=f2bf(f1.x); s0[5]=f2bf(f1.y); s0[6]=f2bf(f1.z); s0[7]=f2bf(f1.w);
            s1[0]=f2bf(f2.x); s1[1]=f2bf(f2.y); s1[2]=f2bf(f2.z); s1[3]=f2bf(f2.w);
            s1[4]=f2bf(f3.x); s1[5]=f2bf(f3.y); s1[6]=f2bf(f3.z); s1[7]=f2bf(f3.w);
            *(short8*)&Kl[jt][laneA][0] = s0;
            *(short8*)&Kl[jt][laneA + 16][0] = s1;
        }
        {
            float4 r0, r1, r2, r3;
            int j0 = t + vjr;
            const float* vb = V + h * HD + vd0;
            r0 = (j0 + 0 < L_SEQ) ? *(const float4*)(vb + (j0 + 0) * CDIM) : make_float4(0,0,0,0);
            r1 = (j0 + 1 < L_SEQ) ? *(const float4*)(vb + (j0 + 1) * CDIM) : make_float4(0,0,0,0);
            r2 = (j0 + 2 < L_SEQ) ? *(const float4*)(vb + (j0 + 2) * CDIM) : make_float4(0,0,0,0);
            r3 = (j0 + 3 < L_SEQ) ? *(const float4*)(vb + (j0 + 3) * CDIM) : make_float4(0,0,0,0);
            float col[4][4] = {
                { r0.x, r1.x, r2.x, r3.x },
                { r0.y, r1.y, r2.y, r3.y },
                { r0.z, r1.z, r2.z, r3.z },
                { r0.w, r1.w, r2.w, r3.w } };
#pragma unroll
            for (int dd = 0; dd < 4; ++dd) {
                int laneV = ((vd0 + dd) & 15) + 16 * vjg;
                uint2 pk;
                pk.x = pkbf(col[dd][0], col[dd][1]);
                pk.y = pkbf(col[dd][2], col[dd][3]);
                *(uint2*)&Vl[vjc][vdt][laneV][ve0] = pk;
            }
        }
        __syncthreads();

        bool alive = (t + 32 * w) < L_SEQ;
        if (alive) {
            short8 kf0 = *(const short8*)&Kl[2 * w][lane][0];
            short8 kf1 = *(const short8*)&Kl[2 * w + 1][lane][0];
            f32x4 zero = { 0.f, 0.f, 0.f, 0.f };
            f32x4 s[2][2];
            s[0][0] = __builtin_amdgcn_mfma_f32_16x16x32_bf16(kf0, qfrag[0], zero, 0, 0, 0);
            s[0][1] = __builtin_amdgcn_mfma_f32_16x16x32_bf16(kf0, qfrag[1], zero, 0, 0, 0);
            s[1][0] = __builtin_amdgcn_mfma_f32_16x16x32_bf16(kf1, qfrag[0], zero, 0, 0, 0);
            s[1][1] = __builtin_amdgcn_mfma_f32_16x16x32_bf16(kf1, qfrag[1], zero, 0, 0, 0);

            short8 pfrag[2];
#pragma unroll
            for (int qt = 0; qt < 2; ++qt) {
                float mx = s[0][qt][0];
                mx = fmaxf(mx, s[0][qt][1]); mx = fmaxf(mx, s[0][qt][2]); mx = fmaxf(mx, s[0][qt][3]);
                mx = fmaxf(mx, s[1][qt][0]); mx = fmaxf(mx, s[1][qt][1]);
                mx = fmaxf(mx, s[1][qt][2]); mx = fmaxf(mx, s[1][qt][3]);
                mx = fmaxf(mx, __shfl_xor(mx, 16, 64));
                mx = fmaxf(mx, __shfl_xor(mx, 32, 64));
                float nm = fmaxf(m[qt], mx);
                float alpha = __expf(m[qt] - nm);
                m[qt] = nm;
                float p00 = __expf(s[0][qt][0] - nm), p01 = __expf(s[0][qt][1] - nm);
                float p02 = __expf(s[0][qt][2] - nm), p03 = __expf(s[0][qt][3] - nm);
                float p10 = __expf(s[1][qt][0] - nm), p11 = __expf(s[1][qt][1] - nm);
                float p12 = __expf(s[1][qt][2] - nm), p13 = __expf(s[1][qt][3] - nm);
                float ts = ((p00 + p01) + (p02 + p03)) + ((p10 + p11) + (p12 + p13));
                ts += __shfl_xor(ts, 16, 64);
                ts += __shfl_xor(ts, 32, 64);
                l[qt] = l[qt] * alpha + ts;
#pragma unroll
                for (int dt = 0; dt < 2; ++dt) {
                    acc_o[dt][qt][0] *= alpha; acc_o[dt][qt][1] *= alpha;
                    acc_o[dt][qt][2] *= alpha; acc_o[dt][qt][3] *= alpha;
                }
                unsigned w00 = pkbf(p00, p01), w01 = pkbf(p02, p03);
                unsigned w10 = pkbf(p10, p11), w11 = pkbf(p12, p13);
                unsigned a0 = __shfl(w00, src_lo, 64);
                unsigned a1 = __shfl(w10, src_lo, 64);
                unsigned b0 = __shfl(w01, src_lo, 64);
                unsigned b1 = __shfl(w11, src_lo, 64);
                unsigned c0 = __shfl(w00, src_hi, 64);
                unsigned c1 = __shfl(w10, src_hi, 64);
                unsigned d0 = __shfl(w01, src_hi, 64);
                unsigned d1 = __shfl(w11, src_hi, 64);
                union { short8 s8; unsigned u[4]; } P;
                P.u[0] = hisel ? a1 : a0;
                P.u[1] = hisel ? b1 : b0;
                P.u[2] = hisel ? c1 : c0;
                P.u[3] = hisel ? d1 : d0;
                pfrag[qt] = P.s8;
            }

            union { short8 s8; uint2 v[2]; } vf0u, vf1u;
            vf0u.v[0] = *(const uint2*)&Vl[w][0][lane][0];
            vf0u.v[1] = *(const uint2*)&Vl[w][0][lane][4];
            vf1u.v[0] = *(const uint2*)&Vl[w][1][lane][0];
            vf1u.v[1] = *(const uint2*)&Vl[w][1][lane][4];
            acc_o[0][0] = __builtin_amdgcn_mfma_f32_16x16x32_bf16(vf0u.s8, pfrag[0], acc_o[0][0], 0, 0, 0);
            acc_o[0][1] = __builtin_amdgcn_mfma_f32_16x16x32_bf16(vf0u.s8, pfrag[1], acc_o[0][1], 0, 0, 0);
            acc_o[1][0] = __builtin_amdgcn_mfma_f32_16x16x32_bf16(vf1u.s8, pfrag[0], acc_o[1][0], 0, 0, 0);
            acc_o[1][1] = __builtin_amdgcn_mfma_f32_16x16x32_bf16(vf1u.s8, pfrag[1], acc_o[1][1], 0, 0, 0);
        }
        __syncthreads();
    }

    if (g == 0) {
#pragma unroll
        for (int qt = 0; qt < 2; ++qt) { mred[w][qt][c] = m[qt]; lred[w][qt][c] = l[qt]; }
    }
    if (w > 0) {
#pragma unroll
        for (int dt = 0; dt < 2; ++dt)
#pragma unroll
            for (int qt = 0; qt < 2; ++qt)
                *(f32x4*)&Osh[w - 1][dt][qt][lane][0] = acc_o[dt][qt];
    }
    __syncthreads();
    if (w == 0) {
#pragma unroll
        for (int qt = 0; qt < 2; ++qt) {
            float m0_ = mred[0][qt][c], m1_ = mred[1][qt][c];
            float m2_ = mred[2][qt][c], m3_ = mred[3][qt][c];
            float M = fmaxf(fmaxf(m0_, m1_), fmaxf(m2_, m3_));
            float a0 = __expf(m0_ - M), a1 = __expf(m1_ - M);
            float a2 = __expf(m2_ - M), a3 = __expf(m3_ - M);
            float L = a0 * lred[0][qt][c] + a1 * lred[1][qt][c]
                    + a2 * lred[2][qt][c] + a3 * lred[3][qt][c];
            float inv = 1.f / L;
#pragma unroll
            for (int dt = 0; dt < 2; ++dt) {
                f32x4 o1 = *(const f32x4*)&Osh[0][dt][qt][lane][0];
                f32x4 o2 = *(const f32x4*)&Osh[1][dt][qt][lane][0];
                f32x4 o3 = *(const f32x4*)&Osh[2][dt][qt][lane][0];
                float4 r;
                r.x = (acc_o[dt][qt][0] * a0 + o1[0] * a1 + o2[0] * a2 + o3[0] * a3) * inv;
                r.y = (acc_o[dt][qt][1] * a0 + o1[1] * a1 + o2[1] * a2 + o3[1] * a3) * inv;
                r.z = (acc_o[dt][qt][2] * a0 + o1[2] * a1 + o2[2] * a2 + o3[2] * a3) * inv;
                r.w = (acc_o[dt][qt][3] * a0 + o1[3] * a1 + o2[3] * a2 + o3[3] * a3) * inv;
                *(float4*)(O + (qbase + qt * 16 + c) * CDIM + h * HD + dt * 16 + 4 * g) = r;
            }
        }
    }
}

// ---------------------------------------------------------------------------
// MFMA local windowed attention (unchanged, verified)
// ---------------------------------------------------------------------------
__global__ __launch_bounds__(256, 1) void local_mfma(const float* __restrict__ Q,
                                                     const float* __restrict__ K,
                                                     const float* __restrict__ V,
                                                     float* __restrict__ O) {
    __shared__ unsigned short Kp[768 * 40];     // 61440 B
    __shared__ unsigned short Vt[32 * 776];     // 49664 B
    __shared__ float mred[4][3][16];            // 768 B
    __shared__ float lred[4][3][16];            // 768 B
    __shared__ float Osh[3][2][3][64][4];       // 18432 B   (total 131072 B)
    int y = blockIdx.x, h = blockIdx.y;
    int tid = threadIdx.x;
    int w = tid >> 6, lane = tid & 63;
    int g = lane >> 4, c = lane & 15;

#pragma unroll 4
    for (int rep = 0; rep < 24; ++rep) {
        int idx = rep * 256 + tid;
        int key = idx >> 3, dq = idx & 7;
        int ky = key / 48;
        int xx = key - 48 * ky;
        int yy = y + ky - 7;
        bool ok = (xx < 40) && (yy >= 0) && (yy < 40);
        float4 fk = make_float4(0.f, 0.f, 0.f, 0.f);
        float4 fv = make_float4(0.f, 0.f, 0.f, 0.f);
        if (ok) {
            int pos = (yy * 40 + xx) * CDIM + h * HD + 4 * dq;
            fk = *(const float4*)(K + pos);
            fv = *(const float4*)(V + pos);
        }
        *(uint2*)&Kp[key * 40 + 4 * dq] = make_uint2(pkbf(fk.x, fk.y), pkbf(fk.z, fk.w));
        int vb = (4 * dq) * 776 + key;
        Vt[vb] = f2bf(fv.x);
        Vt[vb + 776] = f2bf(fv.y);
        Vt[vb + 1552] = f2bf(fv.z);
        Vt[vb + 2328] = f2bf(fv.w);
    }

    short8 qfrag[3];
#pragma unroll
    for (int qt = 0; qt < 3; ++qt) {
        short8 s = { 0, 0, 0, 0, 0, 0, 0, 0 };
        int qx = qt * 16 + c;
        if (qx < 40) {
            const float* qp = Q + (y * 40 + qx) * CDIM + h * HD + g * 8;
            float4 f0 = *(const float4*)qp;
            float4 f1 = *(const float4*)(qp + 4);
            s[0] = (short)f2bf(f0.x * SCALE_QK); s[1] = (short)f2bf(f0.y * SCALE_QK);
            s[2] = (short)f2bf(f0.z * SCALE_QK); s[3] = (short)f2bf(f0.w * SCALE_QK);
            s[4] = (short)f2bf(f1.x * SCALE_QK); s[5] = (short)f2bf(f1.y * SCALE_QK);
            s[6] = (short)f2bf(f1.z * SCALE_QK); s[7] = (short)f2bf(f1.w * SCALE_QK);
        }
        qfrag[qt] = s;
    }
    __syncthreads();

    f32x4 sfr[12][3];
    const f32x4 zf = { 0.f, 0.f, 0.f, 0.f };
#pragma unroll
    for (int i = 0; i < 12; ++i) {
        int ky = 4 * w + i / 3;
        int fx = i % 3;
        short8 kf = *(const short8*)&Kp[(ky * 48 + fx * 16 + c) * 40 + 8 * g];
#pragma unroll
        for (int qt = 0; qt < 3; ++qt)
            sfr[i][qt] = __builtin_amdgcn_mfma_f32_16x16x32_bf16(kf, qfrag[qt], zf, 0, 0, 0);
    }

    float mw[3] = { -1e30f, -1e30f, -1e30f };
#pragma unroll
    for (int i = 0; i < 12; ++i) {
        int ky = 4 * w + i / 3, fx = i % 3;
        int yy = y + ky - 7;
        bool rowok = (yy >= 0) && (yy < 40);
        int xxb = fx * 16 + 4 * g;
#pragma unroll
        for (int qt = 0; qt < 3; ++qt) {
            int qx = qt * 16 + c;
#pragma unroll
            for (int r = 0; r < 4; ++r) {
                int xx = xxb + r;
                int dd = xx - qx;
                bool ok = rowok && (xx < 40) && (dd <= 7) && (dd >= -7);
                float v = ok ? sfr[i][qt][r] : -1e9f;
                sfr[i][qt][r] = v;
                mw[qt] = fmaxf(mw[qt], v);
            }
        }
    }
#pragma unroll
    for (int qt = 0; qt < 3; ++qt) {
        mw[qt] = fmaxf(mw[qt], __shfl_xor(mw[qt], 16, 64));
        mw[qt] = fmaxf(mw[qt], __shfl_xor(mw[qt], 32, 64));
    }
    if (lane < 16) {
#pragma unroll
        for (int qt = 0; qt < 3; ++qt) mred[w][qt][lane] = mw[qt];
    }
    __syncthreads();
    float M[3];
#pragma unroll
    for (int qt = 0; qt < 3; ++qt)
        M[qt] = fmaxf(fmaxf(mred[0][qt][c], mred[1][qt][c]),
                      fmaxf(mred[2][qt][c], mred[3][qt][c]));

    float lsum[3] = { 0.f, 0.f, 0.f };
    f32x4 acc_o[2][3] = {};
    int src_lo = 16 * ((2 * g) & 3) + c;
    int src_hi = 16 * ((2 * g + 1) & 3) + c;
    bool hisel = (g >= 2);
#pragma unroll
    for (int chk = 0; chk < 6; ++chk) {
        short8 pfrag[3];
#pragma unroll
        for (int qt = 0; qt < 3; ++qt) {
            float p00 = __expf(sfr[2 * chk][qt][0] - M[qt]);
            float p01 = __expf(sfr[2 * chk][qt][1] - M[qt]);
            float p02 = __expf(sfr[2 * chk][qt][2] - M[qt]);
            float p03 = __expf(sfr[2 * chk][qt][3] - M[qt]);
            float p10 = __expf(sfr[2 * chk + 1][qt][0] - M[qt]);
            float p11 = __expf(sfr[2 * chk + 1][qt][1] - M[qt]);
            float p12 = __expf(sfr[2 * chk + 1][qt][2] - M[qt]);
            float p13 = __expf(sfr[2 * chk + 1][qt][3] - M[qt]);
            lsum[qt] += ((p00 + p01) + (p02 + p03)) + ((p10 + p11) + (p12 + p13));
            unsigned w00 = pkbf(p00, p01), w01 = pkbf(p02, p03);
            unsigned w10 = pkbf(p10, p11), w11 = pkbf(p12, p13);
            unsigned a0 = __shfl(w00, src_lo, 64);
            unsigned a1 = __shfl(w10, src_lo, 64);
            unsigned b0 = __shfl(w01, src_lo, 64);
            unsigned b1 = __shfl(w11, src_lo, 64);
            unsigned c0 = __shfl(w00, src_hi, 64);
            unsigned c1 = __shfl(w10, src_hi, 64);
            unsigned d0 = __shfl(w01, src_hi, 64);
            unsigned d1 = __shfl(w11, src_hi, 64);
            union { short8 s8; unsigned u[4]; } P;
            P.u[0] = hisel ? a1 : a0;
            P.u[1] = hisel ? b1 : b0;
            P.u[2] = hisel ? c1 : c0;
            P.u[3] = hisel ? d1 : d0;
            pfrag[qt] = P.s8;
        }
        int jb = 32 * (6 * w + chk);
        short8 vf0 = *(const short8*)&Vt[c * 776 + jb + 8 * g];
        short8 vf1 = *(const short8*)&Vt[(16 + c) * 776 + jb + 8 * g];
#pragma unroll
        for (int qt = 0; qt < 3; ++qt) {
            acc_o[0][qt] = __builtin_amdgcn_mfma_f32_16x16x32_bf16(vf0, pfrag[qt], acc_o[0][qt], 0, 0, 0);
            acc_o[1][qt] = __builtin_amdgcn_mfma_f32_16x16x32_bf16(vf1, pfrag[qt], acc_o[1][qt], 0, 0, 0);
        }
    }

#pragma unroll
    for (int qt = 0; qt < 3; ++qt) {
        lsum[qt] += __shfl_xor(lsum[qt], 16, 64);
        lsum[qt] += __shfl_xor(lsum[qt], 32, 64);
    }
    if (lane < 16) {
#pragma unroll
        for (int qt = 0; qt < 3; ++qt) lred[w][qt][lane] = lsum[qt];
    }
    if (w > 0) {
#pragma unroll
        for (int dt = 0; dt < 2; ++dt)
#pragma unroll
            for (int qt = 0; qt < 3; ++qt)
                *(f32x4*)&Osh[w - 1][dt][qt][lane][0] = acc_o[dt][qt];
    }
    __syncthreads();
    if (w == 0) {
#pragma unroll
        for (int qt = 0; qt < 3; ++qt) {
            int qx = qt * 16 + c;
            if (qx >= 40) continue;
            float L = (lred[0][qt][c] + lred[1][qt][c]) + (lred[2][qt][c] + lred[3][qt][c]);
            float inv = 1.f / L;
#pragma unroll
            for (int dt = 0; dt < 2; ++dt) {
                f32x4 o1 = *(const f32x4*)&Osh[0][dt][qt][lane][0];
                f32x4 o2 = *(const f32x4*)&Osh[1][dt][qt][lane][0];
                f32x4 o3 = *(const f32x4*)&Osh[2][dt][qt][lane][0];
                float4 r;
                r.x = (acc_o[dt][qt][0] + o1[0] + o2[0] + o3[0]) * inv;
                r.y = (acc_o[dt][qt][1] + o1[1] + o2[1] + o3[1]) * inv;
                r.z = (acc_o[dt][qt][2] + o1[2] + o2[2] + o3[2]) * inv;
                r.w = (acc_o[dt][qt][3] + o1[3] + o2[3] + o3[3]) * inv;
                *(float4*)(O + (y * 40 + qx) * CDIM + h * HD + dt * 16 + 4 * g) = r;
            }
        }
    }
}

// build curr_Q (contiguous), global_K, global_V from qv (1600x512) and idkv (1600x264)
__global__ __launch_bounds__(256) void make_qkv_kernel(const float* __restrict__ qv,
                                                       const float* __restrict__ idkv,
                                                       float* __restrict__ Qc,
                                                       float* __restrict__ gK,
                                                       float* __restrict__ gV) {
    int idx = blockIdx.x * 256 + threadIdx.x;
    if (idx >= L_SEQ * CDIM) return;
    int l = idx >> 8, c = idx & 255;
    int h = c >> 5;
    float q = qv[l * 512 + c];
    Qc[idx] = q;
    gK[idx] = q * (1.f + tanhf(idkv[l * 264 + h]));
    gV[idx] = qv[l * 512 + 256 + c] + idkv[l * 264 + 8 + c];
}

// GroupNorm partials: grid (32 groups, 8 chunks); deterministic partial sums.
__global__ __launch_bounds__(256) void gn_partial(const float* __restrict__ X,
                                                  float* __restrict__ gstat) {
    __shared__ float sh4[4];
    int g = blockIdx.x, chunk = blockIdx.y;
    int base = g * 32;
    float s = 0.f, s2 = 0.f;
    for (int i = threadIdx.x; i < 200 * 32; i += 256) {
        int l = chunk * 200 + (i >> 5), c = i & 31;
        float v = X[l * DFF_ + base + c];
        s += v;
        s2 += v * v;
    }
    s = blockReduceSum(s, sh4);
    s2 = blockReduceSum(s2, sh4);
    if (threadIdx.x == 0) {
        gstat[g * 8 + chunk] = s;
        gstat[256 + g * 8 + chunk] = s2;
    }
}

// GroupNorm apply + exact GELU, float4-vectorized. 1600 blocks x 256 thr.
__global__ __launch_bounds__(256) void gn_apply(const float* __restrict__ X,
                                                const float* __restrict__ gstat,
                                                const float* __restrict__ g,
                                                const float* __restrict__ b,
                                                float* __restrict__ Y) {
    int idx = blockIdx.x * 256 + threadIdx.x;
    int e4 = idx * 4;
    int c = e4 & 1023;
    int grp = c >> 5;
    float s = 0.f, s2 = 0.f;
#pragma unroll
    for (int i = 0; i < 8; ++i) {
        s += gstat[grp * 8 + i];
        s2 += gstat[256 + grp * 8 + i];
    }
    const float invn = 1.0f / 51200.f;
    float mean = s * invn;
    float rs = rsqrtf(s2 * invn - mean * mean + 1e-5f);
    float4 v = *(const float4*)(X + e4);
    float4 gg = *(const float4*)(g + c);
    float4 bb = *(const float4*)(b + c);
    float4 r;
    float y0 = (v.x - mean) * rs * gg.x + bb.x;
    float y1 = (v.y - mean) * rs * gg.y + bb.y;
    float y2 = (v.z - mean) * rs * gg.z + bb.z;
    float y3 = (v.w - mean) * rs * gg.w + bb.w;
    r.x = 0.5f * y0 * (1.0f + erff(y0 * 0.70710678118654752f));
    r.y = 0.5f * y1 * (1.0f + erff(y1 * 0.70710678118654752f));
    r.z = 0.5f * y2 * (1.0f + erff(y2 * 0.70710678118654752f));
    r.w = 0.5f * y3 * (1.0f + erff(y3 * 0.70710678118654752f));
    *(float4*)(Y + e4) = r;
}

// transpose dw_k (1024,25) -> Kt (25,1024) for coalesced float4 weight loads
__global__ __launch_bounds__(256) void dwk_transpose(const float* __restrict__ Kw,
                                                     float* __restrict__ Kt) {
    int idx = blockIdx.x * 256 + threadIdx.x;
    if (idx >= 25 * DFF_) return;
    int k = idx >> 10, c = idx & 1023;
    Kt[idx] = Kw[c * 25 + k];
}

// depthwise 5x5 conv v2: one block = one spatial location (l), 256 threads =
// 256 float4 channel-groups. float4 X loads + float4 Kt loads, fully unrolled,
// 4 independent FMA chains. Interior/boundary branch is block-uniform.
__global__ __launch_bounds__(256) void dwconv_v2(const float* __restrict__ X,
                                                 const float* __restrict__ Kt,
                                                 float* __restrict__ Y) {
    int l = blockIdx.x;
    int c4 = threadIdx.x * 4;
    int y = l / GRID_W, x = l - y * GRID_W;
    float4 acc = make_float4(0.f, 0.f, 0.f, 0.f);
    if (y >= 2 && y < GRID_H - 2 && x >= 2 && x < GRID_W - 2) {
#pragma unroll
        for (int ky = 0; ky < 5; ++ky) {
#pragma unroll
            for (int kx = 0; kx < 5; ++kx) {
                float4 xv = *(const float4*)(X + ((y + ky - 2) * GRID_W + x + kx - 2) * DFF_ + c4);
                float4 wv = *(const float4*)(Kt + (ky * 5 + kx) * DFF_ + c4);
                acc.x += xv.x * wv.x; acc.y += xv.y * wv.y;
                acc.z += xv.z * wv.z; acc.w += xv.w * wv.w;
            }
        }
    } else {
#pragma unroll
        for (int ky = 0; ky < 5; ++ky) {
            int yy = y + ky - 2;
            if (yy < 0 || yy >= GRID_H) continue;
#pragma unroll
            for (int kx = 0; kx < 5; ++kx) {
                int xx = x + kx - 2;
                if (xx < 0 || xx >= GRID_W) continue;
                float4 xv = *(const float4*)(X + (yy * GRID_W + xx) * DFF_ + c4);
                float4 wv = *(const float4*)(Kt + (ky * 5 + kx) * DFF_ + c4);
                acc.x += xv.x * wv.x; acc.y += xv.y * wv.y;
                acc.z += xv.z * wv.z; acc.w += xv.w * wv.w;
            }
        }
    }
    *(float4*)(Y + l * DFF_ + c4) = acc;
}

extern "C" void kernel_launch(void* const* d_in, const int* in_sizes, int n_in,
                              void* d_out, int out_size, void* d_ws, size_t ws_size,
                              hipStream_t stream) {
    (void)in_sizes; (void)n_in; (void)out_size; (void)ws_size;
    const float* tgt = (const float*)d_in[0];
    const float* curr_id_emb = (const float*)d_in[1];
    const float* self_pos = (const float*)d_in[2];
    const float* ln1_g = (const float*)d_in[3];
    const float* ln1_b = (const float*)d_in[4];
    const float* sa_wq = (const float*)d_in[5];
    const float* sa_bq = (const float*)d_in[6];
    const float* sa_wk = (const float*)d_in[7];
    const float* sa_bk = (const float*)d_in[8];
    const float* sa_wv = (const float*)d_in[9];
    const float* sa_bv = (const float*)d_in[10];
    const float* sa_wo = (const float*)d_in[11];
    const float* sa_bo = (const float*)d_in[12];
    const float* ln2_g = (const float*)d_in[13];
    const float* ln2_b = (const float*)d_in[14];
    const float* w_qv = (const float*)d_in[15];
    const float* b_qv = (const float*)d_in[16];
    const float* w_id = (const float*)d_in[17];
    const float* b_id = (const float*)d_in[18];
    const float* lt_wo = (const float*)d_in[19];
    const float* lt_bo = (const float*)d_in[20];
    const float* st_wo = (const float*)d_in[21];
    const float* st_bo = (const float*)d_in[22];
    const float* ln3_g = (const float*)d_in[23];
    const float* ln3_b = (const float*)d_in[24];
    const float* w1 = (const float*)d_in[25];
    const float* b1 = (const float*)d_in[26];
    const float* gn_g = (const float*)d_in[27];
    const float* gn_b = (const float*)d_in[28];
    const float* dw_k = (const float*)d_in[29];
    const float* w2 = (const float*)d_in[30];
    const float* b2 = (const float*)d_in[31];
    float* out = (float*)d_out;

    float* ws = (float*)d_ws;
    const int LC = L_SEQ * CDIM;           // 409600
    float* bufA = ws;                      // _t
    float* bufB = bufA + LC;               // qk_in / tgt1+tgt2
    float* bufC = bufB + LC;               // q_ / curr_Q
    float* bufD = bufC + LC;               // k_ / global_K
    float* bufE = bufD + LC;               // v_ / global_V
    float* bufF = bufE + LC;               // attn outs
    float* bufG = bufF + LC;               // tgt1 / tgt_b
    float* bufH = bufG + LC;               // qv (1600x512); later: gstat
    float* bufI = bufH + L_SEQ * 512;      // idkv (1600x264)
    float* bufX = bufI + L_SEQ * 264;      // w1 out (1600x1024)
    float* bufY = bufX + L_SEQ * DFF_;     // gn+gelu out
    float* bufZ = bufY + L_SEQ * DFF_;     // conv out
    float* bufW = bufZ + L_SEQ * DFF_;     // transposed dw_k (25x1024)

    dim3 blk(256);
    dim3 g256(4, 25), g264(5, 25), g512(8, 25), g1024(16, 25);
    dim3 mhaGrid(L_SEQ / QBLK, NH);

    // 0. transpose depthwise weights (independent; issue first)
    dwk_transpose<<<100, blk, 0, stream>>>(dw_k, bufW);
    // 1. LN1: bufA = ln(tgt), bufB = bufA + self_pos
    ln_kernel<<<L_SEQ, blk, 0, stream>>>(tgt, ln1_g, ln1_b, self_pos, bufA, bufB);
    // 2-4. q,k,v projections
    gemm_mfma<<<g256, blk, 0, stream>>>(bufB, sa_wq, sa_bq, nullptr, bufC, L_SEQ, CDIM, CDIM);
    gemm_mfma<<<g256, blk, 0, stream>>>(bufB, sa_wk, sa_bk, nullptr, bufD, L_SEQ, CDIM, CDIM);
    gemm_mfma<<<g256, blk, 0, stream>>>(bufA, sa_wv, sa_bv, nullptr, bufE, L_SEQ, CDIM, CDIM);
    // 5. self attention
    mha_mfma<<<mhaGrid, blk, 0, stream>>>(bufC, bufD, bufE, bufF);
    // 6. out proj + residual -> tgt1 (bufG)
    gemm_mfma<<<g256, blk, 0, stream>>>(bufF, sa_wo, sa_bo, tgt, bufG, L_SEQ, CDIM, CDIM);
    // 7. LN2 -> bufA
    ln_kernel<<<L_SEQ, blk, 0, stream>>>(bufG, ln2_g, ln2_b, nullptr, bufA, nullptr);
    // 8. qv = bufA @ w_qv^T -> bufH (1600x512)
    gemm_mfma<<<g512, blk, 0, stream>>>(bufA, w_qv, b_qv, nullptr, bufH, L_SEQ, 512, CDIM);
    // 9. idkv = curr_id_emb @ w_id^T -> bufI (1600x264)
    gemm_mfma<<<g264, blk, 0, stream>>>(curr_id_emb, w_id, b_id, nullptr, bufI, L_SEQ, 264, CDIM);
    // 10. curr_Q (bufC), global_K (bufD), global_V (bufE)
    make_qkv_kernel<<<L_SEQ, blk, 0, stream>>>(bufH, bufI, bufC, bufD, bufE);
    // 11. long-term attention
    mha_mfma<<<mhaGrid, blk, 0, stream>>>(bufC, bufD, bufE, bufF);
    // 12. lt out proj + residual(tgt1) -> bufB
    gemm_mfma<<<g256, blk, 0, stream>>>(bufF, lt_wo, lt_bo, bufG, bufB, L_SEQ, CDIM, CDIM);
    // 13. local attention (MFMA) -> bufF
    local_mfma<<<dim3(GRID_H, NH), blk, 0, stream>>>(bufC, bufD, bufE, bufF);
    // 14. st out proj + residual(bufB) -> tgt_b (bufG)
    gemm_mfma<<<g256, blk, 0, stream>>>(bufF, st_wo, st_bo, bufB, bufG, L_SEQ, CDIM, CDIM);
    // 15. LN3 -> bufA
    ln_kernel<<<L_SEQ, blk, 0, stream>>>(bufG, ln3_g, ln3_b, nullptr, bufA, nullptr);
    // 16. x = bufA @ w1^T -> bufX (1600x1024)
    gemm_mfma<<<g1024, blk, 0, stream>>>(bufA, w1, b1, nullptr, bufX, L_SEQ, DFF_, CDIM);
    // 17. GroupNorm + GELU -> bufY  (bufH is dead; reuse as gstat)
    gn_partial<<<dim3(32, 8), blk, 0, stream>>>(bufX, bufH);
    gn_apply<<<L_SEQ, blk, 0, stream>>>(bufX, bufH, gn_g, gn_b, bufY);
    // 18. depthwise conv v2 -> bufZ
    dwconv_v2<<<L_SEQ, blk, 0, stream>>>(bufY, bufW, bufZ);
    // 19. final proj + residual(tgt_b) -> out
    gemm_mfma<<<g256, blk, 0, stream>>>(bufZ, w2, b2, bufG, out, L_SEQ, CDIM, DFF_);
}

// Round 9
// 348.516 us; speedup vs baseline: 5.4622x; 1.1005x over previous
//
#include <hip/hip_runtime.h>
#include <math.h>

#define L_SEQ 1600
#define CDIM 256
#define NH 8
#define HD 32
#define GRID_H 40
#define GRID_W 40
#define DFF_ 1024
#define SCALE_QK 0.17677669529663687f

typedef __attribute__((ext_vector_type(8))) short short8;
typedef __attribute__((ext_vector_type(4))) float f32x4;

__device__ __forceinline__ float waveReduceSum(float v) {
#pragma unroll
    for (int off = 32; off > 0; off >>= 1) v += __shfl_down(v, off, 64);
    return v;
}
__device__ __forceinline__ float blockReduceSum(float v, float* sh4) {
    v = waveReduceSum(v);
    int lane = threadIdx.x & 63, wid = threadIdx.x >> 6;
    __syncthreads();
    if (lane == 0) sh4[wid] = v;
    __syncthreads();
    return sh4[0] + sh4[1] + sh4[2] + sh4[3];
}

__device__ __forceinline__ unsigned short f2bf(float x) {
    union { float f; unsigned u; } v; v.f = x;
    unsigned r = (v.u + 0x7FFFu + ((v.u >> 16) & 1u)) >> 16;
    return (unsigned short)r;
}
__device__ __forceinline__ unsigned pkbf(float lo, float hi) {
    return (unsigned)f2bf(lo) | ((unsigned)f2bf(hi) << 16);
}

// LayerNorm over C=256; one block per row. out2 = out + addin (optional)
__global__ __launch_bounds__(256) void ln_kernel(const float* __restrict__ x,
                                                 const float* __restrict__ g,
                                                 const float* __restrict__ b,
                                                 const float* __restrict__ addin,
                                                 float* __restrict__ out,
                                                 float* __restrict__ out2) {
    __shared__ float sh4[4];
    int row = blockIdx.x;
    int c = threadIdx.x;
    float v = x[row * CDIM + c];
    float mean = blockReduceSum(v, sh4) * (1.0f / CDIM);
    float d = v - mean;
    float var = blockReduceSum(d * d, sh4) * (1.0f / CDIM);
    float y = d * rsqrtf(var + 1e-5f) * g[c] + b[c];
    out[row * CDIM + c] = y;
    if (out2) out2[row * CDIM + c] = y + addin[row * CDIM + c];
}

// ---------------------------------------------------------------------------
// bf16 MFMA GEMM, batched up to 3 jobs via blockIdx.z (same verified body).
// ---------------------------------------------------------------------------
struct GJob {
    const float* A; const float* W; const float* bias; const float* res;
    float* C; int N; int K;
};

__global__ __launch_bounds__(256) void gemm_mfma(GJob j0, GJob j1, GJob j2) {
    GJob j = j0;
    if (blockIdx.z == 1) j = j1;
    else if (blockIdx.z == 2) j = j2;
    const float* __restrict__ A = j.A;
    const float* __restrict__ W = j.W;
    const float* bias = j.bias;
    const float* res = j.res;
    float* __restrict__ C = j.C;
    int N = j.N, K = j.K;

    __shared__ unsigned short Al[2][4][64][8];
    __shared__ unsigned short Bl[2][4][64][8];
    int tid = threadIdx.x;
    int bm = blockIdx.y * 64, bn = blockIdx.x * 64;
    if (bn >= N) return;
    int lane = tid & 63, wave = tid >> 6;
    int wr = wave >> 1, wc = wave & 1;

    int srow = tid >> 3;
    int q = tid & 7;
    int e0 = (q & 1) * 4;

    f32x4 acc[2][2] = {};
    int nsteps = K >> 5;

    float4 ra[2], rb[2];
    {
#pragma unroll
        for (int r = 0; r < 2; ++r) {
            int row = srow + 32 * r;
            ra[r] = *(const float4*)(A + (bm + row) * K + 4 * q);
            int n = bn + row;
            rb[r] = (n < N) ? *(const float4*)(W + n * K + 4 * q)
                            : make_float4(0.f, 0.f, 0.f, 0.f);
        }
#pragma unroll
        for (int r = 0; r < 2; ++r) {
            int row = srow + 32 * r;
            int frag = (row >> 4), l = (row & 15) + 16 * (q >> 1);
            *(uint2*)&Al[0][frag][l][e0] = make_uint2(pkbf(ra[r].x, ra[r].y), pkbf(ra[r].z, ra[r].w));
            *(uint2*)&Bl[0][frag][l][e0] = make_uint2(pkbf(rb[r].x, rb[r].y), pkbf(rb[r].z, rb[r].w));
        }
    }
    __syncthreads();

    for (int s = 0; s < nsteps; ++s) {
        bool more = (s + 1) < nsteps;
        if (more) {
            int k0 = (s + 1) << 5;
#pragma unroll
            for (int r = 0; r < 2; ++r) {
                int row = srow + 32 * r;
                ra[r] = *(const float4*)(A + (bm + row) * K + k0 + 4 * q);
                int n = bn + row;
                rb[r] = (n < N) ? *(const float4*)(W + n * K + k0 + 4 * q)
                                : make_float4(0.f, 0.f, 0.f, 0.f);
            }
        }
        {
            int buf = s & 1;
            short8 af[2], bfr[2];
#pragma unroll
            for (int i = 0; i < 2; ++i) {
                af[i] = *(const short8*)&Al[buf][2 * wr + i][lane][0];
                bfr[i] = *(const short8*)&Bl[buf][2 * wc + i][lane][0];
            }
#pragma unroll
            for (int i = 0; i < 2; ++i)
#pragma unroll
                for (int jj = 0; jj < 2; ++jj)
                    acc[i][jj] = __builtin_amdgcn_mfma_f32_16x16x32_bf16(af[i], bfr[jj], acc[i][jj], 0, 0, 0);
        }
        if (more) {
            int buf = (s + 1) & 1;
#pragma unroll
            for (int r = 0; r < 2; ++r) {
                int row = srow + 32 * r;
                int frag = (row >> 4), l = (row & 15) + 16 * (q >> 1);
                *(uint2*)&Al[buf][frag][l][e0] = make_uint2(pkbf(ra[r].x, ra[r].y), pkbf(ra[r].z, ra[r].w));
                *(uint2*)&Bl[buf][frag][l][e0] = make_uint2(pkbf(rb[r].x, rb[r].y), pkbf(rb[r].z, rb[r].w));
            }
        }
        __syncthreads();
    }

#pragma unroll
    for (int jj = 0; jj < 2; ++jj) {
        int col = bn + wc * 32 + jj * 16 + (lane & 15);
        if (col >= N) continue;
        float bv = bias ? bias[col] : 0.f;
#pragma unroll
        for (int i = 0; i < 2; ++i) {
            int rbase = bm + wr * 32 + i * 16 + ((lane >> 4) << 2);
#pragma unroll
            for (int r = 0; r < 4; ++r) {
                int row = rbase + r;
                float v = acc[i][jj][r] + bv;
                if (res) v += res[row * N + col];
                C[row * N + col] = v;
            }
        }
    }
}

// ---------------------------------------------------------------------------
// MFMA flash attention (verified; + ldo output stride param)
// ---------------------------------------------------------------------------
#define QBLK 32
#define KTJ 128
__global__ __launch_bounds__(256) void mha_mfma(const float* __restrict__ Q,
                                                const float* __restrict__ K,
                                                const float* __restrict__ V,
                                                float* __restrict__ O, int ldo) {
    __shared__ unsigned short Kl[8][64][8];
    __shared__ unsigned short Vl[4][2][64][12];
    __shared__ float mred[4][2][16];
    __shared__ float lred[4][2][16];
    __shared__ float Osh[3][2][2][64][4];
    int h = blockIdx.y;
    int qbase = blockIdx.x * QBLK;
    int tid = threadIdx.x;
    int w = tid >> 6, lane = tid & 63;
    int g = lane >> 4, c = lane & 15;

    short8 qfrag[2];
#pragma unroll
    for (int qt = 0; qt < 2; ++qt) {
        const float* qp = Q + (qbase + qt * 16 + c) * CDIM + h * HD + g * 8;
        float4 f0 = *(const float4*)qp;
        float4 f1 = *(const float4*)(qp + 4);
        short8 s;
        s[0] = (short)f2bf(f0.x * SCALE_QK); s[1] = (short)f2bf(f0.y * SCALE_QK);
        s[2] = (short)f2bf(f0.z * SCALE_QK); s[3] = (short)f2bf(f0.w * SCALE_QK);
        s[4] = (short)f2bf(f1.x * SCALE_QK); s[5] = (short)f2bf(f1.y * SCALE_QK);
        s[6] = (short)f2bf(f1.z * SCALE_QK); s[7] = (short)f2bf(f1.w * SCALE_QK);
        qfrag[qt] = s;
    }

    float m[2] = { -INFINITY, -INFINITY };
    float l[2] = { 0.f, 0.f };
    f32x4 acc_o[2][2] = {};

    int jrow = tid >> 1;
    int dhalf = (tid & 1) * 16;
    int vjq = tid >> 3;
    int vdq = tid & 7;
    int vjr = 4 * vjq;
    int vd0 = 4 * vdq;
    int vjc = vjr >> 5, vdt = vd0 >> 4, vjg = (vjr & 31) >> 3, ve0 = vjr & 7;

    int src_lo = 16 * ((2 * g) & 3) + c;
    int src_hi = 16 * ((2 * g + 1) & 3) + c;
    bool hisel = (g >= 2);

    for (int t = 0; t < L_SEQ; t += KTJ) {
        {
            int jj = t + jrow;
            float4 f0, f1, f2, f3;
            if (jj < L_SEQ) {
                const float4* kp = (const float4*)(K + jj * CDIM + h * HD + dhalf);
                f0 = kp[0]; f1 = kp[1]; f2 = kp[2]; f3 = kp[3];
            } else {
                f0 = f1 = f2 = f3 = make_float4(0.f, 0.f, 0.f, 0.f);
            }
            int jt = jrow >> 4;
            int laneA = (jrow & 15) + dhalf * 2;
            short8 s0, s1;
            s0[0]=f2bf(f0.x); s0[1]=f2bf(f0.y); s0[2]=f2bf(f0.z); s0[3]=f2bf(f0.w);
            s0[4]=f2bf(f1.x); s0[5]=f2bf(f1.y); s0[6]=f2bf(f1.z); s0[7]=f2bf(f1.w);
            s1[0]=f2bf(f2.x); s1[1]=f2bf(f2.y); s1[2]=f2bf(f2.z); s1[3]=f2bf(f2.w);
            s1[4]=f2bf(f3.x); s1[5]=f2bf(f3.y); s1[6]=f2bf(f3.z); s1[7]=f2bf(f3.w);
            *(short8*)&Kl[jt][laneA][0] = s0;
            *(short8*)&Kl[jt][laneA + 16][0] = s1;
        }
        {
            float4 r0, r1, r2, r3;
            int j0 = t + vjr;
            const float* vb = V + h * HD + vd0;
            r0 = (j0 + 0 < L_SEQ) ? *(const float4*)(vb + (j0 + 0) * CDIM) : make_float4(0,0,0,0);
            r1 = (j0 + 1 < L_SEQ) ? *(const float4*)(vb + (j0 + 1) * CDIM) : make_float4(0,0,0,0);
            r2 = (j0 + 2 < L_SEQ) ? *(const float4*)(vb + (j0 + 2) * CDIM) : make_float4(0,0,0,0);
            r3 = (j0 + 3 < L_SEQ) ? *(const float4*)(vb + (j0 + 3) * CDIM) : make_float4(0,0,0,0);
            float col[4][4] = {
                { r0.x, r1.x, r2.x, r3.x },
                { r0.y, r1.y, r2.y, r3.y },
                { r0.z, r1.z, r2.z, r3.z },
                { r0.w, r1.w, r2.w, r3.w } };
#pragma unroll
            for (int dd = 0; dd < 4; ++dd) {
                int laneV = ((vd0 + dd) & 15) + 16 * vjg;
                uint2 pk;
                pk.x = pkbf(col[dd][0], col[dd][1]);
                pk.y = pkbf(col[dd][2], col[dd][3]);
                *(uint2*)&Vl[vjc][vdt][laneV][ve0] = pk;
            }
        }
        __syncthreads();

        bool alive = (t + 32 * w) < L_SEQ;
        if (alive) {
            short8 kf0 = *(const short8*)&Kl[2 * w][lane][0];
            short8 kf1 = *(const short8*)&Kl[2 * w + 1][lane][0];
            f32x4 zero = { 0.f, 0.f, 0.f, 0.f };
            f32x4 s[2][2];
            s[0][0] = __builtin_amdgcn_mfma_f32_16x16x32_bf16(kf0, qfrag[0], zero, 0, 0, 0);
            s[0][1] = __builtin_amdgcn_mfma_f32_16x16x32_bf16(kf0, qfrag[1], zero, 0, 0, 0);
            s[1][0] = __builtin_amdgcn_mfma_f32_16x16x32_bf16(kf1, qfrag[0], zero, 0, 0, 0);
            s[1][1] = __builtin_amdgcn_mfma_f32_16x16x32_bf16(kf1, qfrag[1], zero, 0, 0, 0);

            short8 pfrag[2];
#pragma unroll
            for (int qt = 0; qt < 2; ++qt) {
                float mx = s[0][qt][0];
                mx = fmaxf(mx, s[0][qt][1]); mx = fmaxf(mx, s[0][qt][2]); mx = fmaxf(mx, s[0][qt][3]);
                mx = fmaxf(mx, s[1][qt][0]); mx = fmaxf(mx, s[1][qt][1]);
                mx = fmaxf(mx, s[1][qt][2]); mx = fmaxf(mx, s[1][qt][3]);
                mx = fmaxf(mx, __shfl_xor(mx, 16, 64));
                mx = fmaxf(mx, __shfl_xor(mx, 32, 64));
                float nm = fmaxf(m[qt], mx);
                float alpha = __expf(m[qt] - nm);
                m[qt] = nm;
                float p00 = __expf(s[0][qt][0] - nm), p01 = __expf(s[0][qt][1] - nm);
                float p02 = __expf(s[0][qt][2] - nm), p03 = __expf(s[0][qt][3] - nm);
                float p10 = __expf(s[1][qt][0] - nm), p11 = __expf(s[1][qt][1] - nm);
                float p12 = __expf(s[1][qt][2] - nm), p13 = __expf(s[1][qt][3] - nm);
                float ts = ((p00 + p01) + (p02 + p03)) + ((p10 + p11) + (p12 + p13));
                ts += __shfl_xor(ts, 16, 64);
                ts += __shfl_xor(ts, 32, 64);
                l[qt] = l[qt] * alpha + ts;
#pragma unroll
                for (int dt = 0; dt < 2; ++dt) {
                    acc_o[dt][qt][0] *= alpha; acc_o[dt][qt][1] *= alpha;
                    acc_o[dt][qt][2] *= alpha; acc_o[dt][qt][3] *= alpha;
                }
                unsigned w00 = pkbf(p00, p01), w01 = pkbf(p02, p03);
                unsigned w10 = pkbf(p10, p11), w11 = pkbf(p12, p13);
                unsigned a0 = __shfl(w00, src_lo, 64);
                unsigned a1 = __shfl(w10, src_lo, 64);
                unsigned b0 = __shfl(w01, src_lo, 64);
                unsigned b1 = __shfl(w11, src_lo, 64);
                unsigned c0 = __shfl(w00, src_hi, 64);
                unsigned c1 = __shfl(w10, src_hi, 64);
                unsigned d0 = __shfl(w01, src_hi, 64);
                unsigned d1 = __shfl(w11, src_hi, 64);
                union { short8 s8; unsigned u[4]; } P;
                P.u[0] = hisel ? a1 : a0;
                P.u[1] = hisel ? b1 : b0;
                P.u[2] = hisel ? c1 : c0;
                P.u[3] = hisel ? d1 : d0;
                pfrag[qt] = P.s8;
            }

            union { short8 s8; uint2 v[2]; } vf0u, vf1u;
            vf0u.v[0] = *(const uint2*)&Vl[w][0][lane][0];
            vf0u.v[1] = *(const uint2*)&Vl[w][0][lane][4];
            vf1u.v[0] = *(const uint2*)&Vl[w][1][lane][0];
            vf1u.v[1] = *(const uint2*)&Vl[w][1][lane][4];
            acc_o[0][0] = __builtin_amdgcn_mfma_f32_16x16x32_bf16(vf0u.s8, pfrag[0], acc_o[0][0], 0, 0, 0);
            acc_o[0][1] = __builtin_amdgcn_mfma_f32_16x16x32_bf16(vf0u.s8, pfrag[1], acc_o[0][1], 0, 0, 0);
            acc_o[1][0] = __builtin_amdgcn_mfma_f32_16x16x32_bf16(vf1u.s8, pfrag[0], acc_o[1][0], 0, 0, 0);
            acc_o[1][1] = __builtin_amdgcn_mfma_f32_16x16x32_bf16(vf1u.s8, pfrag[1], acc_o[1][1], 0, 0, 0);
        }
        __syncthreads();
    }

    if (g == 0) {
#pragma unroll
        for (int qt = 0; qt < 2; ++qt) { mred[w][qt][c] = m[qt]; lred[w][qt][c] = l[qt]; }
    }
    if (w > 0) {
#pragma unroll
        for (int dt = 0; dt < 2; ++dt)
#pragma unroll
            for (int qt = 0; qt < 2; ++qt)
                *(f32x4*)&Osh[w - 1][dt][qt][lane][0] = acc_o[dt][qt];
    }
    __syncthreads();
    if (w == 0) {
#pragma unroll
        for (int qt = 0; qt < 2; ++qt) {
            float m0_ = mred[0][qt][c], m1_ = mred[1][qt][c];
            float m2_ = mred[2][qt][c], m3_ = mred[3][qt][c];
            float M = fmaxf(fmaxf(m0_, m1_), fmaxf(m2_, m3_));
            float a0 = __expf(m0_ - M), a1 = __expf(m1_ - M);
            float a2 = __expf(m2_ - M), a3 = __expf(m3_ - M);
            float L = a0 * lred[0][qt][c] + a1 * lred[1][qt][c]
                    + a2 * lred[2][qt][c] + a3 * lred[3][qt][c];
            float inv = 1.f / L;
#pragma unroll
            for (int dt = 0; dt < 2; ++dt) {
                f32x4 o1 = *(const f32x4*)&Osh[0][dt][qt][lane][0];
                f32x4 o2 = *(const f32x4*)&Osh[1][dt][qt][lane][0];
                f32x4 o3 = *(const f32x4*)&Osh[2][dt][qt][lane][0];
                float4 r;
                r.x = (acc_o[dt][qt][0] * a0 + o1[0] * a1 + o2[0] * a2 + o3[0] * a3) * inv;
                r.y = (acc_o[dt][qt][1] * a0 + o1[1] * a1 + o2[1] * a2 + o3[1] * a3) * inv;
                r.z = (acc_o[dt][qt][2] * a0 + o1[2] * a1 + o2[2] * a2 + o3[2] * a3) * inv;
                r.w = (acc_o[dt][qt][3] * a0 + o1[3] * a1 + o2[3] * a2 + o3[3] * a3) * inv;
                *(float4*)(O + (qbase + qt * 16 + c) * ldo + h * HD + dt * 16 + 4 * g) = r;
            }
        }
    }
}

// ---------------------------------------------------------------------------
// MFMA local windowed attention (verified; + ldo output stride param)
// ---------------------------------------------------------------------------
__global__ __launch_bounds__(256, 1) void local_mfma(const float* __restrict__ Q,
                                                     const float* __restrict__ K,
                                                     const float* __restrict__ V,
                                                     float* __restrict__ O, int ldo) {
    __shared__ unsigned short Kp[768 * 40];
    __shared__ unsigned short Vt[32 * 776];
    __shared__ float mred[4][3][16];
    __shared__ float lred[4][3][16];
    __shared__ float Osh[3][2][3][64][4];
    int y = blockIdx.x, h = blockIdx.y;
    int tid = threadIdx.x;
    int w = tid >> 6, lane = tid & 63;
    int g = lane >> 4, c = lane & 15;

#pragma unroll 4
    for (int rep = 0; rep < 24; ++rep) {
        int idx = rep * 256 + tid;
        int key = idx >> 3, dq = idx & 7;
        int ky = key / 48;
        int xx = key - 48 * ky;
        int yy = y + ky - 7;
        bool ok = (xx < 40) && (yy >= 0) && (yy < 40);
        float4 fk = make_float4(0.f, 0.f, 0.f, 0.f);
        float4 fv = make_float4(0.f, 0.f, 0.f, 0.f);
        if (ok) {
            int pos = (yy * 40 + xx) * CDIM + h * HD + 4 * dq;
            fk = *(const float4*)(K + pos);
            fv = *(const float4*)(V + pos);
        }
        *(uint2*)&Kp[key * 40 + 4 * dq] = make_uint2(pkbf(fk.x, fk.y), pkbf(fk.z, fk.w));
        int vb = (4 * dq) * 776 + key;
        Vt[vb] = f2bf(fv.x);
        Vt[vb + 776] = f2bf(fv.y);
        Vt[vb + 1552] = f2bf(fv.z);
        Vt[vb + 2328] = f2bf(fv.w);
    }

    short8 qfrag[3];
#pragma unroll
    for (int qt = 0; qt < 3; ++qt) {
        short8 s = { 0, 0, 0, 0, 0, 0, 0, 0 };
        int qx = qt * 16 + c;
        if (qx < 40) {
            const float* qp = Q + (y * 40 + qx) * CDIM + h * HD + g * 8;
            float4 f0 = *(const float4*)qp;
            float4 f1 = *(const float4*)(qp + 4);
            s[0] = (short)f2bf(f0.x * SCALE_QK); s[1] = (short)f2bf(f0.y * SCALE_QK);
            s[2] = (short)f2bf(f0.z * SCALE_QK); s[3] = (short)f2bf(f0.w * SCALE_QK);
            s[4] = (short)f2bf(f1.x * SCALE_QK); s[5] = (short)f2bf(f1.y * SCALE_QK);
            s[6] = (short)f2bf(f1.z * SCALE_QK); s[7] = (short)f2bf(f1.w * SCALE_QK);
        }
        qfrag[qt] = s;
    }
    __syncthreads();

    f32x4 sfr[12][3];
    const f32x4 zf = { 0.f, 0.f, 0.f, 0.f };
#pragma unroll
    for (int i = 0; i < 12; ++i) {
        int ky = 4 * w + i / 3;
        int fx = i % 3;
        short8 kf = *(const short8*)&Kp[(ky * 48 + fx * 16 + c) * 40 + 8 * g];
#pragma unroll
        for (int qt = 0; qt < 3; ++qt)
            sfr[i][qt] = __builtin_amdgcn_mfma_f32_16x16x32_bf16(kf, qfrag[qt], zf, 0, 0, 0);
    }

    float mw[3] = { -1e30f, -1e30f, -1e30f };
#pragma unroll
    for (int i = 0; i < 12; ++i) {
        int ky = 4 * w + i / 3, fx = i % 3;
        int yy = y + ky - 7;
        bool rowok = (yy >= 0) && (yy < 40);
        int xxb = fx * 16 + 4 * g;
#pragma unroll
        for (int qt = 0; qt < 3; ++qt) {
            int qx = qt * 16 + c;
#pragma unroll
            for (int r = 0; r < 4; ++r) {
                int xx = xxb + r;
                int dd = xx - qx;
                bool ok = rowok && (xx < 40) && (dd <= 7) && (dd >= -7);
                float v = ok ? sfr[i][qt][r] : -1e9f;
                sfr[i][qt][r] = v;
                mw[qt] = fmaxf(mw[qt], v);
            }
        }
    }
#pragma unroll
    for (int qt = 0; qt < 3; ++qt) {
        mw[qt] = fmaxf(mw[qt], __shfl_xor(mw[qt], 16, 64));
        mw[qt] = fmaxf(mw[qt], __shfl_xor(mw[qt], 32, 64));
    }
    if (lane < 16) {
#pragma unroll
        for (int qt = 0; qt < 3; ++qt) mred[w][qt][lane] = mw[qt];
    }
    __syncthreads();
    float M[3];
#pragma unroll
    for (int qt = 0; qt < 3; ++qt)
        M[qt] = fmaxf(fmaxf(mred[0][qt][c], mred[1][qt][c]),
                      fmaxf(mred[2][qt][c], mred[3][qt][c]));

    float lsum[3] = { 0.f, 0.f, 0.f };
    f32x4 acc_o[2][3] = {};
    int src_lo = 16 * ((2 * g) & 3) + c;
    int src_hi = 16 * ((2 * g + 1) & 3) + c;
    bool hisel = (g >= 2);
#pragma unroll
    for (int chk = 0; chk < 6; ++chk) {
        short8 pfrag[3];
#pragma unroll
        for (int qt = 0; qt < 3; ++qt) {
            float p00 = __expf(sfr[2 * chk][qt][0] - M[qt]);
            float p01 = __expf(sfr[2 * chk][qt][1] - M[qt]);
            float p02 = __expf(sfr[2 * chk][qt][2] - M[qt]);
            float p03 = __expf(sfr[2 * chk][qt][3] - M[qt]);
            float p10 = __expf(sfr[2 * chk + 1][qt][0] - M[qt]);
            float p11 = __expf(sfr[2 * chk + 1][qt][1] - M[qt]);
            float p12 = __expf(sfr[2 * chk + 1][qt][2] - M[qt]);
            float p13 = __expf(sfr[2 * chk + 1][qt][3] - M[qt]);
            lsum[qt] += ((p00 + p01) + (p02 + p03)) + ((p10 + p11) + (p12 + p13));
            unsigned w00 = pkbf(p00, p01), w01 = pkbf(p02, p03);
            unsigned w10 = pkbf(p10, p11), w11 = pkbf(p12, p13);
            unsigned a0 = __shfl(w00, src_lo, 64);
            unsigned a1 = __shfl(w10, src_lo, 64);
            unsigned b0 = __shfl(w01, src_lo, 64);
            unsigned b1 = __shfl(w11, src_lo, 64);
            unsigned c0 = __shfl(w00, src_hi, 64);
            unsigned c1 = __shfl(w10, src_hi, 64);
            unsigned d0 = __shfl(w01, src_hi, 64);
            unsigned d1 = __shfl(w11, src_hi, 64);
            union { short8 s8; unsigned u[4]; } P;
            P.u[0] = hisel ? a1 : a0;
            P.u[1] = hisel ? b1 : b0;
            P.u[2] = hisel ? c1 : c0;
            P.u[3] = hisel ? d1 : d0;
            pfrag[qt] = P.s8;
        }
        int jb = 32 * (6 * w + chk);
        short8 vf0 = *(const short8*)&Vt[c * 776 + jb + 8 * g];
        short8 vf1 = *(const short8*)&Vt[(16 + c) * 776 + jb + 8 * g];
#pragma unroll
        for (int qt = 0; qt < 3; ++qt) {
            acc_o[0][qt] = __builtin_amdgcn_mfma_f32_16x16x32_bf16(vf0, pfrag[qt], acc_o[0][qt], 0, 0, 0);
            acc_o[1][qt] = __builtin_amdgcn_mfma_f32_16x16x32_bf16(vf1, pfrag[qt], acc_o[1][qt], 0, 0, 0);
        }
    }

#pragma unroll
    for (int qt = 0; qt < 3; ++qt) {
        lsum[qt] += __shfl_xor(lsum[qt], 16, 64);
        lsum[qt] += __shfl_xor(lsum[qt], 32, 64);
    }
    if (lane < 16) {
#pragma unroll
        for (int qt = 0; qt < 3; ++qt) lred[w][qt][lane] = lsum[qt];
    }
    if (w > 0) {
#pragma unroll
        for (int dt = 0; dt < 2; ++dt)
#pragma unroll
            for (int qt = 0; qt < 3; ++qt)
                *(f32x4*)&Osh[w - 1][dt][qt][lane][0] = acc_o[dt][qt];
    }
    __syncthreads();
    if (w == 0) {
#pragma unroll
        for (int qt = 0; qt < 3; ++qt) {
            int qx = qt * 16 + c;
            if (qx >= 40) continue;
            float L = (lred[0][qt][c] + lred[1][qt][c]) + (lred[2][qt][c] + lred[3][qt][c]);
            float inv = 1.f / L;
#pragma unroll
            for (int dt = 0; dt < 2; ++dt) {
                f32x4 o1 = *(const f32x4*)&Osh[0][dt][qt][lane][0];
                f32x4 o2 = *(const f32x4*)&Osh[1][dt][qt][lane][0];
                f32x4 o3 = *(const f32x4*)&Osh[2][dt][qt][lane][0];
                float4 r;
                r.x = (acc_o[dt][qt][0] + o1[0] + o2[0] + o3[0]) * inv;
                r.y = (acc_o[dt][qt][1] + o1[1] + o2[1] + o3[1]) * inv;
                r.z = (acc_o[dt][qt][2] + o1[2] + o2[2] + o3[2]) * inv;
                r.w = (acc_o[dt][qt][3] + o1[3] + o2[3] + o3[3]) * inv;
                *(float4*)(O + (y * 40 + qx) * ldo + h * HD + dt * 16 + 4 * g) = r;
            }
        }
    }
}

// build curr_Q, global_K, global_V from qv (1600x512) and idkv (1600x264)
__global__ __launch_bounds__(256) void make_qkv_kernel(const float* __restrict__ qv,
                                                       const float* __restrict__ idkv,
                                                       float* __restrict__ Qc,
                                                       float* __restrict__ gK,
                                                       float* __restrict__ gV) {
    int idx = blockIdx.x * 256 + threadIdx.x;
    if (idx >= L_SEQ * CDIM) return;
    int l = idx >> 8, c = idx & 255;
    int h = c >> 5;
    float q = qv[l * 512 + c];
    Qc[idx] = q;
    gK[idx] = q * (1.f + tanhf(idkv[l * 264 + h]));
    gV[idx] = qv[l * 512 + 256 + c] + idkv[l * 264 + 8 + c];
}

// concat [lt_wo | st_wo] along K into wcat (256 x 512); bsum = lt_bo + st_bo
__global__ __launch_bounds__(256) void prep_ltst(const float* __restrict__ lt_wo,
                                                 const float* __restrict__ lt_bo,
                                                 const float* __restrict__ st_wo,
                                                 const float* __restrict__ st_bo,
                                                 float* __restrict__ wcat,
                                                 float* __restrict__ bsum) {
    int idx = blockIdx.x * 256 + threadIdx.x;   // 0..65535
    int n = idx >> 8, k = idx & 255;
    wcat[n * 512 + k] = lt_wo[idx];
    wcat[n * 512 + 256 + k] = st_wo[idx];
    if (idx < 256) bsum[idx] = lt_bo[idx] + st_bo[idx];
}

// GroupNorm partials: grid (32 groups, 8 chunks); deterministic partial sums.
__global__ __launch_bounds__(256) void gn_partial(const float* __restrict__ X,
                                                  float* __restrict__ gstat) {
    __shared__ float sh4[4];
    int g = blockIdx.x, chunk = blockIdx.y;
    int base = g * 32;
    float s = 0.f, s2 = 0.f;
    for (int i = threadIdx.x; i < 200 * 32; i += 256) {
        int l = chunk * 200 + (i >> 5), c = i & 31;
        float v = X[l * DFF_ + base + c];
        s += v;
        s2 += v * v;
    }
    s = blockReduceSum(s, sh4);
    s2 = blockReduceSum(s2, sh4);
    if (threadIdx.x == 0) {
        gstat[g * 8 + chunk] = s;
        gstat[256 + g * 8 + chunk] = s2;
    }
}

// GroupNorm apply + exact GELU, float4-vectorized.
__global__ __launch_bounds__(256) void gn_apply(const float* __restrict__ X,
                                                const float* __restrict__ gstat,
                                                const float* __restrict__ g,
                                                const float* __restrict__ b,
                                                float* __restrict__ Y) {
    int idx = blockIdx.x * 256 + threadIdx.x;
    int e4 = idx * 4;
    int c = e4 & 1023;
    int grp = c >> 5;
    float s = 0.f, s2 = 0.f;
#pragma unroll
    for (int i = 0; i < 8; ++i) {
        s += gstat[grp * 8 + i];
        s2 += gstat[256 + grp * 8 + i];
    }
    const float invn = 1.0f / 51200.f;
    float mean = s * invn;
    float rs = rsqrtf(s2 * invn - mean * mean + 1e-5f);
    float4 v = *(const float4*)(X + e4);
    float4 gg = *(const float4*)(g + c);
    float4 bb = *(const float4*)(b + c);
    float4 r;
    float y0 = (v.x - mean) * rs * gg.x + bb.x;
    float y1 = (v.y - mean) * rs * gg.y + bb.y;
    float y2 = (v.z - mean) * rs * gg.z + bb.z;
    float y3 = (v.w - mean) * rs * gg.w + bb.w;
    r.x = 0.5f * y0 * (1.0f + erff(y0 * 0.70710678118654752f));
    r.y = 0.5f * y1 * (1.0f + erff(y1 * 0.70710678118654752f));
    r.z = 0.5f * y2 * (1.0f + erff(y2 * 0.70710678118654752f));
    r.w = 0.5f * y3 * (1.0f + erff(y3 * 0.70710678118654752f));
    *(float4*)(Y + e4) = r;
}

// transpose dw_k (1024,25) -> Kt (25,1024)
__global__ __launch_bounds__(256) void dwk_transpose(const float* __restrict__ Kw,
                                                     float* __restrict__ Kt) {
    int idx = blockIdx.x * 256 + threadIdx.x;
    if (idx >= 25 * DFF_) return;
    int k = idx >> 10, c = idx & 1023;
    Kt[idx] = Kw[c * 25 + k];
}

// depthwise 5x5 conv v2 (verified)
__global__ __launch_bounds__(256) void dwconv_v2(const float* __restrict__ X,
                                                 const float* __restrict__ Kt,
                                                 float* __restrict__ Y) {
    int l = blockIdx.x;
    int c4 = threadIdx.x * 4;
    int y = l / GRID_W, x = l - y * GRID_W;
    float4 acc = make_float4(0.f, 0.f, 0.f, 0.f);
    if (y >= 2 && y < GRID_H - 2 && x >= 2 && x < GRID_W - 2) {
#pragma unroll
        for (int ky = 0; ky < 5; ++ky) {
#pragma unroll
            for (int kx = 0; kx < 5; ++kx) {
                float4 xv = *(const float4*)(X + ((y + ky - 2) * GRID_W + x + kx - 2) * DFF_ + c4);
                float4 wv = *(const float4*)(Kt + (ky * 5 + kx) * DFF_ + c4);
                acc.x += xv.x * wv.x; acc.y += xv.y * wv.y;
                acc.z += xv.z * wv.z; acc.w += xv.w * wv.w;
            }
        }
    } else {
#pragma unroll
        for (int ky = 0; ky < 5; ++ky) {
            int yy = y + ky - 2;
            if (yy < 0 || yy >= GRID_H) continue;
#pragma unroll
            for (int kx = 0; kx < 5; ++kx) {
                int xx = x + kx - 2;
                if (xx < 0 || xx >= GRID_W) continue;
                float4 xv = *(const float4*)(X + (yy * GRID_W + xx) * DFF_ + c4);
                float4 wv = *(const float4*)(Kt + (ky * 5 + kx) * DFF_ + c4);
                acc.x += xv.x * wv.x; acc.y += xv.y * wv.y;
                acc.z += xv.z * wv.z; acc.w += xv.w * wv.w;
            }
        }
    }
    *(float4*)(Y + l * DFF_ + c4) = acc;
}

extern "C" void kernel_launch(void* const* d_in, const int* in_sizes, int n_in,
                              void* d_out, int out_size, void* d_ws, size_t ws_size,
                              hipStream_t stream) {
    (void)in_sizes; (void)n_in; (void)out_size; (void)ws_size;
    const float* tgt = (const float*)d_in[0];
    const float* curr_id_emb = (const float*)d_in[1];
    const float* self_pos = (const float*)d_in[2];
    const float* ln1_g = (const float*)d_in[3];
    const float* ln1_b = (const float*)d_in[4];
    const float* sa_wq = (const float*)d_in[5];
    const float* sa_bq = (const float*)d_in[6];
    const float* sa_wk = (const float*)d_in[7];
    const float* sa_bk = (const float*)d_in[8];
    const float* sa_wv = (const float*)d_in[9];
    const float* sa_bv = (const float*)d_in[10];
    const float* sa_wo = (const float*)d_in[11];
    const float* sa_bo = (const float*)d_in[12];
    const float* ln2_g = (const float*)d_in[13];
    const float* ln2_b = (const float*)d_in[14];
    const float* w_qv = (const float*)d_in[15];
    const float* b_qv = (const float*)d_in[16];
    const float* w_id = (const float*)d_in[17];
    const float* b_id = (const float*)d_in[18];
    const float* lt_wo = (const float*)d_in[19];
    const float* lt_bo = (const float*)d_in[20];
    const float* st_wo = (const float*)d_in[21];
    const float* st_bo = (const float*)d_in[22];
    const float* ln3_g = (const float*)d_in[23];
    const float* ln3_b = (const float*)d_in[24];
    const float* w1 = (const float*)d_in[25];
    const float* b1 = (const float*)d_in[26];
    const float* gn_g = (const float*)d_in[27];
    const float* gn_b = (const float*)d_in[28];
    const float* dw_k = (const float*)d_in[29];
    const float* w2 = (const float*)d_in[30];
    const float* b2 = (const float*)d_in[31];
    float* out = (float*)d_out;

    float* ws = (float*)d_ws;
    const int LC = L_SEQ * CDIM;           // 409600
    float* bufA = ws;                      // ln outputs
    float* bufB = bufA + LC;               // qk_in / tgt_b
    float* bufC = bufB + LC;               // q_ / curr_Q
    float* bufD = bufC + LC;               // k_ / global_K
    float* bufE = bufD + LC;               // v_ / global_V
    float* bufG = bufE + LC;               // tgt1
    float* bufFW = bufG + LC;              // attn outs (1600x512; self-attn uses ldo=256)
    float* bufH = bufFW + L_SEQ * 512;     // qv (1600x512); later gstat
    float* bufI = bufH + L_SEQ * 512;      // idkv (1600x264)
    float* bufX = bufI + L_SEQ * 264;      // w1 out (1600x1024)
    float* bufY = bufX + L_SEQ * DFF_;     // gn+gelu out
    float* bufZ = bufY + L_SEQ * DFF_;     // conv out
    float* bufW = bufZ + L_SEQ * DFF_;     // transposed dw_k (25x1024)
    float* wcat = bufW + 25 * DFF_;        // concat lt/st weights (256x512)
    float* bsum = wcat + 256 * 512;        // summed biases (256)

    dim3 blk(256);
    dim3 mhaGrid(L_SEQ / QBLK, NH);
    auto J = [](const float* A, const float* W, const float* bias, const float* res,
                float* C, int N, int K) {
        GJob j; j.A = A; j.W = W; j.bias = bias; j.res = res; j.C = C; j.N = N; j.K = K;
        return j;
    };

    // 0. independent prep
    dwk_transpose<<<100, blk, 0, stream>>>(dw_k, bufW);
    prep_ltst<<<256, blk, 0, stream>>>(lt_wo, lt_bo, st_wo, st_bo, wcat, bsum);
    // 1. LN1: bufA = ln(tgt), bufB = bufA + self_pos
    ln_kernel<<<L_SEQ, blk, 0, stream>>>(tgt, ln1_g, ln1_b, self_pos, bufA, bufB);
    // 2. q,k,v projections (one batched dispatch, 300 blocks)
    {
        GJob jq = J(bufB, sa_wq, sa_bq, nullptr, bufC, CDIM, CDIM);
        GJob jk = J(bufB, sa_wk, sa_bk, nullptr, bufD, CDIM, CDIM);
        GJob jv = J(bufA, sa_wv, sa_bv, nullptr, bufE, CDIM, CDIM);
        gemm_mfma<<<dim3(4, 25, 3), blk, 0, stream>>>(jq, jk, jv);
    }
    // 3. self attention -> bufFW (ldo=256)
    mha_mfma<<<mhaGrid, blk, 0, stream>>>(bufC, bufD, bufE, bufFW, CDIM);
    // 4. out proj + residual -> tgt1 (bufG)
    {
        GJob jo = J(bufFW, sa_wo, sa_bo, tgt, bufG, CDIM, CDIM);
        gemm_mfma<<<dim3(4, 25, 1), blk, 0, stream>>>(jo, jo, jo);
    }
    // 5. LN2 -> bufA
    ln_kernel<<<L_SEQ, blk, 0, stream>>>(bufG, ln2_g, ln2_b, nullptr, bufA, nullptr);
    // 6. qv + idkv (one batched dispatch)
    {
        GJob jqv = J(bufA, w_qv, b_qv, nullptr, bufH, 512, CDIM);
        GJob jid = J(curr_id_emb, w_id, b_id, nullptr, bufI, 264, CDIM);
        gemm_mfma<<<dim3(8, 25, 2), blk, 0, stream>>>(jqv, jid, jid);
    }
    // 7. curr_Q (bufC), global_K (bufD), global_V (bufE)
    make_qkv_kernel<<<L_SEQ, blk, 0, stream>>>(bufH, bufI, bufC, bufD, bufE);
    // 8. long-term attention -> bufFW cols 0..255 ; local attention -> cols 256..511
    mha_mfma<<<mhaGrid, blk, 0, stream>>>(bufC, bufD, bufE, bufFW, 512);
    local_mfma<<<dim3(GRID_H, NH), blk, 0, stream>>>(bufC, bufD, bufE, bufFW + 256, 512);
    // 9. merged lt/st projection: tgt_b = tgt1 + [mha2|local] @ wcat^T + bsum -> bufB
    {
        GJob jm = J(bufFW, wcat, bsum, bufG, bufB, CDIM, 512);
        gemm_mfma<<<dim3(4, 25, 1), blk, 0, stream>>>(jm, jm, jm);
    }
    // 10. LN3 -> bufA
    ln_kernel<<<L_SEQ, blk, 0, stream>>>(bufB, ln3_g, ln3_b, nullptr, bufA, nullptr);
    // 11. x = bufA @ w1^T -> bufX
    {
        GJob jw1 = J(bufA, w1, b1, nullptr, bufX, DFF_, CDIM);
        gemm_mfma<<<dim3(16, 25, 1), blk, 0, stream>>>(jw1, jw1, jw1);
    }
    // 12. GroupNorm + GELU -> bufY (bufH dead; reuse as gstat)
    gn_partial<<<dim3(32, 8), blk, 0, stream>>>(bufX, bufH);
    gn_apply<<<L_SEQ, blk, 0, stream>>>(bufX, bufH, gn_g, gn_b, bufY);
    // 13. depthwise conv -> bufZ
    dwconv_v2<<<L_SEQ, blk, 0, stream>>>(bufY, bufW, bufZ);
    // 14. final proj + residual(tgt_b) -> out
    {
        GJob jw2 = J(bufZ, w2, b2, bufB, out, CDIM, DFF_);
        gemm_mfma<<<dim3(4, 25, 1), blk, 0, stream>>>(jw2, jw2, jw2);
    }
}